// Round 1
// baseline (1590.333 us; speedup 1.0000x reference)
//
#include <hip/hip_runtime.h>

#define SEQ    2048
#define DIN    2048
#define DMODEL 1024
#define NROWS  4096   // BATCH*SEQ

__device__ __forceinline__ float sigf(float x) { return 1.0f / (1.0f + __expf(-x)); }

// ---------------- generic fp32 GEMM: C[m][n] = sum_k A[m][k] * W[n][k] ----------------
// grid: (M/128, N/128), 256 threads, 8x8 micro-tile, BK=16
__global__ __launch_bounds__(256) void gemm_ant(
    const float* __restrict__ A, const float* __restrict__ W, float* __restrict__ C,
    int K, int lda, int ldw, int ldc)
{
    __shared__ float As[16][128];
    __shared__ float Ws[16][128];
    const int tid = threadIdx.x;
    const int m0 = blockIdx.x * 128;
    const int n0 = blockIdx.y * 128;
    const int tx = tid & 15, ty = tid >> 4;

    float acc[8][8];
#pragma unroll
    for (int i = 0; i < 8; ++i)
#pragma unroll
        for (int j = 0; j < 8; ++j) acc[i][j] = 0.f;

    const int lr = tid >> 2;        // 0..63
    const int lc = (tid & 3) * 4;   // 0,4,8,12

    for (int k0 = 0; k0 < K; k0 += 16) {
#pragma unroll
        for (int j = 0; j < 2; ++j) {
            int r = lr + j * 64;
            float4 av = *(const float4*)(A + (m0 + r) * lda + k0 + lc);
            float4 wv = *(const float4*)(W + (n0 + r) * ldw + k0 + lc);
            As[lc + 0][r] = av.x; As[lc + 1][r] = av.y; As[lc + 2][r] = av.z; As[lc + 3][r] = av.w;
            Ws[lc + 0][r] = wv.x; Ws[lc + 1][r] = wv.y; Ws[lc + 2][r] = wv.z; Ws[lc + 3][r] = wv.w;
        }
        __syncthreads();
#pragma unroll
        for (int kk = 0; kk < 16; ++kk) {
            float a[8], b[8];
            *(float4*)&a[0] = *(const float4*)&As[kk][ty * 8];
            *(float4*)&a[4] = *(const float4*)&As[kk][ty * 8 + 4];
            *(float4*)&b[0] = *(const float4*)&Ws[kk][tx * 8];
            *(float4*)&b[4] = *(const float4*)&Ws[kk][tx * 8 + 4];
#pragma unroll
            for (int i = 0; i < 8; ++i)
#pragma unroll
                for (int j = 0; j < 8; ++j)
                    acc[i][j] = fmaf(a[i], b[j], acc[i][j]);
        }
        __syncthreads();
    }
#pragma unroll
    for (int i = 0; i < 8; ++i) {
        float4 v0 = make_float4(acc[i][0], acc[i][1], acc[i][2], acc[i][3]);
        float4 v1 = make_float4(acc[i][4], acc[i][5], acc[i][6], acc[i][7]);
        float* p = C + (m0 + ty * 8 + i) * ldc + n0 + tx * 8;
        *(float4*)p = v0;
        *(float4*)(p + 4) = v1;
    }
}

// ---------------- causal depthwise conv(4) + bias + SiLU ----------------
// xs = xz[:, :, 0:2048]; xc[b,l,d] = silu(sum_k xs[b,l-3+k,d]*w[d,k] + b[d])
__global__ __launch_bounds__(256) void conv_silu_k(
    const float* __restrict__ xz, const float* __restrict__ cw,
    const float* __restrict__ cb, float* __restrict__ xc)
{
    int idx = blockIdx.x * 256 + threadIdx.x;   // 2*2048*2048 total
    int d = idx & (DIN - 1);
    int l = (idx >> 11) & (SEQ - 1);
    int b = idx >> 22;
    float w0 = cw[d * 4 + 0], w1 = cw[d * 4 + 1], w2 = cw[d * 4 + 2], w3 = cw[d * 4 + 3];
    int rowb = b * SEQ + l;
    const float* col = xz + d;
    float acc = cb[d];
    if (l >= 3) acc = fmaf(col[(rowb - 3) * 4096], w0, acc);
    if (l >= 2) acc = fmaf(col[(rowb - 2) * 4096], w1, acc);
    if (l >= 1) acc = fmaf(col[(rowb - 1) * 4096], w2, acc);
    acc = fmaf(col[rowb * 4096], w3, acc);
    xc[rowb * DIN + d] = acc * sigf(acc);
}

// ---------------- x_dbl = xc @ x_proj_w^T  (M=4096, N=96, K=2048) ----------------
// grid: M/32 blocks, 256 threads; each thread: 2 rows x 6 cols
__global__ __launch_bounds__(256) void xproj_k(
    const float* __restrict__ xc, const float* __restrict__ Wx, float* __restrict__ xdbl)
{
    __shared__ float xs[32][129];
    __shared__ float wsh[96][129];
    const int tid = threadIdx.x;
    const int m0 = blockIdx.x * 32;
    const int ml = (tid & 15) * 2;
    const int rg = tid >> 4;                   // 0..15 -> cols rg*6..rg*6+5
    float acc0[6] = {0, 0, 0, 0, 0, 0};
    float acc1[6] = {0, 0, 0, 0, 0, 0};
    for (int k0 = 0; k0 < DIN; k0 += 128) {
        for (int i = tid; i < 32 * 128; i += 256) {
            int r = i >> 7, c = i & 127;
            xs[r][c] = xc[(m0 + r) * DIN + k0 + c];
        }
        for (int i = tid; i < 96 * 128; i += 256) {
            int r = i >> 7, c = i & 127;
            wsh[r][c] = Wx[r * DIN + k0 + c];
        }
        __syncthreads();
        for (int c = 0; c < 128; ++c) {
            float a0 = xs[ml][c], a1 = xs[ml + 1][c];
#pragma unroll
            for (int j = 0; j < 6; ++j) {
                float w = wsh[rg * 6 + j][c];
                acc0[j] = fmaf(a0, w, acc0[j]);
                acc1[j] = fmaf(a1, w, acc1[j]);
            }
        }
        __syncthreads();
    }
#pragma unroll
    for (int j = 0; j < 6; ++j) {
        xdbl[(m0 + ml) * 96 + rg * 6 + j]     = acc0[j];
        xdbl[(m0 + ml + 1) * 96 + rg * 6 + j] = acc1[j];
    }
}

// ---------------- dt = softplus(dt_low @ dt_proj_w^T + b)  (M=4096, N=2048, K=64) ----------------
__global__ __launch_bounds__(256) void dtproj_k(
    const float* __restrict__ xdbl, const float* __restrict__ Wd,
    const float* __restrict__ bd, float* __restrict__ dt)
{
    __shared__ float as[64][65];
    __shared__ float wsh[64][65];
    const int tid = threadIdx.x;
    const int m0 = blockIdx.x * 64, n0 = blockIdx.y * 64;
    for (int i = tid; i < 4096; i += 256) {
        int r = i >> 6, c = i & 63;
        as[r][c]  = xdbl[(m0 + r) * 96 + c];   // dt_low = x_dbl[:, 0:64]
        wsh[r][c] = Wd[(n0 + r) * 64 + c];
    }
    __syncthreads();
    const int tx = tid & 15, ty = tid >> 4;
    float acc[4][4] = {};
#pragma unroll
    for (int k = 0; k < 64; ++k) {
        float a[4], w[4];
#pragma unroll
        for (int i = 0; i < 4; ++i) a[i] = as[ty * 4 + i][k];
#pragma unroll
        for (int j = 0; j < 4; ++j) w[j] = wsh[tx * 4 + j][k];
#pragma unroll
        for (int i = 0; i < 4; ++i)
#pragma unroll
            for (int j = 0; j < 4; ++j)
                acc[i][j] = fmaf(a[i], w[j], acc[i][j]);
    }
#pragma unroll
    for (int i = 0; i < 4; ++i)
#pragma unroll
        for (int j = 0; j < 4; ++j) {
            int m = m0 + ty * 4 + i, n = n0 + tx * 4 + j;
            float v = acc[i][j] + bd[n];
            v = (v > 20.0f) ? v : log1pf(__expf(v));
            dt[m * DIN + n] = v;
        }
}

// ---------------- selective scan + epilogue ----------------
// block = (16 states) x (16 d); grid = (128 d-groups, 2 batch)
// op[b,l,d] = (scan_y + xc*D[d]) * silu(z);   op may alias dt (rows staged before overwrite)
__global__ __launch_bounds__(256) void scan_k(
    const float* __restrict__ dt, const float* __restrict__ xc,
    const float* __restrict__ xz, const float* __restrict__ xdbl,
    const float* __restrict__ Alog, const float* __restrict__ Dp,
    float* __restrict__ op)
{
    __shared__ float dts[64][16], xcs[64][16], zss[64][16], Bss[64][16], Css[64][16];
    const int b  = blockIdx.y;
    const int d0 = blockIdx.x * 16;
    const int tid = threadIdx.x;
    const int n = tid & 15, dl = tid >> 4;
    const int d = d0 + dl;
    const float Aval = -__expf(Alog[d * 16 + n]);
    const float Dd = Dp[d];
    float h = 0.f;
    for (int t0 = 0; t0 < SEQ; t0 += 64) {
        for (int i = tid; i < 1024; i += 256) {
            int tt = i >> 4, c = i & 15;
            int row = b * SEQ + t0 + tt;
            dts[tt][c] = dt[row * DIN + d0 + c];
            xcs[tt][c] = xc[row * DIN + d0 + c];
            zss[tt][c] = xz[row * 4096 + DIN + d0 + c];
            Bss[tt][c] = xdbl[row * 96 + 64 + c];
            Css[tt][c] = xdbl[row * 96 + 80 + c];
        }
        __syncthreads();
        for (int tt = 0; tt < 64; ++tt) {
            float dtv = dts[tt][dl];
            float xcv = xcs[tt][dl];
            float dA = __expf(dtv * Aval);
            h = fmaf(dA, h, dtv * Bss[tt][n] * xcv);
            float p = h * Css[tt][n];
            p += __shfl_xor(p, 1, 16);
            p += __shfl_xor(p, 2, 16);
            p += __shfl_xor(p, 4, 16);
            p += __shfl_xor(p, 8, 16);
            if (n == 0) {
                float zv = zss[tt][dl];
                int row = b * SEQ + t0 + tt;
                op[row * DIN + d] = (p + xcv * Dd) * zv * sigf(zv);
            }
        }
        __syncthreads();
    }
}

extern "C" void kernel_launch(void* const* d_in, const int* in_sizes, int n_in,
                              void* d_out, int out_size, void* d_ws, size_t ws_size,
                              hipStream_t stream)
{
    const float* x    = (const float*)d_in[0];
    const float* wi   = (const float*)d_in[1];
    const float* cw   = (const float*)d_in[2];
    const float* cb   = (const float*)d_in[3];
    const float* wx   = (const float*)d_in[4];
    const float* wd   = (const float*)d_in[5];
    const float* bd   = (const float*)d_in[6];
    const float* alog = (const float*)d_in[7];
    const float* Dp   = (const float*)d_in[8];
    const float* wo   = (const float*)d_in[9];
    float* out = (float*)d_out;

    float* wsf  = (float*)d_ws;
    float* xz   = wsf;                          // 4096*4096 = 64 MB
    float* xc   = xz + (size_t)NROWS * 4096;    // 4096*2048 = 32 MB
    float* xdbl = xc + (size_t)NROWS * DIN;     // 4096*96
    float* dt   = xdbl + (size_t)NROWS * 96;    // 4096*2048 = 32 MB
    float* op   = dt;                           // alias: scan stages dt rows into LDS before overwrite

    // xz = x @ in_proj_w^T  (M=4096, N=4096, K=1024)
    gemm_ant<<<dim3(32, 32), 256, 0, stream>>>(x, wi, xz, 1024, 1024, 1024, 4096);
    // xc = silu(depthwise_conv(xs) + b)
    conv_silu_k<<<32768, 256, 0, stream>>>(xz, cw, cb, xc);
    // x_dbl = xc @ x_proj_w^T
    xproj_k<<<128, 256, 0, stream>>>(xc, wx, xdbl);
    // dt = softplus(dt_low @ dt_proj_w^T + b)
    dtproj_k<<<dim3(64, 32), 256, 0, stream>>>(xdbl, wd, bd, dt);
    // selective scan + gating epilogue -> op
    scan_k<<<dim3(128, 2), 256, 0, stream>>>(dt, xc, xz, xdbl, alog, Dp, op);
    // out = op @ out_proj_w^T  (M=4096, N=1024, K=2048)
    gemm_ant<<<dim3(32, 8), 256, 0, stream>>>(op, wo, out, 2048, 2048, 2048, 1024);
}

// Round 2
// 1210.013 us; speedup vs baseline: 1.3143x; 1.3143x over previous
//
#include <hip/hip_runtime.h>

#define SEQ    2048
#define DIN    2048
#define DMODEL 1024
#define NROWS  4096   // BATCH*SEQ
#define NCH    32     // chunks
#define CHL    64     // chunk length

__device__ __forceinline__ float sigf(float x) { return 1.0f / (1.0f + __expf(-x)); }

// map a linear index into the dead xs-half of xz (row-major [4096][4096], cols 0..2047 dead after conv)
__device__ __forceinline__ float* deadp(float* xzbuf, size_t j) {
    return xzbuf + ((j >> 11) << 12) + (j & 2047);
}

// ---------------- generic fp32 GEMM: C[m][n] = sum_k A[m][k] * W[n][k] ----------------
__global__ __launch_bounds__(256) void gemm_ant(
    const float* __restrict__ A, const float* __restrict__ W, float* __restrict__ C,
    int K, int lda, int ldw, int ldc)
{
    __shared__ float As[16][128];
    __shared__ float Ws[16][128];
    const int tid = threadIdx.x;
    const int m0 = blockIdx.x * 128;
    const int n0 = blockIdx.y * 128;
    const int tx = tid & 15, ty = tid >> 4;

    float acc[8][8];
#pragma unroll
    for (int i = 0; i < 8; ++i)
#pragma unroll
        for (int j = 0; j < 8; ++j) acc[i][j] = 0.f;

    const int lr = tid >> 2;
    const int lc = (tid & 3) * 4;

    for (int k0 = 0; k0 < K; k0 += 16) {
#pragma unroll
        for (int j = 0; j < 2; ++j) {
            int r = lr + j * 64;
            float4 av = *(const float4*)(A + (m0 + r) * lda + k0 + lc);
            float4 wv = *(const float4*)(W + (n0 + r) * ldw + k0 + lc);
            As[lc + 0][r] = av.x; As[lc + 1][r] = av.y; As[lc + 2][r] = av.z; As[lc + 3][r] = av.w;
            Ws[lc + 0][r] = wv.x; Ws[lc + 1][r] = wv.y; Ws[lc + 2][r] = wv.z; Ws[lc + 3][r] = wv.w;
        }
        __syncthreads();
#pragma unroll
        for (int kk = 0; kk < 16; ++kk) {
            float a[8], b[8];
            *(float4*)&a[0] = *(const float4*)&As[kk][ty * 8];
            *(float4*)&a[4] = *(const float4*)&As[kk][ty * 8 + 4];
            *(float4*)&b[0] = *(const float4*)&Ws[kk][tx * 8];
            *(float4*)&b[4] = *(const float4*)&Ws[kk][tx * 8 + 4];
#pragma unroll
            for (int i = 0; i < 8; ++i)
#pragma unroll
                for (int j = 0; j < 8; ++j)
                    acc[i][j] = fmaf(a[i], b[j], acc[i][j]);
        }
        __syncthreads();
    }
#pragma unroll
    for (int i = 0; i < 8; ++i) {
        float4 v0 = make_float4(acc[i][0], acc[i][1], acc[i][2], acc[i][3]);
        float4 v1 = make_float4(acc[i][4], acc[i][5], acc[i][6], acc[i][7]);
        float* p = C + (m0 + ty * 8 + i) * ldc + n0 + tx * 8;
        *(float4*)p = v0;
        *(float4*)(p + 4) = v1;
    }
}

// ---------------- causal depthwise conv(4) + bias + SiLU ----------------
__global__ __launch_bounds__(256) void conv_silu_k(
    const float* __restrict__ xz, const float* __restrict__ cw,
    const float* __restrict__ cb, float* __restrict__ xc)
{
    int idx = blockIdx.x * 256 + threadIdx.x;
    int d = idx & (DIN - 1);
    int l = (idx >> 11) & (SEQ - 1);
    int b = idx >> 22;
    float w0 = cw[d * 4 + 0], w1 = cw[d * 4 + 1], w2 = cw[d * 4 + 2], w3 = cw[d * 4 + 3];
    int rowb = b * SEQ + l;
    const float* col = xz + d;
    float acc = cb[d];
    if (l >= 3) acc = fmaf(col[(rowb - 3) * 4096], w0, acc);
    if (l >= 2) acc = fmaf(col[(rowb - 2) * 4096], w1, acc);
    if (l >= 1) acc = fmaf(col[(rowb - 1) * 4096], w2, acc);
    acc = fmaf(col[rowb * 4096], w3, acc);
    xc[rowb * DIN + d] = acc * sigf(acc);
}

// ---------------- x_dbl = xc @ x_proj_w^T  (M=4096, N=96, K=2048) ----------------
__global__ __launch_bounds__(256) void xproj_k(
    const float* __restrict__ xc, const float* __restrict__ Wx, float* __restrict__ xdbl)
{
    __shared__ float xs[32][129];
    __shared__ float wsh[96][129];
    const int tid = threadIdx.x;
    const int m0 = blockIdx.x * 32;
    const int ml = (tid & 15) * 2;
    const int rg = tid >> 4;
    float acc0[6] = {0, 0, 0, 0, 0, 0};
    float acc1[6] = {0, 0, 0, 0, 0, 0};
    for (int k0 = 0; k0 < DIN; k0 += 128) {
        for (int i = tid; i < 32 * 128; i += 256) {
            int r = i >> 7, c = i & 127;
            xs[r][c] = xc[(m0 + r) * DIN + k0 + c];
        }
        for (int i = tid; i < 96 * 128; i += 256) {
            int r = i >> 7, c = i & 127;
            wsh[r][c] = Wx[r * DIN + k0 + c];
        }
        __syncthreads();
        for (int c = 0; c < 128; ++c) {
            float a0 = xs[ml][c], a1 = xs[ml + 1][c];
#pragma unroll
            for (int j = 0; j < 6; ++j) {
                float w = wsh[rg * 6 + j][c];
                acc0[j] = fmaf(a0, w, acc0[j]);
                acc1[j] = fmaf(a1, w, acc1[j]);
            }
        }
        __syncthreads();
    }
#pragma unroll
    for (int j = 0; j < 6; ++j) {
        xdbl[(m0 + ml) * 96 + rg * 6 + j]     = acc0[j];
        xdbl[(m0 + ml + 1) * 96 + rg * 6 + j] = acc1[j];
    }
}

// ---------------- dt = softplus(dt_low @ dt_proj_w^T + b) ----------------
__global__ __launch_bounds__(256) void dtproj_k(
    const float* __restrict__ xdbl, const float* __restrict__ Wd,
    const float* __restrict__ bd, float* __restrict__ dt)
{
    __shared__ float as[64][65];
    __shared__ float wsh[64][65];
    const int tid = threadIdx.x;
    const int m0 = blockIdx.x * 64, n0 = blockIdx.y * 64;
    for (int i = tid; i < 4096; i += 256) {
        int r = i >> 6, c = i & 63;
        as[r][c]  = xdbl[(m0 + r) * 96 + c];
        wsh[r][c] = Wd[(n0 + r) * 64 + c];
    }
    __syncthreads();
    const int tx = tid & 15, ty = tid >> 4;
    float acc[4][4] = {};
#pragma unroll
    for (int k = 0; k < 64; ++k) {
        float a[4], w[4];
#pragma unroll
        for (int i = 0; i < 4; ++i) a[i] = as[ty * 4 + i][k];
#pragma unroll
        for (int j = 0; j < 4; ++j) w[j] = wsh[tx * 4 + j][k];
#pragma unroll
        for (int i = 0; i < 4; ++i)
#pragma unroll
            for (int j = 0; j < 4; ++j)
                acc[i][j] = fmaf(a[i], w[j], acc[i][j]);
    }
#pragma unroll
    for (int i = 0; i < 4; ++i)
#pragma unroll
        for (int j = 0; j < 4; ++j) {
            int m = m0 + ty * 4 + i, n = n0 + tx * 4 + j;
            float v = acc[i][j] + bd[n];
            v = (v > 20.0f) ? v : log1pf(__expf(v));
            dt[m * DIN + n] = v;
        }
}

// ---------------- chunked selective scan ----------------
// pass 1: per-chunk local scan (h0=0) + exact per-chunk prod(dA)
// grid (128 d-groups, 32 chunks, 2 batch); block 256 = 16n x 16d
__global__ __launch_bounds__(256) void scan_pass1(
    const float* __restrict__ dt, const float* __restrict__ xc,
    const float* __restrict__ xdbl, const float* __restrict__ Alog,
    float* __restrict__ xzbuf)   // hloc/aprd live in dead xs half of xz
{
    __shared__ float dts[CHL][16], xcs[CHL][16], Bss[CHL][16];
    const int b  = blockIdx.z;
    const int c  = blockIdx.y;
    const int d0 = blockIdx.x * 16;
    const int tid = threadIdx.x;
    const int n = tid & 15, dl = tid >> 4;
    const int d = d0 + dl;
    const float Aval = -__expf(Alog[d * 16 + n]);
    const int t0 = c * CHL;
    for (int i = tid; i < CHL * 16; i += 256) {
        int tt = i >> 4, cc = i & 15;
        int row = b * SEQ + t0 + tt;
        dts[tt][cc] = dt[row * DIN + d0 + cc];
        xcs[tt][cc] = xc[row * DIN + d0 + cc];
        Bss[tt][cc] = xdbl[row * 96 + 64 + cc];
    }
    __syncthreads();
    float h = 0.f, ap = 1.f;
#pragma unroll 8
    for (int tt = 0; tt < CHL; ++tt) {
        float dtv = dts[tt][dl];
        float dA = __expf(dtv * Aval);
        h = fmaf(dA, h, dtv * Bss[tt][n] * xcs[tt][dl]);
        ap *= dA;
    }
    size_t e = ((size_t)(b * NCH + c) << 15) + (size_t)d * 16 + n;
    *deadp(xzbuf, e)                      = h;   // hloc
    *deadp(xzbuf, e + ((size_t)1 << 21))  = ap;  // aprd
}

// pass 2: in-place exclusive scan over chunks; one thread per (b,d,n)
__global__ __launch_bounds__(256) void scan_pass2(float* __restrict__ xzbuf)
{
    int idx = blockIdx.x * 256 + threadIdx.x;   // 2*2048*16 = 65536
    int b = idx >> 15;
    int dn = idx & 32767;
    float carry = 0.f;
    for (int c = 0; c < NCH; ++c) {
        size_t e = ((size_t)(b * NCH + c) << 15) + dn;
        float* hp = deadp(xzbuf, e);
        float hl = *hp;
        float ap = *deadp(xzbuf, e + ((size_t)1 << 21));
        *hp = carry;                       // h_in for chunk c
        carry = fmaf(ap, carry, hl);
    }
}

// pass 3: re-scan chunk from h_in, emit y + fused epilogue.  op may alias dt.
__global__ __launch_bounds__(256) void scan_pass3(
    const float* __restrict__ dt, const float* __restrict__ xc,
    const float* __restrict__ xz, const float* __restrict__ xdbl,
    const float* __restrict__ Alog, const float* __restrict__ Dp,
    float* __restrict__ xzbuf, float* __restrict__ op)
{
    __shared__ float dts[CHL][16], xcs[CHL][16], zss[CHL][16], Bss[CHL][16], Css[CHL][16];
    const int b  = blockIdx.z;
    const int c  = blockIdx.y;
    const int d0 = blockIdx.x * 16;
    const int tid = threadIdx.x;
    const int n = tid & 15, dl = tid >> 4;
    const int d = d0 + dl;
    const float Aval = -__expf(Alog[d * 16 + n]);
    const float Dd = Dp[d];
    const int t0 = c * CHL;
    for (int i = tid; i < CHL * 16; i += 256) {
        int tt = i >> 4, cc = i & 15;
        int row = b * SEQ + t0 + tt;
        dts[tt][cc] = dt[row * DIN + d0 + cc];
        xcs[tt][cc] = xc[row * DIN + d0 + cc];
        zss[tt][cc] = xz[row * 4096 + DIN + d0 + cc];
        Bss[tt][cc] = xdbl[row * 96 + 64 + cc];
        Css[tt][cc] = xdbl[row * 96 + 80 + cc];
    }
    __syncthreads();
    float h = *deadp(xzbuf, ((size_t)(b * NCH + c) << 15) + (size_t)d * 16 + n);
    for (int tt = 0; tt < CHL; ++tt) {
        float dtv = dts[tt][dl];
        float xcv = xcs[tt][dl];
        float dA = __expf(dtv * Aval);
        h = fmaf(dA, h, dtv * Bss[tt][n] * xcv);
        float p = h * Css[tt][n];
        p += __shfl_xor(p, 1, 16);
        p += __shfl_xor(p, 2, 16);
        p += __shfl_xor(p, 4, 16);
        p += __shfl_xor(p, 8, 16);
        if (n == 0) {
            float zv = zss[tt][dl];
            int row = b * SEQ + t0 + tt;
            op[row * DIN + d] = (p + xcv * Dd) * zv * sigf(zv);
        }
    }
}

extern "C" void kernel_launch(void* const* d_in, const int* in_sizes, int n_in,
                              void* d_out, int out_size, void* d_ws, size_t ws_size,
                              hipStream_t stream)
{
    const float* x    = (const float*)d_in[0];
    const float* wi   = (const float*)d_in[1];
    const float* cw   = (const float*)d_in[2];
    const float* cb   = (const float*)d_in[3];
    const float* wx   = (const float*)d_in[4];
    const float* wd   = (const float*)d_in[5];
    const float* bd   = (const float*)d_in[6];
    const float* alog = (const float*)d_in[7];
    const float* Dp   = (const float*)d_in[8];
    const float* wo   = (const float*)d_in[9];
    float* out = (float*)d_out;

    float* wsf  = (float*)d_ws;
    float* xz   = wsf;                          // 4096*4096
    float* xc   = xz + (size_t)NROWS * 4096;    // 4096*2048
    float* xdbl = xc + (size_t)NROWS * DIN;     // 4096*96
    float* dt   = xdbl + (size_t)NROWS * 96;    // 4096*2048
    float* op   = dt;                           // alias (disjoint per-block r/w)

    gemm_ant<<<dim3(32, 32), 256, 0, stream>>>(x, wi, xz, 1024, 1024, 1024, 4096);
    conv_silu_k<<<32768, 256, 0, stream>>>(xz, cw, cb, xc);
    xproj_k<<<128, 256, 0, stream>>>(xc, wx, xdbl);
    dtproj_k<<<dim3(64, 32), 256, 0, stream>>>(xdbl, wd, bd, dt);
    scan_pass1<<<dim3(128, NCH, 2), 256, 0, stream>>>(dt, xc, xdbl, alog, xz);
    scan_pass2<<<256, 256, 0, stream>>>(xz);
    scan_pass3<<<dim3(128, NCH, 2), 256, 0, stream>>>(dt, xc, xz, xdbl, alog, Dp, xz, op);
    gemm_ant<<<dim3(32, 8), 256, 0, stream>>>(op, wo, out, 2048, 2048, 2048, 1024);
}

// Round 3
// 658.851 us; speedup vs baseline: 2.4138x; 1.8366x over previous
//
#include <hip/hip_runtime.h>

#define SEQ    2048
#define DIN    2048
#define DMODEL 1024
#define NROWS  4096   // BATCH*SEQ
#define NCH    32     // scan chunks
#define CHL    64     // chunk length

typedef __attribute__((ext_vector_type(8))) short short8v;
typedef __attribute__((ext_vector_type(4))) float f32x4;

__device__ __forceinline__ float sigf(float x) { return 1.0f / (1.0f + __expf(-x)); }

// map a linear index into the dead xs-half of xz (row-major [4096][4096], cols 0..2047 dead after conv)
__device__ __forceinline__ float* deadp(float* xzbuf, size_t j) {
    return xzbuf + ((j >> 11) << 12) + (j & 2047);
}

__device__ __forceinline__ void gload16(const void* g, const void* l) {
    __builtin_amdgcn_global_load_lds((const __attribute__((address_space(1))) void*)g,
                                     (__attribute__((address_space(3))) void*)l, 16, 0, 0);
}

// ---------------- fp32 -> bf16 hi/lo split (RNE both) ----------------
__device__ __forceinline__ void split1(float x, unsigned short& h, unsigned short& l) {
    unsigned u = __float_as_uint(x);
    unsigned hb = (u + 0x7FFFu + ((u >> 16) & 1u)) >> 16;
    float hf = __uint_as_float(hb << 16);
    float r = x - hf;
    unsigned u2 = __float_as_uint(r);
    unsigned lb = (u2 + 0x7FFFu + ((u2 >> 16) & 1u)) >> 16;
    h = (unsigned short)hb; l = (unsigned short)lb;
}

__global__ __launch_bounds__(256) void cvt_split_k(
    const float* __restrict__ in, unsigned short* __restrict__ hi,
    unsigned short* __restrict__ lo, int n4)
{
    int i = blockIdx.x * 256 + threadIdx.x;
    if (i >= n4) return;
    float4 v = ((const float4*)in)[i];
    ushort4 h, l;
    split1(v.x, h.x, l.x);
    split1(v.y, h.y, l.y);
    split1(v.z, h.z, l.z);
    split1(v.w, h.w, l.w);
    ((ushort4*)hi)[i] = h;
    ((ushort4*)lo)[i] = l;
}

// ---------------- split-bf16 MFMA GEMM: C[M][N] = (Ahi+Alo) . (Whi+Wlo)^T ----------------
// A* : [M][K] bf16, W* : [N][K] bf16, C : [M][N] f32.  Tile 128x128, BK=64, 4 waves.
#define AHI_OFF 0
#define ALO_OFF 16384
#define WHI_OFF 32768
#define WLO_OFF 49152

__global__ __launch_bounds__(256) void gemm_mfma_split(
    const unsigned short* __restrict__ Ahi, const unsigned short* __restrict__ Alo,
    const unsigned short* __restrict__ Whi, const unsigned short* __restrict__ Wlo,
    float* __restrict__ C, int K, int N, int mtiles)
{
    __shared__ uint4 ldsu4[4096];           // 64 KiB: Ahi|Alo|Whi|Wlo, each [128][64] bf16 swizzled
    char* lds = (char*)ldsu4;
    const int tid  = threadIdx.x;
    const int w    = tid >> 6, lane = tid & 63;

    // XCD-aware block swizzle (grid % 8 == 0 for both call sites)
    const int nwg = gridDim.x;
    const int cpx = nwg >> 3;
    const int bid = blockIdx.x;
    const int swz = (bid & 7) * cpx + (bid >> 3);
    const int m0 = (swz % mtiles) * 128;
    const int n0 = (swz / mtiles) * 128;

    const int wr = w >> 1, wc = w & 1;      // wave owns 64x64 at (wr*64, wc*64)

    f32x4 acc[4][4];
#pragma unroll
    for (int i = 0; i < 4; ++i)
#pragma unroll
        for (int j = 0; j < 4; ++j) { acc[i][j][0]=0.f; acc[i][j][1]=0.f; acc[i][j][2]=0.f; acc[i][j][3]=0.f; }

    // staging: wave w stages local rows [w*32, w*32+32) of each array, 4 issues x 8 rows
    const int rloc = w * 32 + (lane >> 3);           // local row for issue 0
    const int xr8  = ((lane & 7) ^ (lane >> 3)) << 3; // pre-swizzled k-chunk (elements)
    const unsigned short* gAhi = Ahi + (size_t)(m0 + rloc) * K + xr8;
    const unsigned short* gAlo = Alo + (size_t)(m0 + rloc) * K + xr8;
    const unsigned short* gWhi = Whi + (size_t)(n0 + rloc) * K + xr8;
    const unsigned short* gWlo = Wlo + (size_t)(n0 + rloc) * K + xr8;

    const int lm  = lane & 15;
    const int lk  = lane >> 4;
    const int lk4 = lk * 4;

    for (int kt = 0; kt < K; kt += 64) {
#pragma unroll
        for (int i = 0; i < 4; ++i) {
            const int rb = w * 32 + i * 8;           // LDS row base (uniform)
            const size_t go = (size_t)i * 8 * K + kt;
            gload16(gAhi + go, lds + AHI_OFF + rb * 128);
            gload16(gAlo + go, lds + ALO_OFF + rb * 128);
            gload16(gWhi + go, lds + WHI_OFF + rb * 128);
            gload16(gWlo + go, lds + WLO_OFF + rb * 128);
        }
        __syncthreads();
#pragma unroll
        for (int h = 0; h < 2; ++h) {
            short8v afh[4], afl[4], wfh[4], wfl[4];
            const int ch = h * 4 + lk;
#pragma unroll
            for (int t = 0; t < 4; ++t) {
                const int ar = wr * 64 + t * 16 + lm;
                const int wrw = wc * 64 + t * 16 + lm;
                afh[t] = *(const short8v*)(lds + AHI_OFF + ar * 128 + ((ch ^ (ar & 7)) << 4));
                afl[t] = *(const short8v*)(lds + ALO_OFF + ar * 128 + ((ch ^ (ar & 7)) << 4));
                wfh[t] = *(const short8v*)(lds + WHI_OFF + wrw * 128 + ((ch ^ (wrw & 7)) << 4));
                wfl[t] = *(const short8v*)(lds + WLO_OFF + wrw * 128 + ((ch ^ (wrw & 7)) << 4));
            }
#pragma unroll
            for (int i = 0; i < 4; ++i)
#pragma unroll
                for (int j = 0; j < 4; ++j) {
                    acc[i][j] = __builtin_amdgcn_mfma_f32_16x16x32_bf16(afh[i], wfh[j], acc[i][j], 0, 0, 0);
                    acc[i][j] = __builtin_amdgcn_mfma_f32_16x16x32_bf16(afh[i], wfl[j], acc[i][j], 0, 0, 0);
                    acc[i][j] = __builtin_amdgcn_mfma_f32_16x16x32_bf16(afl[i], wfh[j], acc[i][j], 0, 0, 0);
                }
        }
        __syncthreads();
    }

#pragma unroll
    for (int i = 0; i < 4; ++i)
#pragma unroll
        for (int j = 0; j < 4; ++j)
#pragma unroll
            for (int r = 0; r < 4; ++r)
                C[(size_t)(m0 + wr * 64 + i * 16 + lk4 + r) * N + (n0 + wc * 64 + j * 16 + lm)] = acc[i][j][r];
}

// ---------------- causal depthwise conv(4) + bias + SiLU ----------------
__global__ __launch_bounds__(256) void conv_silu_k(
    const float* __restrict__ xz, const float* __restrict__ cw,
    const float* __restrict__ cb, float* __restrict__ xc)
{
    int idx = blockIdx.x * 256 + threadIdx.x;
    int d = idx & (DIN - 1);
    int l = (idx >> 11) & (SEQ - 1);
    int b = idx >> 22;
    float w0 = cw[d * 4 + 0], w1 = cw[d * 4 + 1], w2 = cw[d * 4 + 2], w3 = cw[d * 4 + 3];
    int rowb = b * SEQ + l;
    const float* col = xz + d;
    float acc = cb[d];
    if (l >= 3) acc = fmaf(col[(rowb - 3) * 4096], w0, acc);
    if (l >= 2) acc = fmaf(col[(rowb - 2) * 4096], w1, acc);
    if (l >= 1) acc = fmaf(col[(rowb - 1) * 4096], w2, acc);
    acc = fmaf(col[rowb * 4096], w3, acc);
    xc[rowb * DIN + d] = acc * sigf(acc);
}

// ---------------- x_dbl = xc @ x_proj_w^T  (M=4096, N=96, K=2048) ----------------
__global__ __launch_bounds__(256) void xproj_k(
    const float* __restrict__ xc, const float* __restrict__ Wx, float* __restrict__ xdbl)
{
    __shared__ float xs[32][129];
    __shared__ float wsh[96][129];
    const int tid = threadIdx.x;
    const int m0 = blockIdx.x * 32;
    const int ml = (tid & 15) * 2;
    const int rg = tid >> 4;
    float acc0[6] = {0, 0, 0, 0, 0, 0};
    float acc1[6] = {0, 0, 0, 0, 0, 0};
    for (int k0 = 0; k0 < DIN; k0 += 128) {
        for (int i = tid; i < 32 * 128; i += 256) {
            int r = i >> 7, c = i & 127;
            xs[r][c] = xc[(m0 + r) * DIN + k0 + c];
        }
        for (int i = tid; i < 96 * 128; i += 256) {
            int r = i >> 7, c = i & 127;
            wsh[r][c] = Wx[r * DIN + k0 + c];
        }
        __syncthreads();
        for (int c = 0; c < 128; ++c) {
            float a0 = xs[ml][c], a1 = xs[ml + 1][c];
#pragma unroll
            for (int j = 0; j < 6; ++j) {
                float w = wsh[rg * 6 + j][c];
                acc0[j] = fmaf(a0, w, acc0[j]);
                acc1[j] = fmaf(a1, w, acc1[j]);
            }
        }
        __syncthreads();
    }
#pragma unroll
    for (int j = 0; j < 6; ++j) {
        xdbl[(m0 + ml) * 96 + rg * 6 + j]     = acc0[j];
        xdbl[(m0 + ml + 1) * 96 + rg * 6 + j] = acc1[j];
    }
}

// ---------------- dt = softplus(dt_low @ dt_proj_w^T + b) ----------------
__global__ __launch_bounds__(256) void dtproj_k(
    const float* __restrict__ xdbl, const float* __restrict__ Wd,
    const float* __restrict__ bd, float* __restrict__ dt)
{
    __shared__ float as[64][65];
    __shared__ float wsh[64][65];
    const int tid = threadIdx.x;
    const int m0 = blockIdx.x * 64, n0 = blockIdx.y * 64;
    for (int i = tid; i < 4096; i += 256) {
        int r = i >> 6, c = i & 63;
        as[r][c]  = xdbl[(m0 + r) * 96 + c];
        wsh[r][c] = Wd[(n0 + r) * 64 + c];
    }
    __syncthreads();
    const int tx = tid & 15, ty = tid >> 4;
    float acc[4][4] = {};
#pragma unroll
    for (int k = 0; k < 64; ++k) {
        float a[4], wv[4];
#pragma unroll
        for (int i = 0; i < 4; ++i) a[i] = as[ty * 4 + i][k];
#pragma unroll
        for (int j = 0; j < 4; ++j) wv[j] = wsh[tx * 4 + j][k];
#pragma unroll
        for (int i = 0; i < 4; ++i)
#pragma unroll
            for (int j = 0; j < 4; ++j)
                acc[i][j] = fmaf(a[i], wv[j], acc[i][j]);
    }
#pragma unroll
    for (int i = 0; i < 4; ++i)
#pragma unroll
        for (int j = 0; j < 4; ++j) {
            int m = m0 + ty * 4 + i, n = n0 + tx * 4 + j;
            float v = acc[i][j] + bd[n];
            v = (v > 20.0f) ? v : log1pf(__expf(v));
            dt[m * DIN + n] = v;
        }
}

// ---------------- chunked selective scan ----------------
__global__ __launch_bounds__(256) void scan_pass1(
    const float* __restrict__ dt, const float* __restrict__ xc,
    const float* __restrict__ xdbl, const float* __restrict__ Alog,
    float* __restrict__ xzbuf)
{
    __shared__ float dts[CHL][16], xcs[CHL][16], Bss[CHL][16];
    const int b  = blockIdx.z;
    const int c  = blockIdx.y;
    const int d0 = blockIdx.x * 16;
    const int tid = threadIdx.x;
    const int n = tid & 15, dl = tid >> 4;
    const int d = d0 + dl;
    const float Aval = -__expf(Alog[d * 16 + n]);
    const int t0 = c * CHL;
    for (int i = tid; i < CHL * 16; i += 256) {
        int tt = i >> 4, cc = i & 15;
        int row = b * SEQ + t0 + tt;
        dts[tt][cc] = dt[row * DIN + d0 + cc];
        xcs[tt][cc] = xc[row * DIN + d0 + cc];
        Bss[tt][cc] = xdbl[row * 96 + 64 + cc];
    }
    __syncthreads();
    float h = 0.f, ap = 1.f;
#pragma unroll 8
    for (int tt = 0; tt < CHL; ++tt) {
        float dtv = dts[tt][dl];
        float dA = __expf(dtv * Aval);
        h = fmaf(dA, h, dtv * Bss[tt][n] * xcs[tt][dl]);
        ap *= dA;
    }
    size_t e = ((size_t)(b * NCH + c) << 15) + (size_t)d * 16 + n;
    *deadp(xzbuf, e)                      = h;
    *deadp(xzbuf, e + ((size_t)1 << 21))  = ap;
}

__global__ __launch_bounds__(256) void scan_pass2(float* __restrict__ xzbuf)
{
    int idx = blockIdx.x * 256 + threadIdx.x;
    int b = idx >> 15;
    int dn = idx & 32767;
    float carry = 0.f;
    for (int c = 0; c < NCH; ++c) {
        size_t e = ((size_t)(b * NCH + c) << 15) + dn;
        float* hp = deadp(xzbuf, e);
        float hl = *hp;
        float ap = *deadp(xzbuf, e + ((size_t)1 << 21));
        *hp = carry;
        carry = fmaf(ap, carry, hl);
    }
}

__global__ __launch_bounds__(256) void scan_pass3(
    const float* __restrict__ dt, const float* __restrict__ xc,
    const float* __restrict__ xz, const float* __restrict__ xdbl,
    const float* __restrict__ Alog, const float* __restrict__ Dp,
    float* __restrict__ xzbuf, float* __restrict__ op)
{
    __shared__ float dts[CHL][16], xcs[CHL][16], zss[CHL][16], Bss[CHL][16], Css[CHL][16];
    const int b  = blockIdx.z;
    const int c  = blockIdx.y;
    const int d0 = blockIdx.x * 16;
    const int tid = threadIdx.x;
    const int n = tid & 15, dl = tid >> 4;
    const int d = d0 + dl;
    const float Aval = -__expf(Alog[d * 16 + n]);
    const float Dd = Dp[d];
    const int t0 = c * CHL;
    for (int i = tid; i < CHL * 16; i += 256) {
        int tt = i >> 4, cc = i & 15;
        int row = b * SEQ + t0 + tt;
        dts[tt][cc] = dt[row * DIN + d0 + cc];
        xcs[tt][cc] = xc[row * DIN + d0 + cc];
        zss[tt][cc] = xz[row * 4096 + DIN + d0 + cc];
        Bss[tt][cc] = xdbl[row * 96 + 64 + cc];
        Css[tt][cc] = xdbl[row * 96 + 80 + cc];
    }
    __syncthreads();
    float h = *deadp(xzbuf, ((size_t)(b * NCH + c) << 15) + (size_t)d * 16 + n);
    for (int tt = 0; tt < CHL; ++tt) {
        float dtv = dts[tt][dl];
        float xcv = xcs[tt][dl];
        float dA = __expf(dtv * Aval);
        h = fmaf(dA, h, dtv * Bss[tt][n] * xcv);
        float p = h * Css[tt][n];
        p += __shfl_xor(p, 1, 16);
        p += __shfl_xor(p, 2, 16);
        p += __shfl_xor(p, 4, 16);
        p += __shfl_xor(p, 8, 16);
        if (n == 0) {
            float zv = zss[tt][dl];
            int row = b * SEQ + t0 + tt;
            op[row * DIN + d] = (p + xcv * Dd) * zv * sigf(zv);
        }
    }
}

extern "C" void kernel_launch(void* const* d_in, const int* in_sizes, int n_in,
                              void* d_out, int out_size, void* d_ws, size_t ws_size,
                              hipStream_t stream)
{
    const float* x    = (const float*)d_in[0];
    const float* wi   = (const float*)d_in[1];
    const float* cw   = (const float*)d_in[2];
    const float* cb   = (const float*)d_in[3];
    const float* wx   = (const float*)d_in[4];
    const float* wd   = (const float*)d_in[5];
    const float* bd   = (const float*)d_in[6];
    const float* alog = (const float*)d_in[7];
    const float* Dp   = (const float*)d_in[8];
    const float* wo   = (const float*)d_in[9];
    float* out = (float*)d_out;

    float* wsf  = (float*)d_ws;
    float* xz   = wsf;                          // [4096][4096] f32
    float* xc   = xz + (size_t)NROWS * 4096;    // [4096][2048] f32
    float* xdbl = xc + (size_t)NROWS * DIN;     // [4096][96]
    float* dt   = xdbl + (size_t)NROWS * 96;    // [4096][2048] f32
    float* op   = dt;                           // alias

    // bf16 split buffers (region reuse; all dead before their region's next writer)
    unsigned short* xhi  = (unsigned short*)xc;              // 4M elems (xc not yet written)
    unsigned short* xlo  = xhi + (size_t)4096 * 1024;
    unsigned short* wihi = (unsigned short*)dt;              // 4M elems (dt not yet written)
    unsigned short* wilo = wihi + (size_t)4096 * 1024;
    unsigned short* ophi = (unsigned short*)xz;              // 8M elems (xz dead after scan_pass3)
    unsigned short* oplo = ophi + (size_t)4096 * 2048;
    unsigned short* wohi = oplo + (size_t)4096 * 2048;       // 2M elems
    unsigned short* wolo = wohi + (size_t)1024 * 2048;

    // 1) split inputs of in_proj
    cvt_split_k<<<4096, 256, 0, stream>>>(x, xhi, xlo, 1048576);
    cvt_split_k<<<4096, 256, 0, stream>>>(wi, wihi, wilo, 1048576);
    // 2) xz = x @ in_proj_w^T   (M=4096, N=4096, K=1024)
    gemm_mfma_split<<<1024, 256, 0, stream>>>(xhi, xlo, wihi, wilo, xz, 1024, 4096, 32);
    // 3) xc = silu(conv(xs)+b)  (overwrites xhi/xlo — dead)
    conv_silu_k<<<32768, 256, 0, stream>>>(xz, cw, cb, xc);
    // 4) x_dbl
    xproj_k<<<128, 256, 0, stream>>>(xc, wx, xdbl);
    // 5) dt (overwrites wihi/wilo — dead)
    dtproj_k<<<dim3(64, 32), 256, 0, stream>>>(xdbl, wd, bd, dt);
    // 6) chunked scan
    scan_pass1<<<dim3(128, NCH, 2), 256, 0, stream>>>(dt, xc, xdbl, alog, xz);
    scan_pass2<<<256, 256, 0, stream>>>(xz);
    scan_pass3<<<dim3(128, NCH, 2), 256, 0, stream>>>(dt, xc, xz, xdbl, alog, Dp, xz, op);
    // 7) split inputs of out_proj (xz fully dead now)
    cvt_split_k<<<8192, 256, 0, stream>>>(op, ophi, oplo, 2097152);
    cvt_split_k<<<2048, 256, 0, stream>>>(wo, wohi, wolo, 524288);
    // 8) out = op @ out_proj_w^T (M=4096, N=1024, K=2048)
    gemm_mfma_split<<<256, 256, 0, stream>>>(ophi, oplo, wohi, wolo, out, 2048, 1024, 32);
}

// Round 4
// 470.945 us; speedup vs baseline: 3.3769x; 1.3990x over previous
//
#include <hip/hip_runtime.h>

#define SEQ    2048
#define DIN    2048
#define DMODEL 1024
#define NROWS  4096   // BATCH*SEQ
#define NCH    32     // scan chunks
#define CHL    64     // chunk length

typedef __attribute__((ext_vector_type(8))) short short8v;
typedef __attribute__((ext_vector_type(4))) float f32x4;

__device__ __forceinline__ float sigf(float x) { return 1.0f / (1.0f + __expf(-x)); }

// dead xs-half of xz (rows 0..2047 usage by scan): j -> row j>>11, col j&2047
__device__ __forceinline__ float* deadp(float* xzbuf, size_t j) {
    return xzbuf + ((j >> 11) << 12) + (j & 2047);
}
// second dead window: rows 2048..4095, cols 0..2047 (xproj partials)
__device__ __forceinline__ float* deadp2(float* xzbuf, size_t j) {
    return xzbuf + ((size_t)(2048 + (j >> 11)) << 12) + (j & 2047);
}

__device__ __forceinline__ void gload16(const void* g, const void* l) {
    __builtin_amdgcn_global_load_lds((const __attribute__((address_space(1))) void*)g,
                                     (__attribute__((address_space(3))) void*)l, 16, 0, 0);
}

// ---------------- fp32 -> bf16 hi/lo split (RNE both) ----------------
__device__ __forceinline__ void split1(float x, unsigned short& h, unsigned short& l) {
    unsigned u = __float_as_uint(x);
    unsigned hb = (u + 0x7FFFu + ((u >> 16) & 1u)) >> 16;
    float hf = __uint_as_float(hb << 16);
    float r = x - hf;
    unsigned u2 = __float_as_uint(r);
    unsigned lb = (u2 + 0x7FFFu + ((u2 >> 16) & 1u)) >> 16;
    h = (unsigned short)hb; l = (unsigned short)lb;
}

__global__ __launch_bounds__(256) void cvt_split_k(
    const float* __restrict__ in, unsigned short* __restrict__ hi,
    unsigned short* __restrict__ lo, int n4)
{
    int i = blockIdx.x * 256 + threadIdx.x;
    if (i >= n4) return;
    float4 v = ((const float4*)in)[i];
    ushort4 h, l;
    split1(v.x, h.x, l.x);
    split1(v.y, h.y, l.y);
    split1(v.z, h.z, l.z);
    split1(v.w, h.w, l.w);
    ((ushort4*)hi)[i] = h;
    ((ushort4*)lo)[i] = l;
}

// ---------------- split-bf16 MFMA GEMM (unchanged) ----------------
#define AHI_OFF 0
#define ALO_OFF 16384
#define WHI_OFF 32768
#define WLO_OFF 49152

__global__ __launch_bounds__(256) void gemm_mfma_split(
    const unsigned short* __restrict__ Ahi, const unsigned short* __restrict__ Alo,
    const unsigned short* __restrict__ Whi, const unsigned short* __restrict__ Wlo,
    float* __restrict__ C, int K, int N, int mtiles)
{
    __shared__ uint4 ldsu4[4096];
    char* lds = (char*)ldsu4;
    const int tid  = threadIdx.x;
    const int w    = tid >> 6, lane = tid & 63;

    const int nwg = gridDim.x;
    const int cpx = nwg >> 3;
    const int bid = blockIdx.x;
    const int swz = (bid & 7) * cpx + (bid >> 3);
    const int m0 = (swz % mtiles) * 128;
    const int n0 = (swz / mtiles) * 128;

    const int wr = w >> 1, wc = w & 1;

    f32x4 acc[4][4];
#pragma unroll
    for (int i = 0; i < 4; ++i)
#pragma unroll
        for (int j = 0; j < 4; ++j) { acc[i][j][0]=0.f; acc[i][j][1]=0.f; acc[i][j][2]=0.f; acc[i][j][3]=0.f; }

    const int rloc = w * 32 + (lane >> 3);
    const int xr8  = ((lane & 7) ^ (lane >> 3)) << 3;
    const unsigned short* gAhi = Ahi + (size_t)(m0 + rloc) * K + xr8;
    const unsigned short* gAlo = Alo + (size_t)(m0 + rloc) * K + xr8;
    const unsigned short* gWhi = Whi + (size_t)(n0 + rloc) * K + xr8;
    const unsigned short* gWlo = Wlo + (size_t)(n0 + rloc) * K + xr8;

    const int lm  = lane & 15;
    const int lk  = lane >> 4;
    const int lk4 = lk * 4;

    for (int kt = 0; kt < K; kt += 64) {
#pragma unroll
        for (int i = 0; i < 4; ++i) {
            const int rb = w * 32 + i * 8;
            const size_t go = (size_t)i * 8 * K + kt;
            gload16(gAhi + go, lds + AHI_OFF + rb * 128);
            gload16(gAlo + go, lds + ALO_OFF + rb * 128);
            gload16(gWhi + go, lds + WHI_OFF + rb * 128);
            gload16(gWlo + go, lds + WLO_OFF + rb * 128);
        }
        __syncthreads();
#pragma unroll
        for (int h = 0; h < 2; ++h) {
            short8v afh[4], afl[4], wfh[4], wfl[4];
            const int ch = h * 4 + lk;
#pragma unroll
            for (int t = 0; t < 4; ++t) {
                const int ar = wr * 64 + t * 16 + lm;
                const int wrw = wc * 64 + t * 16 + lm;
                afh[t] = *(const short8v*)(lds + AHI_OFF + ar * 128 + ((ch ^ (ar & 7)) << 4));
                afl[t] = *(const short8v*)(lds + ALO_OFF + ar * 128 + ((ch ^ (ar & 7)) << 4));
                wfh[t] = *(const short8v*)(lds + WHI_OFF + wrw * 128 + ((ch ^ (wrw & 7)) << 4));
                wfl[t] = *(const short8v*)(lds + WLO_OFF + wrw * 128 + ((ch ^ (wrw & 7)) << 4));
            }
#pragma unroll
            for (int i = 0; i < 4; ++i)
#pragma unroll
                for (int j = 0; j < 4; ++j) {
                    acc[i][j] = __builtin_amdgcn_mfma_f32_16x16x32_bf16(afh[i], wfh[j], acc[i][j], 0, 0, 0);
                    acc[i][j] = __builtin_amdgcn_mfma_f32_16x16x32_bf16(afh[i], wfl[j], acc[i][j], 0, 0, 0);
                    acc[i][j] = __builtin_amdgcn_mfma_f32_16x16x32_bf16(afl[i], wfh[j], acc[i][j], 0, 0, 0);
                }
        }
        __syncthreads();
    }

#pragma unroll
    for (int i = 0; i < 4; ++i)
#pragma unroll
        for (int j = 0; j < 4; ++j)
#pragma unroll
            for (int r = 0; r < 4; ++r)
                C[(size_t)(m0 + wr * 64 + i * 16 + lk4 + r) * N + (n0 + wc * 64 + j * 16 + lm)] = acc[i][j][r];
}

// ---------------- causal depthwise conv(4) + bias + SiLU ----------------
__global__ __launch_bounds__(256) void conv_silu_k(
    const float* __restrict__ xz, const float* __restrict__ cw,
    const float* __restrict__ cb, float* __restrict__ xc)
{
    int idx = blockIdx.x * 256 + threadIdx.x;
    int d = idx & (DIN - 1);
    int l = (idx >> 11) & (SEQ - 1);
    int b = idx >> 22;
    float w0 = cw[d * 4 + 0], w1 = cw[d * 4 + 1], w2 = cw[d * 4 + 2], w3 = cw[d * 4 + 3];
    int rowb = b * SEQ + l;
    const float* col = xz + d;
    float acc = cb[d];
    if (l >= 3) acc = fmaf(col[(rowb - 3) * 4096], w0, acc);
    if (l >= 2) acc = fmaf(col[(rowb - 2) * 4096], w1, acc);
    if (l >= 1) acc = fmaf(col[(rowb - 1) * 4096], w2, acc);
    acc = fmaf(col[rowb * 4096], w3, acc);
    xc[rowb * DIN + d] = acc * sigf(acc);
}

// ---------------- xproj stage 1: partial x_dbl over K-split ----------------
// grid (64 m-tiles of 64 rows, 8 k-splits of 256); partials -> dead xz rows 2048+
__global__ __launch_bounds__(256) void xproj_part_k(
    const float* __restrict__ xc, const float* __restrict__ Wx, float* __restrict__ xzbuf)
{
    __shared__ float xs[64][68];
    __shared__ float wsh[96][68];
    const int tid = threadIdx.x;
    const int m0 = blockIdx.x * 64;
    const int ks = blockIdx.y;
    const int tx = tid & 15, rg = tid >> 4;
    float acc[4][6] = {};
    for (int k0 = ks * 256; k0 < ks * 256 + 256; k0 += 64) {
        for (int i = tid; i < 64 * 16; i += 256) {
            int r = i >> 4, c = i & 15;
            *(float4*)&xs[r][c * 4] = *(const float4*)&xc[(size_t)(m0 + r) * DIN + k0 + c * 4];
        }
        for (int i = tid; i < 96 * 16; i += 256) {
            int r = i >> 4, c = i & 15;
            *(float4*)&wsh[r][c * 4] = *(const float4*)&Wx[(size_t)r * DIN + k0 + c * 4];
        }
        __syncthreads();
#pragma unroll 2
        for (int c4 = 0; c4 < 16; ++c4) {
            float4 a[4];
#pragma unroll
            for (int i = 0; i < 4; ++i) a[i] = *(float4*)&xs[tx + i * 16][c4 * 4];
#pragma unroll
            for (int j = 0; j < 6; ++j) {
                float4 w = *(float4*)&wsh[rg * 6 + j][c4 * 4];
#pragma unroll
                for (int i = 0; i < 4; ++i) {
                    acc[i][j] = fmaf(a[i].x, w.x, acc[i][j]);
                    acc[i][j] = fmaf(a[i].y, w.y, acc[i][j]);
                    acc[i][j] = fmaf(a[i].z, w.z, acc[i][j]);
                    acc[i][j] = fmaf(a[i].w, w.w, acc[i][j]);
                }
            }
        }
        __syncthreads();
    }
#pragma unroll
    for (int i = 0; i < 4; ++i)
#pragma unroll
        for (int j = 0; j < 6; ++j) {
            size_t jj = (size_t)ks * (NROWS * 96) + (size_t)(m0 + tx + i * 16) * 96 + rg * 6 + j;
            *deadp2(xzbuf, jj) = acc[i][j];
        }
}

// stage 2: xdbl = sum of 8 partials
__global__ __launch_bounds__(256) void xproj_reduce_k(
    const float* __restrict__ xzbuf_c, float* __restrict__ xdbl)
{
    float* xzbuf = (float*)xzbuf_c;
    int i = blockIdx.x * 256 + threadIdx.x;   // 4096*96 = 393216
    if (i >= NROWS * 96) return;
    float s = 0.f;
#pragma unroll
    for (int ks = 0; ks < 8; ++ks)
        s += *deadp2(xzbuf, (size_t)ks * (NROWS * 96) + i);
    xdbl[i] = s;
}

// ---------------- dt = softplus(dt_low @ dt_proj_w^T + b)  (rewritten) ----------------
// tile 128m x 64n, K=64 staged once; pad-68 LDS rows -> conflict-free b128 reads
__global__ __launch_bounds__(256) void dtproj_k(
    const float* __restrict__ xdbl, const float* __restrict__ Wd,
    const float* __restrict__ bd, float* __restrict__ dt)
{
    __shared__ float as_[128][68];
    __shared__ float ws_[64][68];
    const int tid = threadIdx.x;
    const int m0 = blockIdx.x * 128, n0 = blockIdx.y * 64;
    const int tx = tid & 15, ty = tid >> 4;
    for (int i = tid; i < 128 * 16; i += 256) {
        int r = i >> 4, c = i & 15;
        *(float4*)&as_[r][c * 4] = *(const float4*)&xdbl[(size_t)(m0 + r) * 96 + c * 4];
    }
    for (int i = tid; i < 64 * 16; i += 256) {
        int r = i >> 4, c = i & 15;
        *(float4*)&ws_[r][c * 4] = *(const float4*)&Wd[(size_t)(n0 + r) * 64 + c * 4];
    }
    __syncthreads();
    float acc[8][4] = {};
#pragma unroll 2
    for (int k4 = 0; k4 < 16; ++k4) {
        float4 av[8], wv[4];
#pragma unroll
        for (int i = 0; i < 8; ++i) av[i] = *(float4*)&as_[i * 16 + ty][k4 * 4];
#pragma unroll
        for (int j = 0; j < 4; ++j) wv[j] = *(float4*)&ws_[j * 16 + tx][k4 * 4];
#pragma unroll
        for (int i = 0; i < 8; ++i)
#pragma unroll
            for (int j = 0; j < 4; ++j) {
                acc[i][j] = fmaf(av[i].x, wv[j].x, acc[i][j]);
                acc[i][j] = fmaf(av[i].y, wv[j].y, acc[i][j]);
                acc[i][j] = fmaf(av[i].z, wv[j].z, acc[i][j]);
                acc[i][j] = fmaf(av[i].w, wv[j].w, acc[i][j]);
            }
    }
#pragma unroll
    for (int i = 0; i < 8; ++i)
#pragma unroll
        for (int j = 0; j < 4; ++j) {
            int m = m0 + i * 16 + ty, n = n0 + j * 16 + tx;
            float v = acc[i][j] + bd[n];
            v = (v > 20.0f) ? v : log1pf(__expf(v));
            dt[(size_t)m * DIN + n] = v;
        }
}

// ---------------- chunked selective scan (unchanged) ----------------
__global__ __launch_bounds__(256) void scan_pass1(
    const float* __restrict__ dt, const float* __restrict__ xc,
    const float* __restrict__ xdbl, const float* __restrict__ Alog,
    float* __restrict__ xzbuf)
{
    __shared__ float dts[CHL][16], xcs[CHL][16], Bss[CHL][16];
    const int b  = blockIdx.z;
    const int c  = blockIdx.y;
    const int d0 = blockIdx.x * 16;
    const int tid = threadIdx.x;
    const int n = tid & 15, dl = tid >> 4;
    const int d = d0 + dl;
    const float Aval = -__expf(Alog[d * 16 + n]);
    const int t0 = c * CHL;
    for (int i = tid; i < CHL * 16; i += 256) {
        int tt = i >> 4, cc = i & 15;
        int row = b * SEQ + t0 + tt;
        dts[tt][cc] = dt[row * DIN + d0 + cc];
        xcs[tt][cc] = xc[row * DIN + d0 + cc];
        Bss[tt][cc] = xdbl[row * 96 + 64 + cc];
    }
    __syncthreads();
    float h = 0.f, ap = 1.f;
#pragma unroll 8
    for (int tt = 0; tt < CHL; ++tt) {
        float dtv = dts[tt][dl];
        float dA = __expf(dtv * Aval);
        h = fmaf(dA, h, dtv * Bss[tt][n] * xcs[tt][dl]);
        ap *= dA;
    }
    size_t e = ((size_t)(b * NCH + c) << 15) + (size_t)d * 16 + n;
    *deadp(xzbuf, e)                      = h;
    *deadp(xzbuf, e + ((size_t)1 << 21))  = ap;
}

__global__ __launch_bounds__(256) void scan_pass2(float* __restrict__ xzbuf)
{
    int idx = blockIdx.x * 256 + threadIdx.x;
    int b = idx >> 15;
    int dn = idx & 32767;
    float carry = 0.f;
    for (int c = 0; c < NCH; ++c) {
        size_t e = ((size_t)(b * NCH + c) << 15) + dn;
        float* hp = deadp(xzbuf, e);
        float hl = *hp;
        float ap = *deadp(xzbuf, e + ((size_t)1 << 21));
        *hp = carry;
        carry = fmaf(ap, carry, hl);
    }
}

__global__ __launch_bounds__(256) void scan_pass3(
    const float* __restrict__ dt, const float* __restrict__ xc,
    const float* __restrict__ xz, const float* __restrict__ xdbl,
    const float* __restrict__ Alog, const float* __restrict__ Dp,
    float* __restrict__ xzbuf, float* __restrict__ op)
{
    __shared__ float dts[CHL][16], xcs[CHL][16], zss[CHL][16], Bss[CHL][16], Css[CHL][16];
    const int b  = blockIdx.z;
    const int c  = blockIdx.y;
    const int d0 = blockIdx.x * 16;
    const int tid = threadIdx.x;
    const int n = tid & 15, dl = tid >> 4;
    const int d = d0 + dl;
    const float Aval = -__expf(Alog[d * 16 + n]);
    const float Dd = Dp[d];
    const int t0 = c * CHL;
    for (int i = tid; i < CHL * 16; i += 256) {
        int tt = i >> 4, cc = i & 15;
        int row = b * SEQ + t0 + tt;
        dts[tt][cc] = dt[row * DIN + d0 + cc];
        xcs[tt][cc] = xc[row * DIN + d0 + cc];
        zss[tt][cc] = xz[row * 4096 + DIN + d0 + cc];
        Bss[tt][cc] = xdbl[row * 96 + 64 + cc];
        Css[tt][cc] = xdbl[row * 96 + 80 + cc];
    }
    __syncthreads();
    float h = *deadp(xzbuf, ((size_t)(b * NCH + c) << 15) + (size_t)d * 16 + n);
    for (int tt = 0; tt < CHL; ++tt) {
        float dtv = dts[tt][dl];
        float xcv = xcs[tt][dl];
        float dA = __expf(dtv * Aval);
        h = fmaf(dA, h, dtv * Bss[tt][n] * xcv);
        float p = h * Css[tt][n];
        p += __shfl_xor(p, 1, 16);
        p += __shfl_xor(p, 2, 16);
        p += __shfl_xor(p, 4, 16);
        p += __shfl_xor(p, 8, 16);
        if (n == 0) {
            float zv = zss[tt][dl];
            int row = b * SEQ + t0 + tt;
            op[row * DIN + d] = (p + xcv * Dd) * zv * sigf(zv);
        }
    }
}

extern "C" void kernel_launch(void* const* d_in, const int* in_sizes, int n_in,
                              void* d_out, int out_size, void* d_ws, size_t ws_size,
                              hipStream_t stream)
{
    const float* x    = (const float*)d_in[0];
    const float* wi   = (const float*)d_in[1];
    const float* cw   = (const float*)d_in[2];
    const float* cb   = (const float*)d_in[3];
    const float* wx   = (const float*)d_in[4];
    const float* wd   = (const float*)d_in[5];
    const float* bd   = (const float*)d_in[6];
    const float* alog = (const float*)d_in[7];
    const float* Dp   = (const float*)d_in[8];
    const float* wo   = (const float*)d_in[9];
    float* out = (float*)d_out;

    float* wsf  = (float*)d_ws;
    float* xz   = wsf;                          // [4096][4096] f32
    float* xc   = xz + (size_t)NROWS * 4096;    // [4096][2048] f32
    float* xdbl = xc + (size_t)NROWS * DIN;     // [4096][96]
    float* dt   = xdbl + (size_t)NROWS * 96;    // [4096][2048] f32
    float* op   = dt;                           // alias

    unsigned short* xhi  = (unsigned short*)xc;
    unsigned short* xlo  = xhi + (size_t)4096 * 1024;
    unsigned short* wihi = (unsigned short*)dt;
    unsigned short* wilo = wihi + (size_t)4096 * 1024;
    unsigned short* ophi = (unsigned short*)xz;
    unsigned short* oplo = ophi + (size_t)4096 * 2048;
    unsigned short* wohi = oplo + (size_t)4096 * 2048;
    unsigned short* wolo = wohi + (size_t)1024 * 2048;

    // 1) split inputs of in_proj
    cvt_split_k<<<4096, 256, 0, stream>>>(x, xhi, xlo, 1048576);
    cvt_split_k<<<4096, 256, 0, stream>>>(wi, wihi, wilo, 1048576);
    // 2) xz = x @ in_proj_w^T
    gemm_mfma_split<<<1024, 256, 0, stream>>>(xhi, xlo, wihi, wilo, xz, 1024, 4096, 32);
    // 3) xc = silu(conv(xs)+b)
    conv_silu_k<<<32768, 256, 0, stream>>>(xz, cw, cb, xc);
    // 4) x_dbl: K-split partials (dead xz rows 2048+) then reduce
    xproj_part_k<<<dim3(64, 8), 256, 0, stream>>>(xc, wx, xz);
    xproj_reduce_k<<<1536, 256, 0, stream>>>(xz, xdbl);
    // 5) dt
    dtproj_k<<<dim3(32, 32), 256, 0, stream>>>(xdbl, wd, bd, dt);
    // 6) chunked scan
    scan_pass1<<<dim3(128, NCH, 2), 256, 0, stream>>>(dt, xc, xdbl, alog, xz);
    scan_pass2<<<256, 256, 0, stream>>>(xz);
    scan_pass3<<<dim3(128, NCH, 2), 256, 0, stream>>>(dt, xc, xz, xdbl, alog, Dp, xz, op);
    // 7) split inputs of out_proj
    cvt_split_k<<<8192, 256, 0, stream>>>(op, ophi, oplo, 2097152);
    cvt_split_k<<<2048, 256, 0, stream>>>(wo, wohi, wolo, 524288);
    // 8) out = op @ out_proj_w^T
    gemm_mfma_split<<<256, 256, 0, stream>>>(ophi, oplo, wohi, wolo, out, 2048, 1024, 32);
}

// Round 5
// 381.035 us; speedup vs baseline: 4.1737x; 1.2360x over previous
//
#include <hip/hip_runtime.h>

#define SEQ    2048
#define DIN    2048
#define DMODEL 1024
#define NROWS  4096   // BATCH*SEQ
#define NCH    64     // scan chunks
#define CHL    32     // chunk length

typedef __attribute__((ext_vector_type(8))) short short8v;
typedef __attribute__((ext_vector_type(4))) float f32x4;

__device__ __forceinline__ float sigf(float x) { return 1.0f / (1.0f + __expf(-x)); }

// dead xs-half of xz (rows 0..2047, cols 0..2047): holds h chunk states
__device__ __forceinline__ float* deadp(float* xzbuf, size_t j) {
    return xzbuf + ((j >> 11) << 12) + (j & 2047);
}
// second dead window (rows 2048..4095, cols 0..2047): xproj partials, then prod(dA)
__device__ __forceinline__ float* deadp2(float* xzbuf, size_t j) {
    return xzbuf + ((size_t)(2048 + (j >> 11)) << 12) + (j & 2047);
}

__device__ __forceinline__ void gload16(const void* g, const void* l) {
    __builtin_amdgcn_global_load_lds((const __attribute__((address_space(1))) void*)g,
                                     (__attribute__((address_space(3))) void*)l, 16, 0, 0);
}

// ---------------- fp32 -> bf16 hi/lo split (RNE both) ----------------
__device__ __forceinline__ void split1(float x, unsigned short& h, unsigned short& l) {
    unsigned u = __float_as_uint(x);
    unsigned hb = (u + 0x7FFFu + ((u >> 16) & 1u)) >> 16;
    float hf = __uint_as_float(hb << 16);
    float r = x - hf;
    unsigned u2 = __float_as_uint(r);
    unsigned lb = (u2 + 0x7FFFu + ((u2 >> 16) & 1u)) >> 16;
    h = (unsigned short)hb; l = (unsigned short)lb;
}

__global__ __launch_bounds__(256) void cvt_split_k(
    const float* __restrict__ in, unsigned short* __restrict__ hi,
    unsigned short* __restrict__ lo, int n4)
{
    int i = blockIdx.x * 256 + threadIdx.x;
    if (i >= n4) return;
    float4 v = ((const float4*)in)[i];
    ushort4 h, l;
    split1(v.x, h.x, l.x);
    split1(v.y, h.y, l.y);
    split1(v.z, h.z, l.z);
    split1(v.w, h.w, l.w);
    ((ushort4*)hi)[i] = h;
    ((ushort4*)lo)[i] = l;
}

// ---------------- split-bf16 MFMA GEMM (unchanged) ----------------
#define AHI_OFF 0
#define ALO_OFF 16384
#define WHI_OFF 32768
#define WLO_OFF 49152

__global__ __launch_bounds__(256) void gemm_mfma_split(
    const unsigned short* __restrict__ Ahi, const unsigned short* __restrict__ Alo,
    const unsigned short* __restrict__ Whi, const unsigned short* __restrict__ Wlo,
    float* __restrict__ C, int K, int N, int mtiles)
{
    __shared__ uint4 ldsu4[4096];
    char* lds = (char*)ldsu4;
    const int tid  = threadIdx.x;
    const int w    = tid >> 6, lane = tid & 63;

    const int nwg = gridDim.x;
    const int cpx = nwg >> 3;
    const int bid = blockIdx.x;
    const int swz = (bid & 7) * cpx + (bid >> 3);
    const int m0 = (swz % mtiles) * 128;
    const int n0 = (swz / mtiles) * 128;

    const int wr = w >> 1, wc = w & 1;

    f32x4 acc[4][4];
#pragma unroll
    for (int i = 0; i < 4; ++i)
#pragma unroll
        for (int j = 0; j < 4; ++j) { acc[i][j][0]=0.f; acc[i][j][1]=0.f; acc[i][j][2]=0.f; acc[i][j][3]=0.f; }

    const int rloc = w * 32 + (lane >> 3);
    const int xr8  = ((lane & 7) ^ (lane >> 3)) << 3;
    const unsigned short* gAhi = Ahi + (size_t)(m0 + rloc) * K + xr8;
    const unsigned short* gAlo = Alo + (size_t)(m0 + rloc) * K + xr8;
    const unsigned short* gWhi = Whi + (size_t)(n0 + rloc) * K + xr8;
    const unsigned short* gWlo = Wlo + (size_t)(n0 + rloc) * K + xr8;

    const int lm  = lane & 15;
    const int lk  = lane >> 4;
    const int lk4 = lk * 4;

    for (int kt = 0; kt < K; kt += 64) {
#pragma unroll
        for (int i = 0; i < 4; ++i) {
            const int rb = w * 32 + i * 8;
            const size_t go = (size_t)i * 8 * K + kt;
            gload16(gAhi + go, lds + AHI_OFF + rb * 128);
            gload16(gAlo + go, lds + ALO_OFF + rb * 128);
            gload16(gWhi + go, lds + WHI_OFF + rb * 128);
            gload16(gWlo + go, lds + WLO_OFF + rb * 128);
        }
        __syncthreads();
#pragma unroll
        for (int h = 0; h < 2; ++h) {
            short8v afh[4], afl[4], wfh[4], wfl[4];
            const int ch = h * 4 + lk;
#pragma unroll
            for (int t = 0; t < 4; ++t) {
                const int ar = wr * 64 + t * 16 + lm;
                const int wrw = wc * 64 + t * 16 + lm;
                afh[t] = *(const short8v*)(lds + AHI_OFF + ar * 128 + ((ch ^ (ar & 7)) << 4));
                afl[t] = *(const short8v*)(lds + ALO_OFF + ar * 128 + ((ch ^ (ar & 7)) << 4));
                wfh[t] = *(const short8v*)(lds + WHI_OFF + wrw * 128 + ((ch ^ (wrw & 7)) << 4));
                wfl[t] = *(const short8v*)(lds + WLO_OFF + wrw * 128 + ((ch ^ (wrw & 7)) << 4));
            }
#pragma unroll
            for (int i = 0; i < 4; ++i)
#pragma unroll
                for (int j = 0; j < 4; ++j) {
                    acc[i][j] = __builtin_amdgcn_mfma_f32_16x16x32_bf16(afh[i], wfh[j], acc[i][j], 0, 0, 0);
                    acc[i][j] = __builtin_amdgcn_mfma_f32_16x16x32_bf16(afh[i], wfl[j], acc[i][j], 0, 0, 0);
                    acc[i][j] = __builtin_amdgcn_mfma_f32_16x16x32_bf16(afl[i], wfh[j], acc[i][j], 0, 0, 0);
                }
        }
        __syncthreads();
    }

#pragma unroll
    for (int i = 0; i < 4; ++i)
#pragma unroll
        for (int j = 0; j < 4; ++j)
#pragma unroll
            for (int r = 0; r < 4; ++r)
                C[(size_t)(m0 + wr * 64 + i * 16 + lk4 + r) * N + (n0 + wc * 64 + j * 16 + lm)] = acc[i][j][r];
}

// ---------------- causal depthwise conv(4) + bias + SiLU ----------------
__global__ __launch_bounds__(256) void conv_silu_k(
    const float* __restrict__ xz, const float* __restrict__ cw,
    const float* __restrict__ cb, float* __restrict__ xc)
{
    int idx = blockIdx.x * 256 + threadIdx.x;
    int d = idx & (DIN - 1);
    int l = (idx >> 11) & (SEQ - 1);
    int b = idx >> 22;
    float w0 = cw[d * 4 + 0], w1 = cw[d * 4 + 1], w2 = cw[d * 4 + 2], w3 = cw[d * 4 + 3];
    int rowb = b * SEQ + l;
    const float* col = xz + d;
    float acc = cb[d];
    if (l >= 3) acc = fmaf(col[(rowb - 3) * 4096], w0, acc);
    if (l >= 2) acc = fmaf(col[(rowb - 2) * 4096], w1, acc);
    if (l >= 1) acc = fmaf(col[(rowb - 1) * 4096], w2, acc);
    acc = fmaf(col[rowb * 4096], w3, acc);
    xc[rowb * DIN + d] = acc * sigf(acc);
}

// ---------------- xproj stage 1: partial x_dbl over K-split ----------------
__global__ __launch_bounds__(256) void xproj_part_k(
    const float* __restrict__ xc, const float* __restrict__ Wx, float* __restrict__ xzbuf)
{
    __shared__ float xs[64][68];
    __shared__ float wsh[96][68];
    const int tid = threadIdx.x;
    const int m0 = blockIdx.x * 64;
    const int ks = blockIdx.y;
    const int tx = tid & 15, rg = tid >> 4;
    float acc[4][6] = {};
    for (int k0 = ks * 256; k0 < ks * 256 + 256; k0 += 64) {
        for (int i = tid; i < 64 * 16; i += 256) {
            int r = i >> 4, c = i & 15;
            *(float4*)&xs[r][c * 4] = *(const float4*)&xc[(size_t)(m0 + r) * DIN + k0 + c * 4];
        }
        for (int i = tid; i < 96 * 16; i += 256) {
            int r = i >> 4, c = i & 15;
            *(float4*)&wsh[r][c * 4] = *(const float4*)&Wx[(size_t)r * DIN + k0 + c * 4];
        }
        __syncthreads();
#pragma unroll 2
        for (int c4 = 0; c4 < 16; ++c4) {
            float4 a[4];
#pragma unroll
            for (int i = 0; i < 4; ++i) a[i] = *(float4*)&xs[tx + i * 16][c4 * 4];
#pragma unroll
            for (int j = 0; j < 6; ++j) {
                float4 w = *(float4*)&wsh[rg * 6 + j][c4 * 4];
#pragma unroll
                for (int i = 0; i < 4; ++i) {
                    acc[i][j] = fmaf(a[i].x, w.x, acc[i][j]);
                    acc[i][j] = fmaf(a[i].y, w.y, acc[i][j]);
                    acc[i][j] = fmaf(a[i].z, w.z, acc[i][j]);
                    acc[i][j] = fmaf(a[i].w, w.w, acc[i][j]);
                }
            }
        }
        __syncthreads();
    }
#pragma unroll
    for (int i = 0; i < 4; ++i)
#pragma unroll
        for (int j = 0; j < 6; ++j) {
            size_t jj = (size_t)ks * (NROWS * 96) + (size_t)(m0 + tx + i * 16) * 96 + rg * 6 + j;
            *deadp2(xzbuf, jj) = acc[i][j];
        }
}

__global__ __launch_bounds__(256) void xproj_reduce_k(
    const float* __restrict__ xzbuf_c, float* __restrict__ xdbl)
{
    float* xzbuf = (float*)xzbuf_c;
    int i = blockIdx.x * 256 + threadIdx.x;
    if (i >= NROWS * 96) return;
    float s = 0.f;
#pragma unroll
    for (int ks = 0; ks < 8; ++ks)
        s += *deadp2(xzbuf, (size_t)ks * (NROWS * 96) + i);
    xdbl[i] = s;
}

// ---------------- dt = softplus(dt_low @ dt_proj_w^T + b) ----------------
__global__ __launch_bounds__(256) void dtproj_k(
    const float* __restrict__ xdbl, const float* __restrict__ Wd,
    const float* __restrict__ bd, float* __restrict__ dt)
{
    __shared__ float as_[128][68];
    __shared__ float ws_[64][68];
    const int tid = threadIdx.x;
    const int m0 = blockIdx.x * 128, n0 = blockIdx.y * 64;
    const int tx = tid & 15, ty = tid >> 4;
    for (int i = tid; i < 128 * 16; i += 256) {
        int r = i >> 4, c = i & 15;
        *(float4*)&as_[r][c * 4] = *(const float4*)&xdbl[(size_t)(m0 + r) * 96 + c * 4];
    }
    for (int i = tid; i < 64 * 16; i += 256) {
        int r = i >> 4, c = i & 15;
        *(float4*)&ws_[r][c * 4] = *(const float4*)&Wd[(size_t)(n0 + r) * 64 + c * 4];
    }
    __syncthreads();
    float acc[8][4] = {};
#pragma unroll 2
    for (int k4 = 0; k4 < 16; ++k4) {
        float4 av[8], wv[4];
#pragma unroll
        for (int i = 0; i < 8; ++i) av[i] = *(float4*)&as_[i * 16 + ty][k4 * 4];
#pragma unroll
        for (int j = 0; j < 4; ++j) wv[j] = *(float4*)&ws_[j * 16 + tx][k4 * 4];
#pragma unroll
        for (int i = 0; i < 8; ++i)
#pragma unroll
            for (int j = 0; j < 4; ++j) {
                acc[i][j] = fmaf(av[i].x, wv[j].x, acc[i][j]);
                acc[i][j] = fmaf(av[i].y, wv[j].y, acc[i][j]);
                acc[i][j] = fmaf(av[i].z, wv[j].z, acc[i][j]);
                acc[i][j] = fmaf(av[i].w, wv[j].w, acc[i][j]);
            }
    }
#pragma unroll
    for (int i = 0; i < 8; ++i)
#pragma unroll
        for (int j = 0; j < 4; ++j) {
            int m = m0 + i * 16 + ty, n = n0 + j * 16 + tx;
            float v = acc[i][j] + bd[n];
            v = (v > 20.0f) ? v : log1pf(__expf(v));
            dt[(size_t)m * DIN + n] = v;
        }
}

// ---------------- chunked selective scan: register-resident 16-state ----------------
// pass 1: one thread per (b,chunk,d); h[16],prod(dA)[16] in regs; B via scalar loads
__global__ __launch_bounds__(256) void scan_pass1(
    const float* __restrict__ dt, const float* __restrict__ xc,
    const float* __restrict__ xdbl, const float* __restrict__ Alog,
    float* __restrict__ xzbuf)
{
    const int b = blockIdx.z, c = blockIdx.y;
    const int d = blockIdx.x * 256 + threadIdx.x;
    float A[16];
#pragma unroll
    for (int q = 0; q < 4; ++q) *(float4*)&A[q * 4] = *(const float4*)&Alog[(size_t)d * 16 + q * 4];
#pragma unroll
    for (int n = 0; n < 16; ++n) A[n] = -__expf(A[n]);
    float h[16] = {}, ap[16];
#pragma unroll
    for (int n = 0; n < 16; ++n) ap[n] = 1.f;
    const int rowbase = b * SEQ + c * CHL;
    for (int t = 0; t < CHL; ++t) {
        const int row = rowbase + t;
        const float* xr = xdbl + (size_t)row * 96;   // wave-uniform -> scalar loads
        float dtv = dt[(size_t)row * DIN + d];
        float xcv = xc[(size_t)row * DIN + d];
        float u = dtv * xcv;
#pragma unroll
        for (int n = 0; n < 16; ++n) {
            float dA = __expf(dtv * A[n]);
            h[n] = fmaf(dA, h[n], u * xr[64 + n]);
            ap[n] *= dA;
        }
    }
    size_t e = ((size_t)(b * NCH + c) << 15) + (size_t)d * 16;
#pragma unroll
    for (int q = 0; q < 4; ++q) {
        *(float4*)deadp(xzbuf, e + q * 4)  = *(float4*)&h[q * 4];
        *(float4*)deadp2(xzbuf, e + q * 4) = *(float4*)&ap[q * 4];
    }
}

// pass 2: exclusive scan over chunks; one thread per (b,d,n)
__global__ __launch_bounds__(256) void scan_pass2(float* __restrict__ xzbuf)
{
    int idx = blockIdx.x * 256 + threadIdx.x;   // 65536
    int b = idx >> 15;
    int dn = idx & 32767;
    float carry = 0.f;
    for (int c = 0; c < NCH; ++c) {
        size_t e = ((size_t)(b * NCH + c) << 15) + dn;
        float* hp = deadp(xzbuf, e);
        float hl = *hp;
        float ap = *deadp2(xzbuf, e);
        *hp = carry;
        carry = fmaf(ap, carry, hl);
    }
}

// pass 3: re-scan from h_in, fused epilogue.  op aliases dt (per-element read-before-write).
__global__ __launch_bounds__(256) void scan_pass3(
    const float* __restrict__ dt, const float* __restrict__ xc,
    const float* __restrict__ xz, const float* __restrict__ xdbl,
    const float* __restrict__ Alog, const float* __restrict__ Dp,
    float* __restrict__ xzbuf, float* __restrict__ op)
{
    const int b = blockIdx.z, c = blockIdx.y;
    const int d = blockIdx.x * 256 + threadIdx.x;
    float A[16];
#pragma unroll
    for (int q = 0; q < 4; ++q) *(float4*)&A[q * 4] = *(const float4*)&Alog[(size_t)d * 16 + q * 4];
#pragma unroll
    for (int n = 0; n < 16; ++n) A[n] = -__expf(A[n]);
    float h[16];
    size_t e = ((size_t)(b * NCH + c) << 15) + (size_t)d * 16;
#pragma unroll
    for (int q = 0; q < 4; ++q) *(float4*)&h[q * 4] = *(float4*)deadp(xzbuf, e + q * 4);
    const float Dd = Dp[d];
    const int rowbase = b * SEQ + c * CHL;
    for (int t = 0; t < CHL; ++t) {
        const int row = rowbase + t;
        const float* xr = xdbl + (size_t)row * 96;   // wave-uniform -> scalar loads
        float dtv = dt[(size_t)row * DIN + d];
        float xcv = xc[(size_t)row * DIN + d];
        float zv  = xz[(size_t)row * 4096 + DIN + d];
        float u = dtv * xcv;
        float y = 0.f;
#pragma unroll
        for (int n = 0; n < 16; ++n) {
            float dA = __expf(dtv * A[n]);
            h[n] = fmaf(dA, h[n], u * xr[64 + n]);
            y = fmaf(h[n], xr[80 + n], y);
        }
        op[(size_t)row * DIN + d] = (y + xcv * Dd) * zv * sigf(zv);
    }
}

extern "C" void kernel_launch(void* const* d_in, const int* in_sizes, int n_in,
                              void* d_out, int out_size, void* d_ws, size_t ws_size,
                              hipStream_t stream)
{
    const float* x    = (const float*)d_in[0];
    const float* wi   = (const float*)d_in[1];
    const float* cw   = (const float*)d_in[2];
    const float* cb   = (const float*)d_in[3];
    const float* wx   = (const float*)d_in[4];
    const float* wd   = (const float*)d_in[5];
    const float* bd   = (const float*)d_in[6];
    const float* alog = (const float*)d_in[7];
    const float* Dp   = (const float*)d_in[8];
    const float* wo   = (const float*)d_in[9];
    float* out = (float*)d_out;

    float* wsf  = (float*)d_ws;
    float* xz   = wsf;                          // [4096][4096] f32
    float* xc   = xz + (size_t)NROWS * 4096;    // [4096][2048] f32
    float* xdbl = xc + (size_t)NROWS * DIN;     // [4096][96]
    float* dt   = xdbl + (size_t)NROWS * 96;    // [4096][2048] f32
    float* op   = dt;                           // alias

    unsigned short* xhi  = (unsigned short*)xc;
    unsigned short* xlo  = xhi + (size_t)4096 * 1024;
    unsigned short* wihi = (unsigned short*)dt;
    unsigned short* wilo = wihi + (size_t)4096 * 1024;
    unsigned short* ophi = (unsigned short*)xz;
    unsigned short* oplo = ophi + (size_t)4096 * 2048;
    unsigned short* wohi = oplo + (size_t)4096 * 2048;
    unsigned short* wolo = wohi + (size_t)1024 * 2048;

    // 1) split inputs of in_proj
    cvt_split_k<<<4096, 256, 0, stream>>>(x, xhi, xlo, 1048576);
    cvt_split_k<<<4096, 256, 0, stream>>>(wi, wihi, wilo, 1048576);
    // 2) xz = x @ in_proj_w^T
    gemm_mfma_split<<<1024, 256, 0, stream>>>(xhi, xlo, wihi, wilo, xz, 1024, 4096, 32);
    // 3) xc = silu(conv(xs)+b)
    conv_silu_k<<<32768, 256, 0, stream>>>(xz, cw, cb, xc);
    // 4) x_dbl: K-split partials then reduce
    xproj_part_k<<<dim3(64, 8), 256, 0, stream>>>(xc, wx, xz);
    xproj_reduce_k<<<1536, 256, 0, stream>>>(xz, xdbl);
    // 5) dt
    dtproj_k<<<dim3(32, 32), 256, 0, stream>>>(xdbl, wd, bd, dt);
    // 6) chunked scan (register-resident states)
    scan_pass1<<<dim3(8, NCH, 2), 256, 0, stream>>>(dt, xc, xdbl, alog, xz);
    scan_pass2<<<256, 256, 0, stream>>>(xz);
    scan_pass3<<<dim3(8, NCH, 2), 256, 0, stream>>>(dt, xc, xz, xdbl, alog, Dp, xz, op);
    // 7) split inputs of out_proj
    cvt_split_k<<<8192, 256, 0, stream>>>(op, ophi, oplo, 2097152);
    cvt_split_k<<<2048, 256, 0, stream>>>(wo, wohi, wolo, 524288);
    // 8) out = op @ out_proj_w^T
    gemm_mfma_split<<<256, 256, 0, stream>>>(ophi, oplo, wohi, wolo, out, 2048, 1024, 32);
}

// Round 6
// 372.810 us; speedup vs baseline: 4.2658x; 1.0221x over previous
//
#include <hip/hip_runtime.h>

#define SEQ    2048
#define DIN    2048
#define DMODEL 1024
#define NROWS  4096   // BATCH*SEQ
#define NCH    64     // scan chunks
#define CHL    32     // chunk length

typedef __attribute__((ext_vector_type(8))) short short8v;
typedef __attribute__((ext_vector_type(4))) float f32x4;

__device__ __forceinline__ float sigf(float x) { return 1.0f / (1.0f + __expf(-x)); }

// dead xs-half of xz (rows 0..2047, cols 0..2047): holds h chunk states
__device__ __forceinline__ float* deadp(float* xzbuf, size_t j) {
    return xzbuf + ((j >> 11) << 12) + (j & 2047);
}
// second dead window (rows 2048..4095, cols 0..2047): xproj partials, then prod(dA)
__device__ __forceinline__ float* deadp2(float* xzbuf, size_t j) {
    return xzbuf + ((size_t)(2048 + (j >> 11)) << 12) + (j & 2047);
}

__device__ __forceinline__ void gload16(const void* g, const void* l) {
    __builtin_amdgcn_global_load_lds((const __attribute__((address_space(1))) void*)g,
                                     (__attribute__((address_space(3))) void*)l, 16, 0, 0);
}

// ---------------- fp32 -> bf16 hi/lo split (RNE both) ----------------
__device__ __forceinline__ void split1(float x, unsigned short& h, unsigned short& l) {
    unsigned u = __float_as_uint(x);
    unsigned hb = (u + 0x7FFFu + ((u >> 16) & 1u)) >> 16;
    float hf = __uint_as_float(hb << 16);
    float r = x - hf;
    unsigned u2 = __float_as_uint(r);
    unsigned lb = (u2 + 0x7FFFu + ((u2 >> 16) & 1u)) >> 16;
    h = (unsigned short)hb; l = (unsigned short)lb;
}

__global__ __launch_bounds__(256) void cvt_split_k(
    const float* __restrict__ in, unsigned short* __restrict__ hi,
    unsigned short* __restrict__ lo, int n4)
{
    int i = blockIdx.x * 256 + threadIdx.x;
    if (i >= n4) return;
    float4 v = ((const float4*)in)[i];
    ushort4 h, l;
    split1(v.x, h.x, l.x);
    split1(v.y, h.y, l.y);
    split1(v.z, h.z, l.z);
    split1(v.w, h.w, l.w);
    ((ushort4*)hi)[i] = h;
    ((ushort4*)lo)[i] = l;
}

// strided variant: src rows of srcld floats (take first ncol4*4), dst rows of dstld ushorts
__global__ __launch_bounds__(256) void cvt_split_strided_k(
    const float* __restrict__ src, int srcld,
    unsigned short* __restrict__ hi, unsigned short* __restrict__ lo,
    int dstld, int ncol4, int total4)
{
    int i = blockIdx.x * 256 + threadIdx.x;
    if (i >= total4) return;
    int row = i / ncol4, q = i - row * ncol4;
    float4 v = *(const float4*)(src + (size_t)row * srcld + q * 4);
    ushort4 h, l;
    split1(v.x, h.x, l.x);
    split1(v.y, h.y, l.y);
    split1(v.z, h.z, l.z);
    split1(v.w, h.w, l.w);
    *(ushort4*)(hi + (size_t)row * dstld + q * 4) = h;
    *(ushort4*)(lo + (size_t)row * dstld + q * 4) = l;
}

// ---------------- split-bf16 MFMA GEMM: C = (Ahi+Alo).(Whi+Wlo)^T [+bias, softplus] ----
// A*: [M][lda] bf16 (first K cols), W*: [N][ldw], C: [M][N] f32. Tile 128x128, BK=64.
#define AHI_OFF 0
#define ALO_OFF 16384
#define WHI_OFF 32768
#define WLO_OFF 49152

__global__ __launch_bounds__(256) void gemm_mfma_split(
    const unsigned short* __restrict__ Ahi, const unsigned short* __restrict__ Alo,
    const unsigned short* __restrict__ Whi, const unsigned short* __restrict__ Wlo,
    float* __restrict__ C, int K, int N, int mtiles, int lda, int ldw,
    const float* __restrict__ bias)
{
    __shared__ uint4 ldsu4[4096];
    char* lds = (char*)ldsu4;
    const int tid  = threadIdx.x;
    const int w    = tid >> 6, lane = tid & 63;

    const int nwg = gridDim.x;
    const int cpx = nwg >> 3;
    const int bid = blockIdx.x;
    const int swz = (bid & 7) * cpx + (bid >> 3);
    const int m0 = (swz % mtiles) * 128;
    const int n0 = (swz / mtiles) * 128;

    const int wr = w >> 1, wc = w & 1;

    f32x4 acc[4][4];
#pragma unroll
    for (int i = 0; i < 4; ++i)
#pragma unroll
        for (int j = 0; j < 4; ++j) { acc[i][j][0]=0.f; acc[i][j][1]=0.f; acc[i][j][2]=0.f; acc[i][j][3]=0.f; }

    const int rloc = w * 32 + (lane >> 3);
    const int xr8  = ((lane & 7) ^ (lane >> 3)) << 3;
    const unsigned short* gAhi = Ahi + (size_t)(m0 + rloc) * lda + xr8;
    const unsigned short* gAlo = Alo + (size_t)(m0 + rloc) * lda + xr8;
    const unsigned short* gWhi = Whi + (size_t)(n0 + rloc) * ldw + xr8;
    const unsigned short* gWlo = Wlo + (size_t)(n0 + rloc) * ldw + xr8;

    const int lm  = lane & 15;
    const int lk  = lane >> 4;
    const int lk4 = lk * 4;

    for (int kt = 0; kt < K; kt += 64) {
#pragma unroll
        for (int i = 0; i < 4; ++i) {
            const int rb = w * 32 + i * 8;
            const size_t goA = (size_t)i * 8 * lda + kt;
            const size_t goW = (size_t)i * 8 * ldw + kt;
            gload16(gAhi + goA, lds + AHI_OFF + rb * 128);
            gload16(gAlo + goA, lds + ALO_OFF + rb * 128);
            gload16(gWhi + goW, lds + WHI_OFF + rb * 128);
            gload16(gWlo + goW, lds + WLO_OFF + rb * 128);
        }
        __syncthreads();
#pragma unroll
        for (int h = 0; h < 2; ++h) {
            short8v afh[4], afl[4], wfh[4], wfl[4];
            const int ch = h * 4 + lk;
#pragma unroll
            for (int t = 0; t < 4; ++t) {
                const int ar = wr * 64 + t * 16 + lm;
                const int wrw = wc * 64 + t * 16 + lm;
                afh[t] = *(const short8v*)(lds + AHI_OFF + ar * 128 + ((ch ^ (ar & 7)) << 4));
                afl[t] = *(const short8v*)(lds + ALO_OFF + ar * 128 + ((ch ^ (ar & 7)) << 4));
                wfh[t] = *(const short8v*)(lds + WHI_OFF + wrw * 128 + ((ch ^ (wrw & 7)) << 4));
                wfl[t] = *(const short8v*)(lds + WLO_OFF + wrw * 128 + ((ch ^ (wrw & 7)) << 4));
            }
#pragma unroll
            for (int i = 0; i < 4; ++i)
#pragma unroll
                for (int j = 0; j < 4; ++j) {
                    acc[i][j] = __builtin_amdgcn_mfma_f32_16x16x32_bf16(afh[i], wfh[j], acc[i][j], 0, 0, 0);
                    acc[i][j] = __builtin_amdgcn_mfma_f32_16x16x32_bf16(afh[i], wfl[j], acc[i][j], 0, 0, 0);
                    acc[i][j] = __builtin_amdgcn_mfma_f32_16x16x32_bf16(afl[i], wfh[j], acc[i][j], 0, 0, 0);
                }
        }
        __syncthreads();
    }

    if (bias) {
#pragma unroll
        for (int j = 0; j < 4; ++j) {
            const int n = n0 + wc * 64 + j * 16 + lm;
            const float bv = bias[n];
#pragma unroll
            for (int i = 0; i < 4; ++i)
#pragma unroll
                for (int r = 0; r < 4; ++r) {
                    float v = acc[i][j][r] + bv;
                    v = (v > 20.0f) ? v : log1pf(__expf(v));
                    C[(size_t)(m0 + wr * 64 + i * 16 + lk4 + r) * N + n] = v;
                }
        }
    } else {
#pragma unroll
        for (int i = 0; i < 4; ++i)
#pragma unroll
            for (int j = 0; j < 4; ++j)
#pragma unroll
                for (int r = 0; r < 4; ++r)
                    C[(size_t)(m0 + wr * 64 + i * 16 + lk4 + r) * N + (n0 + wc * 64 + j * 16 + lm)] = acc[i][j][r];
    }
}

// ---------------- causal depthwise conv(4) + bias + SiLU ----------------
__global__ __launch_bounds__(256) void conv_silu_k(
    const float* __restrict__ xz, const float* __restrict__ cw,
    const float* __restrict__ cb, float* __restrict__ xc)
{
    int idx = blockIdx.x * 256 + threadIdx.x;
    int d = idx & (DIN - 1);
    int l = (idx >> 11) & (SEQ - 1);
    int b = idx >> 22;
    float w0 = cw[d * 4 + 0], w1 = cw[d * 4 + 1], w2 = cw[d * 4 + 2], w3 = cw[d * 4 + 3];
    int rowb = b * SEQ + l;
    const float* col = xz + d;
    float acc = cb[d];
    if (l >= 3) acc = fmaf(col[(rowb - 3) * 4096], w0, acc);
    if (l >= 2) acc = fmaf(col[(rowb - 2) * 4096], w1, acc);
    if (l >= 1) acc = fmaf(col[(rowb - 1) * 4096], w2, acc);
    acc = fmaf(col[rowb * 4096], w3, acc);
    xc[rowb * DIN + d] = acc * sigf(acc);
}

// ---------------- xproj stage 1: partial x_dbl over K-split ----------------
__global__ __launch_bounds__(256) void xproj_part_k(
    const float* __restrict__ xc, const float* __restrict__ Wx, float* __restrict__ xzbuf)
{
    __shared__ float xs[64][68];
    __shared__ float wsh[96][68];
    const int tid = threadIdx.x;
    const int m0 = blockIdx.x * 64;
    const int ks = blockIdx.y;
    const int tx = tid & 15, rg = tid >> 4;
    float acc[4][6] = {};
    for (int k0 = ks * 256; k0 < ks * 256 + 256; k0 += 64) {
        for (int i = tid; i < 64 * 16; i += 256) {
            int r = i >> 4, c = i & 15;
            *(float4*)&xs[r][c * 4] = *(const float4*)&xc[(size_t)(m0 + r) * DIN + k0 + c * 4];
        }
        for (int i = tid; i < 96 * 16; i += 256) {
            int r = i >> 4, c = i & 15;
            *(float4*)&wsh[r][c * 4] = *(const float4*)&Wx[(size_t)r * DIN + k0 + c * 4];
        }
        __syncthreads();
#pragma unroll 2
        for (int c4 = 0; c4 < 16; ++c4) {
            float4 a[4];
#pragma unroll
            for (int i = 0; i < 4; ++i) a[i] = *(float4*)&xs[tx + i * 16][c4 * 4];
#pragma unroll
            for (int j = 0; j < 6; ++j) {
                float4 w = *(float4*)&wsh[rg * 6 + j][c4 * 4];
#pragma unroll
                for (int i = 0; i < 4; ++i) {
                    acc[i][j] = fmaf(a[i].x, w.x, acc[i][j]);
                    acc[i][j] = fmaf(a[i].y, w.y, acc[i][j]);
                    acc[i][j] = fmaf(a[i].z, w.z, acc[i][j]);
                    acc[i][j] = fmaf(a[i].w, w.w, acc[i][j]);
                }
            }
        }
        __syncthreads();
    }
#pragma unroll
    for (int i = 0; i < 4; ++i)
#pragma unroll
        for (int j = 0; j < 6; ++j) {
            size_t jj = (size_t)ks * (NROWS * 96) + (size_t)(m0 + tx + i * 16) * 96 + rg * 6 + j;
            *deadp2(xzbuf, jj) = acc[i][j];
        }
}

__global__ __launch_bounds__(256) void xproj_reduce_k(
    const float* __restrict__ xzbuf_c, float* __restrict__ xdbl)
{
    float* xzbuf = (float*)xzbuf_c;
    int i = blockIdx.x * 256 + threadIdx.x;
    if (i >= NROWS * 96) return;
    float s = 0.f;
#pragma unroll
    for (int ks = 0; ks < 8; ++ks)
        s += *deadp2(xzbuf, (size_t)ks * (NROWS * 96) + i);
    xdbl[i] = s;
}

// ---------------- chunked selective scan: register-resident 16-state ----------------
__global__ __launch_bounds__(256) void scan_pass1(
    const float* __restrict__ dt, const float* __restrict__ xc,
    const float* __restrict__ xdbl, const float* __restrict__ Alog,
    float* __restrict__ xzbuf)
{
    const int b = blockIdx.z, c = blockIdx.y;
    const int d = blockIdx.x * 256 + threadIdx.x;
    float A[16];
#pragma unroll
    for (int q = 0; q < 4; ++q) *(float4*)&A[q * 4] = *(const float4*)&Alog[(size_t)d * 16 + q * 4];
#pragma unroll
    for (int n = 0; n < 16; ++n) A[n] = -__expf(A[n]);
    float h[16] = {}, ap[16];
#pragma unroll
    for (int n = 0; n < 16; ++n) ap[n] = 1.f;
    const int rowbase = b * SEQ + c * CHL;
    for (int t = 0; t < CHL; ++t) {
        const int row = rowbase + t;
        const float* xr = xdbl + (size_t)row * 96;
        float dtv = dt[(size_t)row * DIN + d];
        float xcv = xc[(size_t)row * DIN + d];
        float u = dtv * xcv;
#pragma unroll
        for (int n = 0; n < 16; ++n) {
            float dA = __expf(dtv * A[n]);
            h[n] = fmaf(dA, h[n], u * xr[64 + n]);
            ap[n] *= dA;
        }
    }
    size_t e = ((size_t)(b * NCH + c) << 15) + (size_t)d * 16;
#pragma unroll
    for (int q = 0; q < 4; ++q) {
        *(float4*)deadp(xzbuf, e + q * 4)  = *(float4*)&h[q * 4];
        *(float4*)deadp2(xzbuf, e + q * 4) = *(float4*)&ap[q * 4];
    }
}

__global__ __launch_bounds__(256) void scan_pass2(float* __restrict__ xzbuf)
{
    int idx = blockIdx.x * 256 + threadIdx.x;
    int b = idx >> 15;
    int dn = idx & 32767;
    float carry = 0.f;
    for (int c = 0; c < NCH; ++c) {
        size_t e = ((size_t)(b * NCH + c) << 15) + dn;
        float* hp = deadp(xzbuf, e);
        float hl = *hp;
        float ap = *deadp2(xzbuf, e);
        *hp = carry;
        carry = fmaf(ap, carry, hl);
    }
}

__global__ __launch_bounds__(256) void scan_pass3(
    const float* __restrict__ dt, const float* __restrict__ xc,
    const float* __restrict__ xz, const float* __restrict__ xdbl,
    const float* __restrict__ Alog, const float* __restrict__ Dp,
    float* __restrict__ xzbuf, float* __restrict__ op)
{
    const int b = blockIdx.z, c = blockIdx.y;
    const int d = blockIdx.x * 256 + threadIdx.x;
    float A[16];
#pragma unroll
    for (int q = 0; q < 4; ++q) *(float4*)&A[q * 4] = *(const float4*)&Alog[(size_t)d * 16 + q * 4];
#pragma unroll
    for (int n = 0; n < 16; ++n) A[n] = -__expf(A[n]);
    float h[16];
    size_t e = ((size_t)(b * NCH + c) << 15) + (size_t)d * 16;
#pragma unroll
    for (int q = 0; q < 4; ++q) *(float4*)&h[q * 4] = *(float4*)deadp(xzbuf, e + q * 4);
    const float Dd = Dp[d];
    const int rowbase = b * SEQ + c * CHL;
    for (int t = 0; t < CHL; ++t) {
        const int row = rowbase + t;
        const float* xr = xdbl + (size_t)row * 96;
        float dtv = dt[(size_t)row * DIN + d];
        float xcv = xc[(size_t)row * DIN + d];
        float zv  = xz[(size_t)row * 4096 + DIN + d];
        float u = dtv * xcv;
        float y = 0.f;
#pragma unroll
        for (int n = 0; n < 16; ++n) {
            float dA = __expf(dtv * A[n]);
            h[n] = fmaf(dA, h[n], u * xr[64 + n]);
            y = fmaf(h[n], xr[80 + n], y);
        }
        op[(size_t)row * DIN + d] = (y + xcv * Dd) * zv * sigf(zv);
    }
}

extern "C" void kernel_launch(void* const* d_in, const int* in_sizes, int n_in,
                              void* d_out, int out_size, void* d_ws, size_t ws_size,
                              hipStream_t stream)
{
    const float* x    = (const float*)d_in[0];
    const float* wi   = (const float*)d_in[1];
    const float* cw   = (const float*)d_in[2];
    const float* cb   = (const float*)d_in[3];
    const float* wx   = (const float*)d_in[4];
    const float* wd   = (const float*)d_in[5];
    const float* bd   = (const float*)d_in[6];
    const float* alog = (const float*)d_in[7];
    const float* Dp   = (const float*)d_in[8];
    const float* wo   = (const float*)d_in[9];
    float* out = (float*)d_out;

    float* wsf  = (float*)d_ws;
    float* xz   = wsf;                          // [4096][4096] f32
    float* xc   = xz + (size_t)NROWS * 4096;    // [4096][2048] f32
    float* xdbl = xc + (size_t)NROWS * DIN;     // [4096][96]
    float* dt   = xdbl + (size_t)NROWS * 96;    // [4096][2048] f32
    float* op   = dt;                           // alias

    unsigned short* xhi  = (unsigned short*)xc;
    unsigned short* xlo  = xhi + (size_t)4096 * 1024;
    unsigned short* wihi = (unsigned short*)dt;
    unsigned short* wilo = wihi + (size_t)4096 * 1024;
    unsigned short* ophi = (unsigned short*)xz;
    unsigned short* oplo = ophi + (size_t)4096 * 2048;
    unsigned short* wohi = oplo + (size_t)4096 * 2048;
    unsigned short* wolo = wohi + (size_t)1024 * 2048;

    // dtproj split operands live in dead xs-cols of xz (ushort cols 0..255 of each row;
    // z is at ushort cols >= 4096; scan_pass1/2 overwrite this region only after dtproj)
    unsigned short* xzU   = (unsigned short*)xz;
    unsigned short* dlhi  = xzU + 0;     // [4096 rows][64], stride 8192
    unsigned short* dllo  = xzU + 64;
    unsigned short* wdhi  = xzU + 128;   // [2048 rows][64], stride 8192
    unsigned short* wdlo  = xzU + 192;

    // 1) split inputs of in_proj
    cvt_split_k<<<4096, 256, 0, stream>>>(x, xhi, xlo, 1048576);
    cvt_split_k<<<4096, 256, 0, stream>>>(wi, wihi, wilo, 1048576);
    // 2) xz = x @ in_proj_w^T
    gemm_mfma_split<<<1024, 256, 0, stream>>>(xhi, xlo, wihi, wilo, xz, 1024, 4096, 32,
                                              1024, 1024, nullptr);
    // 3) xc = silu(conv(xs)+b)
    conv_silu_k<<<32768, 256, 0, stream>>>(xz, cw, cb, xc);
    // 4) x_dbl: K-split partials then reduce
    xproj_part_k<<<dim3(64, 8), 256, 0, stream>>>(xc, wx, xz);
    xproj_reduce_k<<<1536, 256, 0, stream>>>(xz, xdbl);
    // 5) dt = softplus(dt_low @ Wd^T + bd) on the MFMA pipe
    cvt_split_strided_k<<<256, 256, 0, stream>>>(xdbl, 96, dlhi, dllo, 8192, 16, 65536);
    cvt_split_strided_k<<<128, 256, 0, stream>>>(wd, 64, wdhi, wdlo, 8192, 16, 32768);
    gemm_mfma_split<<<512, 256, 0, stream>>>(dlhi, dllo, wdhi, wdlo, dt, 64, 2048, 32,
                                             8192, 8192, bd);
    // 6) chunked scan (register-resident states)
    scan_pass1<<<dim3(8, NCH, 2), 256, 0, stream>>>(dt, xc, xdbl, alog, xz);
    scan_pass2<<<256, 256, 0, stream>>>(xz);
    scan_pass3<<<dim3(8, NCH, 2), 256, 0, stream>>>(dt, xc, xz, xdbl, alog, Dp, xz, op);
    // 7) split inputs of out_proj
    cvt_split_k<<<8192, 256, 0, stream>>>(op, ophi, oplo, 2097152);
    cvt_split_k<<<2048, 256, 0, stream>>>(wo, wohi, wolo, 524288);
    // 8) out = op @ out_proj_w^T
    gemm_mfma_split<<<256, 256, 0, stream>>>(ophi, oplo, wohi, wolo, out, 2048, 1024, 32,
                                             2048, 2048, nullptr);
}

// Round 7
// 344.594 us; speedup vs baseline: 4.6151x; 1.0819x over previous
//
#include <hip/hip_runtime.h>

#define SEQ    2048
#define DIN    2048
#define DMODEL 1024
#define NROWS  4096   // BATCH*SEQ
#define NCH    64     // scan chunks
#define CHL    32     // chunk length

typedef __attribute__((ext_vector_type(8))) short short8v;
typedef __attribute__((ext_vector_type(4))) float f32x4;

__device__ __forceinline__ float sigf(float x) { return 1.0f / (1.0f + __expf(-x)); }
// inline softplus: no libm call (log1pf is a non-inlined OCML slow path — 100 µs pathology)
__device__ __forceinline__ float softplusf(float v) {
    return fmaxf(v, 0.f) + __logf(1.f + __expf(-fabsf(v)));
}

// dead xs-half of xz (rows 0..2047, cols 0..2047): holds h chunk states
__device__ __forceinline__ float* deadp(float* xzbuf, size_t j) {
    return xzbuf + ((j >> 11) << 12) + (j & 2047);
}
// second dead window (rows 2048..4095, cols 0..2047): xproj partials, then prod(dA)
__device__ __forceinline__ float* deadp2(float* xzbuf, size_t j) {
    return xzbuf + ((size_t)(2048 + (j >> 11)) << 12) + (j & 2047);
}

__device__ __forceinline__ void gload16(const void* g, const void* l) {
    __builtin_amdgcn_global_load_lds((const __attribute__((address_space(1))) void*)g,
                                     (__attribute__((address_space(3))) void*)l, 16, 0, 0);
}

// ---------------- fp32 -> bf16 hi/lo split (RNE both) ----------------
__device__ __forceinline__ void split1(float x, unsigned short& h, unsigned short& l) {
    unsigned u = __float_as_uint(x);
    unsigned hb = (u + 0x7FFFu + ((u >> 16) & 1u)) >> 16;
    float hf = __uint_as_float(hb << 16);
    float r = x - hf;
    unsigned u2 = __float_as_uint(r);
    unsigned lb = (u2 + 0x7FFFu + ((u2 >> 16) & 1u)) >> 16;
    h = (unsigned short)hb; l = (unsigned short)lb;
}

__global__ __launch_bounds__(256) void cvt_split_k(
    const float* __restrict__ in, unsigned short* __restrict__ hi,
    unsigned short* __restrict__ lo, int n4)
{
    int i = blockIdx.x * 256 + threadIdx.x;
    if (i >= n4) return;
    float4 v = ((const float4*)in)[i];
    ushort4 h, l;
    split1(v.x, h.x, l.x);
    split1(v.y, h.y, l.y);
    split1(v.z, h.z, l.z);
    split1(v.w, h.w, l.w);
    ((ushort4*)hi)[i] = h;
    ((ushort4*)lo)[i] = l;
}

// strided variant: src rows of srcld floats (take first ncol4*4), dst rows of dstld ushorts
__global__ __launch_bounds__(256) void cvt_split_strided_k(
    const float* __restrict__ src, int srcld,
    unsigned short* __restrict__ hi, unsigned short* __restrict__ lo,
    int dstld, int ncol4, int total4)
{
    int i = blockIdx.x * 256 + threadIdx.x;
    if (i >= total4) return;
    int row = i / ncol4, q = i - row * ncol4;
    float4 v = *(const float4*)(src + (size_t)row * srcld + q * 4);
    ushort4 h, l;
    split1(v.x, h.x, l.x);
    split1(v.y, h.y, l.y);
    split1(v.z, h.z, l.z);
    split1(v.w, h.w, l.w);
    *(ushort4*)(hi + (size_t)row * dstld + q * 4) = h;
    *(ushort4*)(lo + (size_t)row * dstld + q * 4) = l;
}

// ---------------- split-bf16 MFMA GEMM: C = (Ahi+Alo).(Whi+Wlo)^T [+bias, softplus] ----
// A*: [M][lda] bf16 (first K cols), W*: [N][ldw], C: [M][N] f32. Tile 128x128, BK=64.
// Requires mtiles % 8 == 0 and gridDim.x % 8 == 0.
#define AHI_OFF 0
#define ALO_OFF 16384
#define WHI_OFF 32768
#define WLO_OFF 49152

__global__ __launch_bounds__(256) void gemm_mfma_split(
    const unsigned short* __restrict__ Ahi, const unsigned short* __restrict__ Alo,
    const unsigned short* __restrict__ Whi, const unsigned short* __restrict__ Wlo,
    float* __restrict__ C, int K, int N, int mtiles, int lda, int ldw,
    const float* __restrict__ bias)
{
    __shared__ uint4 ldsu4[4096];
    char* lds = (char*)ldsu4;
    const int tid  = threadIdx.x;
    const int w    = tid >> 6, lane = tid & 63;

    // XCD-aware chunking, then GROUP_M=8 supertiles for L2 locality
    const int nwg = gridDim.x;
    const int cpx = nwg >> 3;
    const int bid = blockIdx.x;
    const int swz = (bid & 7) * cpx + (bid >> 3);
    const int ntiles = nwg / mtiles;
    const int per = 8 * ntiles;
    const int gid = swz / per;
    const int rem = swz - gid * per;
    const int m0 = (gid * 8 + (rem & 7)) * 128;
    const int n0 = (rem >> 3) * 128;

    const int wr = w >> 1, wc = w & 1;

    f32x4 acc[4][4];
#pragma unroll
    for (int i = 0; i < 4; ++i)
#pragma unroll
        for (int j = 0; j < 4; ++j) { acc[i][j][0]=0.f; acc[i][j][1]=0.f; acc[i][j][2]=0.f; acc[i][j][3]=0.f; }

    const int rloc = w * 32 + (lane >> 3);
    const int xr8  = ((lane & 7) ^ (lane >> 3)) << 3;
    const unsigned short* gAhi = Ahi + (size_t)(m0 + rloc) * lda + xr8;
    const unsigned short* gAlo = Alo + (size_t)(m0 + rloc) * lda + xr8;
    const unsigned short* gWhi = Whi + (size_t)(n0 + rloc) * ldw + xr8;
    const unsigned short* gWlo = Wlo + (size_t)(n0 + rloc) * ldw + xr8;

    const int lm  = lane & 15;
    const int lk  = lane >> 4;
    const int lk4 = lk * 4;

    for (int kt = 0; kt < K; kt += 64) {
#pragma unroll
        for (int i = 0; i < 4; ++i) {
            const int rb = w * 32 + i * 8;
            const size_t goA = (size_t)i * 8 * lda + kt;
            const size_t goW = (size_t)i * 8 * ldw + kt;
            gload16(gAhi + goA, lds + AHI_OFF + rb * 128);
            gload16(gAlo + goA, lds + ALO_OFF + rb * 128);
            gload16(gWhi + goW, lds + WHI_OFF + rb * 128);
            gload16(gWlo + goW, lds + WLO_OFF + rb * 128);
        }
        __syncthreads();
#pragma unroll
        for (int h = 0; h < 2; ++h) {
            short8v afh[4], afl[4], wfh[4], wfl[4];
            const int ch = h * 4 + lk;
#pragma unroll
            for (int t = 0; t < 4; ++t) {
                const int ar = wr * 64 + t * 16 + lm;
                const int wrw = wc * 64 + t * 16 + lm;
                afh[t] = *(const short8v*)(lds + AHI_OFF + ar * 128 + ((ch ^ (ar & 7)) << 4));
                afl[t] = *(const short8v*)(lds + ALO_OFF + ar * 128 + ((ch ^ (ar & 7)) << 4));
                wfh[t] = *(const short8v*)(lds + WHI_OFF + wrw * 128 + ((ch ^ (wrw & 7)) << 4));
                wfl[t] = *(const short8v*)(lds + WLO_OFF + wrw * 128 + ((ch ^ (wrw & 7)) << 4));
            }
#pragma unroll
            for (int i = 0; i < 4; ++i)
#pragma unroll
                for (int j = 0; j < 4; ++j) {
                    acc[i][j] = __builtin_amdgcn_mfma_f32_16x16x32_bf16(afh[i], wfh[j], acc[i][j], 0, 0, 0);
                    acc[i][j] = __builtin_amdgcn_mfma_f32_16x16x32_bf16(afh[i], wfl[j], acc[i][j], 0, 0, 0);
                    acc[i][j] = __builtin_amdgcn_mfma_f32_16x16x32_bf16(afl[i], wfh[j], acc[i][j], 0, 0, 0);
                }
        }
        __syncthreads();
    }

    if (bias) {
#pragma unroll
        for (int j = 0; j < 4; ++j) {
            const int n = n0 + wc * 64 + j * 16 + lm;
            const float bv = bias[n];
#pragma unroll
            for (int i = 0; i < 4; ++i)
#pragma unroll
                for (int r = 0; r < 4; ++r) {
                    float v = acc[i][j][r] + bv;
                    C[(size_t)(m0 + wr * 64 + i * 16 + lk4 + r) * N + n] = softplusf(v);
                }
        }
    } else {
#pragma unroll
        for (int i = 0; i < 4; ++i)
#pragma unroll
            for (int j = 0; j < 4; ++j)
#pragma unroll
                for (int r = 0; r < 4; ++r)
                    C[(size_t)(m0 + wr * 64 + i * 16 + lk4 + r) * N + (n0 + wc * 64 + j * 16 + lm)] = acc[i][j][r];
    }
}

// ---------------- causal depthwise conv(4) + bias + SiLU ----------------
__global__ __launch_bounds__(256) void conv_silu_k(
    const float* __restrict__ xz, const float* __restrict__ cw,
    const float* __restrict__ cb, float* __restrict__ xc)
{
    int idx = blockIdx.x * 256 + threadIdx.x;
    int d = idx & (DIN - 1);
    int l = (idx >> 11) & (SEQ - 1);
    int b = idx >> 22;
    float w0 = cw[d * 4 + 0], w1 = cw[d * 4 + 1], w2 = cw[d * 4 + 2], w3 = cw[d * 4 + 3];
    int rowb = b * SEQ + l;
    const float* col = xz + d;
    float acc = cb[d];
    if (l >= 3) acc = fmaf(col[(rowb - 3) * 4096], w0, acc);
    if (l >= 2) acc = fmaf(col[(rowb - 2) * 4096], w1, acc);
    if (l >= 1) acc = fmaf(col[(rowb - 1) * 4096], w2, acc);
    acc = fmaf(col[rowb * 4096], w3, acc);
    xc[rowb * DIN + d] = acc * sigf(acc);
}

// ---------------- xproj stage 1: partial x_dbl over K-split ----------------
__global__ __launch_bounds__(256) void xproj_part_k(
    const float* __restrict__ xc, const float* __restrict__ Wx, float* __restrict__ xzbuf)
{
    __shared__ float xs[64][68];
    __shared__ float wsh[96][68];
    const int tid = threadIdx.x;
    const int m0 = blockIdx.x * 64;
    const int ks = blockIdx.y;
    const int tx = tid & 15, rg = tid >> 4;
    float acc[4][6] = {};
    for (int k0 = ks * 256; k0 < ks * 256 + 256; k0 += 64) {
        for (int i = tid; i < 64 * 16; i += 256) {
            int r = i >> 4, c = i & 15;
            *(float4*)&xs[r][c * 4] = *(const float4*)&xc[(size_t)(m0 + r) * DIN + k0 + c * 4];
        }
        for (int i = tid; i < 96 * 16; i += 256) {
            int r = i >> 4, c = i & 15;
            *(float4*)&wsh[r][c * 4] = *(const float4*)&Wx[(size_t)r * DIN + k0 + c * 4];
        }
        __syncthreads();
#pragma unroll 2
        for (int c4 = 0; c4 < 16; ++c4) {
            float4 a[4];
#pragma unroll
            for (int i = 0; i < 4; ++i) a[i] = *(float4*)&xs[tx + i * 16][c4 * 4];
#pragma unroll
            for (int j = 0; j < 6; ++j) {
                float4 w = *(float4*)&wsh[rg * 6 + j][c4 * 4];
#pragma unroll
                for (int i = 0; i < 4; ++i) {
                    acc[i][j] = fmaf(a[i].x, w.x, acc[i][j]);
                    acc[i][j] = fmaf(a[i].y, w.y, acc[i][j]);
                    acc[i][j] = fmaf(a[i].z, w.z, acc[i][j]);
                    acc[i][j] = fmaf(a[i].w, w.w, acc[i][j]);
                }
            }
        }
        __syncthreads();
    }
#pragma unroll
    for (int i = 0; i < 4; ++i)
#pragma unroll
        for (int j = 0; j < 6; ++j) {
            size_t jj = (size_t)ks * (NROWS * 96) + (size_t)(m0 + tx + i * 16) * 96 + rg * 6 + j;
            *deadp2(xzbuf, jj) = acc[i][j];
        }
}

__global__ __launch_bounds__(256) void xproj_reduce_k(
    const float* __restrict__ xzbuf_c, float* __restrict__ xdbl)
{
    float* xzbuf = (float*)xzbuf_c;
    int i = blockIdx.x * 256 + threadIdx.x;
    if (i >= NROWS * 96) return;
    float s = 0.f;
#pragma unroll
    for (int ks = 0; ks < 8; ++ks)
        s += *deadp2(xzbuf, (size_t)ks * (NROWS * 96) + i);
    xdbl[i] = s;
}

// ---------------- chunked selective scan: register-resident 16-state ----------------
__global__ __launch_bounds__(256) void scan_pass1(
    const float* __restrict__ dt, const float* __restrict__ xc,
    const float* __restrict__ xdbl, const float* __restrict__ Alog,
    float* __restrict__ xzbuf)
{
    const int b = blockIdx.z, c = blockIdx.y;
    const int d = blockIdx.x * 256 + threadIdx.x;
    float A[16];
#pragma unroll
    for (int q = 0; q < 4; ++q) *(float4*)&A[q * 4] = *(const float4*)&Alog[(size_t)d * 16 + q * 4];
#pragma unroll
    for (int n = 0; n < 16; ++n) A[n] = -__expf(A[n]);
    float h[16] = {}, ap[16];
#pragma unroll
    for (int n = 0; n < 16; ++n) ap[n] = 1.f;
    const int rowbase = b * SEQ + c * CHL;
    for (int t = 0; t < CHL; ++t) {
        const int row = rowbase + t;
        const float* xr = xdbl + (size_t)row * 96;
        float dtv = dt[(size_t)row * DIN + d];
        float xcv = xc[(size_t)row * DIN + d];
        float u = dtv * xcv;
#pragma unroll
        for (int n = 0; n < 16; ++n) {
            float dA = __expf(dtv * A[n]);
            h[n] = fmaf(dA, h[n], u * xr[64 + n]);
            ap[n] *= dA;
        }
    }
    size_t e = ((size_t)(b * NCH + c) << 15) + (size_t)d * 16;
#pragma unroll
    for (int q = 0; q < 4; ++q) {
        *(float4*)deadp(xzbuf, e + q * 4)  = *(float4*)&h[q * 4];
        *(float4*)deadp2(xzbuf, e + q * 4) = *(float4*)&ap[q * 4];
    }
}

__global__ __launch_bounds__(256) void scan_pass2(float* __restrict__ xzbuf)
{
    int idx = blockIdx.x * 256 + threadIdx.x;
    int b = idx >> 15;
    int dn = idx & 32767;
    float carry = 0.f;
    for (int c = 0; c < NCH; ++c) {
        size_t e = ((size_t)(b * NCH + c) << 15) + dn;
        float* hp = deadp(xzbuf, e);
        float hl = *hp;
        float ap = *deadp2(xzbuf, e);
        *hp = carry;
        carry = fmaf(ap, carry, hl);
    }
}

__global__ __launch_bounds__(256) void scan_pass3(
    const float* __restrict__ dt, const float* __restrict__ xc,
    const float* __restrict__ xz, const float* __restrict__ xdbl,
    const float* __restrict__ Alog, const float* __restrict__ Dp,
    float* __restrict__ xzbuf, float* __restrict__ op)
{
    const int b = blockIdx.z, c = blockIdx.y;
    const int d = blockIdx.x * 256 + threadIdx.x;
    float A[16];
#pragma unroll
    for (int q = 0; q < 4; ++q) *(float4*)&A[q * 4] = *(const float4*)&Alog[(size_t)d * 16 + q * 4];
#pragma unroll
    for (int n = 0; n < 16; ++n) A[n] = -__expf(A[n]);
    float h[16];
    size_t e = ((size_t)(b * NCH + c) << 15) + (size_t)d * 16;
#pragma unroll
    for (int q = 0; q < 4; ++q) *(float4*)&h[q * 4] = *(float4*)deadp(xzbuf, e + q * 4);
    const float Dd = Dp[d];
    const int rowbase = b * SEQ + c * CHL;
    for (int t = 0; t < CHL; ++t) {
        const int row = rowbase + t;
        const float* xr = xdbl + (size_t)row * 96;
        float dtv = dt[(size_t)row * DIN + d];
        float xcv = xc[(size_t)row * DIN + d];
        float zv  = xz[(size_t)row * 4096 + DIN + d];
        float u = dtv * xcv;
        float y = 0.f;
#pragma unroll
        for (int n = 0; n < 16; ++n) {
            float dA = __expf(dtv * A[n]);
            h[n] = fmaf(dA, h[n], u * xr[64 + n]);
            y = fmaf(h[n], xr[80 + n], y);
        }
        op[(size_t)row * DIN + d] = (y + xcv * Dd) * zv * sigf(zv);
    }
}

extern "C" void kernel_launch(void* const* d_in, const int* in_sizes, int n_in,
                              void* d_out, int out_size, void* d_ws, size_t ws_size,
                              hipStream_t stream)
{
    const float* x    = (const float*)d_in[0];
    const float* wi   = (const float*)d_in[1];
    const float* cw   = (const float*)d_in[2];
    const float* cb   = (const float*)d_in[3];
    const float* wx   = (const float*)d_in[4];
    const float* wd   = (const float*)d_in[5];
    const float* bd   = (const float*)d_in[6];
    const float* alog = (const float*)d_in[7];
    const float* Dp   = (const float*)d_in[8];
    const float* wo   = (const float*)d_in[9];
    float* out = (float*)d_out;

    float* wsf  = (float*)d_ws;
    float* xz   = wsf;                          // [4096][4096] f32
    float* xc   = xz + (size_t)NROWS * 4096;    // [4096][2048] f32
    float* xdbl = xc + (size_t)NROWS * DIN;     // [4096][96]
    float* dt   = xdbl + (size_t)NROWS * 96;    // [4096][2048] f32
    float* op   = dt;                           // alias

    unsigned short* xhi  = (unsigned short*)xc;
    unsigned short* xlo  = xhi + (size_t)4096 * 1024;
    unsigned short* wihi = (unsigned short*)dt;
    unsigned short* wilo = wihi + (size_t)4096 * 1024;
    unsigned short* ophi = (unsigned short*)xz;
    unsigned short* oplo = ophi + (size_t)4096 * 2048;
    unsigned short* wohi = oplo + (size_t)4096 * 2048;
    unsigned short* wolo = wohi + (size_t)1024 * 2048;

    // dtproj split operands in dead xs-cols of xz (ushort cols 0..255 per row)
    unsigned short* xzU   = (unsigned short*)xz;
    unsigned short* dlhi  = xzU + 0;     // [4096][64], stride 8192
    unsigned short* dllo  = xzU + 64;
    unsigned short* wdhi  = xzU + 128;   // [2048][64], stride 8192
    unsigned short* wdlo  = xzU + 192;

    // 1) split inputs of in_proj
    cvt_split_k<<<4096, 256, 0, stream>>>(x, xhi, xlo, 1048576);
    cvt_split_k<<<4096, 256, 0, stream>>>(wi, wihi, wilo, 1048576);
    // 2) xz = x @ in_proj_w^T
    gemm_mfma_split<<<1024, 256, 0, stream>>>(xhi, xlo, wihi, wilo, xz, 1024, 4096, 32,
                                              1024, 1024, nullptr);
    // 3) xc = silu(conv(xs)+b)
    conv_silu_k<<<32768, 256, 0, stream>>>(xz, cw, cb, xc);
    // 4) x_dbl: K-split partials then reduce
    xproj_part_k<<<dim3(64, 8), 256, 0, stream>>>(xc, wx, xz);
    xproj_reduce_k<<<1536, 256, 0, stream>>>(xz, xdbl);
    // 5) dt = softplus(dt_low @ Wd^T + bd) on the MFMA pipe
    cvt_split_strided_k<<<256, 256, 0, stream>>>(xdbl, 96, dlhi, dllo, 8192, 16, 65536);
    cvt_split_strided_k<<<128, 256, 0, stream>>>(wd, 64, wdhi, wdlo, 8192, 16, 32768);
    gemm_mfma_split<<<512, 256, 0, stream>>>(dlhi, dllo, wdhi, wdlo, dt, 64, 2048, 32,
                                             8192, 8192, bd);
    // 6) chunked scan (register-resident states)
    scan_pass1<<<dim3(8, NCH, 2), 256, 0, stream>>>(dt, xc, xdbl, alog, xz);
    scan_pass2<<<256, 256, 0, stream>>>(xz);
    scan_pass3<<<dim3(8, NCH, 2), 256, 0, stream>>>(dt, xc, xz, xdbl, alog, Dp, xz, op);
    // 7) split inputs of out_proj
    cvt_split_k<<<8192, 256, 0, stream>>>(op, ophi, oplo, 2097152);
    cvt_split_k<<<2048, 256, 0, stream>>>(wo, wohi, wolo, 524288);
    // 8) out = op @ out_proj_w^T
    gemm_mfma_split<<<256, 256, 0, stream>>>(ophi, oplo, wohi, wolo, out, 2048, 1024, 32,
                                             2048, 2048, nullptr);
}

// Round 8
// 282.273 us; speedup vs baseline: 5.6340x; 1.2208x over previous
//
#include <hip/hip_runtime.h>

#define SEQ    2048
#define DIN    2048
#define DMODEL 1024
#define NROWS  4096   // BATCH*SEQ
#define NCH    64     // scan chunks
#define CHL    32     // chunk length

typedef __attribute__((ext_vector_type(8))) _Float16 half8v;
typedef __attribute__((ext_vector_type(4))) float f32x4;

__device__ __forceinline__ float sigf(float x) { return 1.0f / (1.0f + __expf(-x)); }
// inline softplus: no libm call (log1pf is a non-inlined OCML slow path — was a 100 µs pathology)
__device__ __forceinline__ float softplusf(float v) {
    return fmaxf(v, 0.f) + __logf(1.f + __expf(-fabsf(v)));
}

// dead xs-half of xz (rows 0..2047, cols 0..2047): holds h chunk states
__device__ __forceinline__ float* deadp(float* xzbuf, size_t j) {
    return xzbuf + ((j >> 11) << 12) + (j & 2047);
}
// second dead window (rows 2048..4095, cols 0..2047): xproj partials, then prod(dA)
__device__ __forceinline__ float* deadp2(float* xzbuf, size_t j) {
    return xzbuf + ((size_t)(2048 + (j >> 11)) << 12) + (j & 2047);
}

__device__ __forceinline__ void gload16(const void* g, const void* l) {
    __builtin_amdgcn_global_load_lds((const __attribute__((address_space(1))) void*)g,
                                     (__attribute__((address_space(3))) void*)l, 16, 0, 0);
}

__device__ __forceinline__ unsigned short f2h(float x) {
    _Float16 h = (_Float16)x;           // v_cvt_f16_f32, RNE
    unsigned short u;
    __builtin_memcpy(&u, &h, 2);
    return u;
}

// ---------------- fp32 -> fp16 convert ----------------
__global__ __launch_bounds__(256) void cvt_h_k(
    const float* __restrict__ in, unsigned short* __restrict__ out, int n4)
{
    int i = blockIdx.x * 256 + threadIdx.x;
    if (i >= n4) return;
    float4 v = ((const float4*)in)[i];
    ushort4 h;
    h.x = f2h(v.x); h.y = f2h(v.y); h.z = f2h(v.z); h.w = f2h(v.w);
    ((ushort4*)out)[i] = h;
}

// strided: src rows of srcld floats (first ncol4*4 cols), dst rows of dstld ushorts
__global__ __launch_bounds__(256) void cvt_h_strided_k(
    const float* __restrict__ src, int srcld,
    unsigned short* __restrict__ dst, int dstld, int ncol4, int total4)
{
    int i = blockIdx.x * 256 + threadIdx.x;
    if (i >= total4) return;
    int row = i / ncol4, q = i - row * ncol4;
    float4 v = *(const float4*)(src + (size_t)row * srcld + q * 4);
    ushort4 h;
    h.x = f2h(v.x); h.y = f2h(v.y); h.z = f2h(v.z); h.w = f2h(v.w);
    *(ushort4*)(dst + (size_t)row * dstld + q * 4) = h;
}

// ---------------- fp16 MFMA GEMM: C[M][N] = A . W^T  [+bias, softplus] ----------------
// A: [M][lda] fp16 (first K cols), W: [N][ldw], C: [M][N] f32. Tile 128x128, BK=64, 4 waves.
// Requires mtiles % 8 == 0 and gridDim.x % 8 == 0.
#define A_OFF 0
#define W_OFF 16384

__global__ __launch_bounds__(256) void gemm_mfma_h(
    const unsigned short* __restrict__ A, const unsigned short* __restrict__ W,
    float* __restrict__ C, int K, int N, int mtiles, int lda, int ldw,
    const float* __restrict__ bias)
{
    __shared__ uint4 ldsu4[2048];           // 32 KiB: A|W, each [128][64] fp16 swizzled
    char* lds = (char*)ldsu4;
    const int tid  = threadIdx.x;
    const int w    = tid >> 6, lane = tid & 63;

    // XCD-aware chunking, then GROUP_M=8 supertiles for L2 locality
    const int nwg = gridDim.x;
    const int cpx = nwg >> 3;
    const int bid = blockIdx.x;
    const int swz = (bid & 7) * cpx + (bid >> 3);
    const int ntiles = nwg / mtiles;
    const int per = 8 * ntiles;
    const int gid = swz / per;
    const int rem = swz - gid * per;
    const int m0 = (gid * 8 + (rem & 7)) * 128;
    const int n0 = (rem >> 3) * 128;

    const int wr = w >> 1, wc = w & 1;      // wave owns 64x64 at (wr*64, wc*64)

    f32x4 acc[4][4];
#pragma unroll
    for (int i = 0; i < 4; ++i)
#pragma unroll
        for (int j = 0; j < 4; ++j) { acc[i][j][0]=0.f; acc[i][j][1]=0.f; acc[i][j][2]=0.f; acc[i][j][3]=0.f; }

    const int rloc = w * 32 + (lane >> 3);
    const int xr8  = ((lane & 7) ^ (lane >> 3)) << 3;   // pre-swizzled k-chunk (elements)
    const unsigned short* gA = A + (size_t)(m0 + rloc) * lda + xr8;
    const unsigned short* gW = W + (size_t)(n0 + rloc) * ldw + xr8;

    const int lm  = lane & 15;
    const int lk  = lane >> 4;
    const int lk4 = lk * 4;

    for (int kt = 0; kt < K; kt += 64) {
#pragma unroll
        for (int i = 0; i < 4; ++i) {
            const int rb = w * 32 + i * 8;
            gload16(gA + (size_t)i * 8 * lda + kt, lds + A_OFF + rb * 128);
            gload16(gW + (size_t)i * 8 * ldw + kt, lds + W_OFF + rb * 128);
        }
        __syncthreads();
#pragma unroll
        for (int h = 0; h < 2; ++h) {
            half8v af[4], wf[4];
            const int ch = h * 4 + lk;
#pragma unroll
            for (int t = 0; t < 4; ++t) {
                const int ar = wr * 64 + t * 16 + lm;
                const int wrw = wc * 64 + t * 16 + lm;
                af[t] = *(const half8v*)(lds + A_OFF + ar * 128 + ((ch ^ (ar & 7)) << 4));
                wf[t] = *(const half8v*)(lds + W_OFF + wrw * 128 + ((ch ^ (wrw & 7)) << 4));
            }
#pragma unroll
            for (int i = 0; i < 4; ++i)
#pragma unroll
                for (int j = 0; j < 4; ++j)
                    acc[i][j] = __builtin_amdgcn_mfma_f32_16x16x32_f16(af[i], wf[j], acc[i][j], 0, 0, 0);
        }
        __syncthreads();
    }

    if (bias) {
#pragma unroll
        for (int j = 0; j < 4; ++j) {
            const int n = n0 + wc * 64 + j * 16 + lm;
            const float bv = bias[n];
#pragma unroll
            for (int i = 0; i < 4; ++i)
#pragma unroll
                for (int r = 0; r < 4; ++r) {
                    float v = acc[i][j][r] + bv;
                    C[(size_t)(m0 + wr * 64 + i * 16 + lk4 + r) * N + n] = softplusf(v);
                }
        }
    } else {
#pragma unroll
        for (int i = 0; i < 4; ++i)
#pragma unroll
            for (int j = 0; j < 4; ++j)
#pragma unroll
                for (int r = 0; r < 4; ++r)
                    C[(size_t)(m0 + wr * 64 + i * 16 + lk4 + r) * N + (n0 + wc * 64 + j * 16 + lm)] = acc[i][j][r];
    }
}

// ---------------- causal depthwise conv(4) + bias + SiLU ----------------
__global__ __launch_bounds__(256) void conv_silu_k(
    const float* __restrict__ xz, const float* __restrict__ cw,
    const float* __restrict__ cb, float* __restrict__ xc)
{
    int idx = blockIdx.x * 256 + threadIdx.x;
    int d = idx & (DIN - 1);
    int l = (idx >> 11) & (SEQ - 1);
    int b = idx >> 22;
    float w0 = cw[d * 4 + 0], w1 = cw[d * 4 + 1], w2 = cw[d * 4 + 2], w3 = cw[d * 4 + 3];
    int rowb = b * SEQ + l;
    const float* col = xz + d;
    float acc = cb[d];
    if (l >= 3) acc = fmaf(col[(rowb - 3) * 4096], w0, acc);
    if (l >= 2) acc = fmaf(col[(rowb - 2) * 4096], w1, acc);
    if (l >= 1) acc = fmaf(col[(rowb - 1) * 4096], w2, acc);
    acc = fmaf(col[rowb * 4096], w3, acc);
    xc[rowb * DIN + d] = acc * sigf(acc);
}

// ---------------- xproj stage 1: partial x_dbl over K-split ----------------
__global__ __launch_bounds__(256) void xproj_part_k(
    const float* __restrict__ xc, const float* __restrict__ Wx, float* __restrict__ xzbuf)
{
    __shared__ float xs[64][68];
    __shared__ float wsh[96][68];
    const int tid = threadIdx.x;
    const int m0 = blockIdx.x * 64;
    const int ks = blockIdx.y;
    const int tx = tid & 15, rg = tid >> 4;
    float acc[4][6] = {};
    for (int k0 = ks * 256; k0 < ks * 256 + 256; k0 += 64) {
        for (int i = tid; i < 64 * 16; i += 256) {
            int r = i >> 4, c = i & 15;
            *(float4*)&xs[r][c * 4] = *(const float4*)&xc[(size_t)(m0 + r) * DIN + k0 + c * 4];
        }
        for (int i = tid; i < 96 * 16; i += 256) {
            int r = i >> 4, c = i & 15;
            *(float4*)&wsh[r][c * 4] = *(const float4*)&Wx[(size_t)r * DIN + k0 + c * 4];
        }
        __syncthreads();
#pragma unroll 2
        for (int c4 = 0; c4 < 16; ++c4) {
            float4 a[4];
#pragma unroll
            for (int i = 0; i < 4; ++i) a[i] = *(float4*)&xs[tx + i * 16][c4 * 4];
#pragma unroll
            for (int j = 0; j < 6; ++j) {
                float4 w = *(float4*)&wsh[rg * 6 + j][c4 * 4];
#pragma unroll
                for (int i = 0; i < 4; ++i) {
                    acc[i][j] = fmaf(a[i].x, w.x, acc[i][j]);
                    acc[i][j] = fmaf(a[i].y, w.y, acc[i][j]);
                    acc[i][j] = fmaf(a[i].z, w.z, acc[i][j]);
                    acc[i][j] = fmaf(a[i].w, w.w, acc[i][j]);
                }
            }
        }
        __syncthreads();
    }
#pragma unroll
    for (int i = 0; i < 4; ++i)
#pragma unroll
        for (int j = 0; j < 6; ++j) {
            size_t jj = (size_t)ks * (NROWS * 96) + (size_t)(m0 + tx + i * 16) * 96 + rg * 6 + j;
            *deadp2(xzbuf, jj) = acc[i][j];
        }
}

__global__ __launch_bounds__(256) void xproj_reduce_k(
    const float* __restrict__ xzbuf_c, float* __restrict__ xdbl)
{
    float* xzbuf = (float*)xzbuf_c;
    int i = blockIdx.x * 256 + threadIdx.x;
    if (i >= NROWS * 96) return;
    float s = 0.f;
#pragma unroll
    for (int ks = 0; ks < 8; ++ks)
        s += *deadp2(xzbuf, (size_t)ks * (NROWS * 96) + i);
    xdbl[i] = s;
}

// ---------------- chunked selective scan: register-resident 16-state ----------------
__global__ __launch_bounds__(256) void scan_pass1(
    const float* __restrict__ dt, const float* __restrict__ xc,
    const float* __restrict__ xdbl, const float* __restrict__ Alog,
    float* __restrict__ xzbuf)
{
    const int b = blockIdx.z, c = blockIdx.y;
    const int d = blockIdx.x * 256 + threadIdx.x;
    float A[16];
#pragma unroll
    for (int q = 0; q < 4; ++q) *(float4*)&A[q * 4] = *(const float4*)&Alog[(size_t)d * 16 + q * 4];
#pragma unroll
    for (int n = 0; n < 16; ++n) A[n] = -__expf(A[n]);
    float h[16] = {}, ap[16];
#pragma unroll
    for (int n = 0; n < 16; ++n) ap[n] = 1.f;
    const int rowbase = b * SEQ + c * CHL;
    for (int t = 0; t < CHL; ++t) {
        const int row = rowbase + t;
        const float* xr = xdbl + (size_t)row * 96;
        float dtv = dt[(size_t)row * DIN + d];
        float xcv = xc[(size_t)row * DIN + d];
        float u = dtv * xcv;
#pragma unroll
        for (int n = 0; n < 16; ++n) {
            float dA = __expf(dtv * A[n]);
            h[n] = fmaf(dA, h[n], u * xr[64 + n]);
            ap[n] *= dA;
        }
    }
    size_t e = ((size_t)(b * NCH + c) << 15) + (size_t)d * 16;
#pragma unroll
    for (int q = 0; q < 4; ++q) {
        *(float4*)deadp(xzbuf, e + q * 4)  = *(float4*)&h[q * 4];
        *(float4*)deadp2(xzbuf, e + q * 4) = *(float4*)&ap[q * 4];
    }
}

__global__ __launch_bounds__(256) void scan_pass2(float* __restrict__ xzbuf)
{
    int idx = blockIdx.x * 256 + threadIdx.x;
    int b = idx >> 15;
    int dn = idx & 32767;
    float carry = 0.f;
    for (int c = 0; c < NCH; ++c) {
        size_t e = ((size_t)(b * NCH + c) << 15) + dn;
        float* hp = deadp(xzbuf, e);
        float hl = *hp;
        float ap = *deadp2(xzbuf, e);
        *hp = carry;
        carry = fmaf(ap, carry, hl);
    }
}

__global__ __launch_bounds__(256) void scan_pass3(
    const float* __restrict__ dt, const float* __restrict__ xc,
    const float* __restrict__ xz, const float* __restrict__ xdbl,
    const float* __restrict__ Alog, const float* __restrict__ Dp,
    float* __restrict__ xzbuf, float* __restrict__ op)
{
    const int b = blockIdx.z, c = blockIdx.y;
    const int d = blockIdx.x * 256 + threadIdx.x;
    float A[16];
#pragma unroll
    for (int q = 0; q < 4; ++q) *(float4*)&A[q * 4] = *(const float4*)&Alog[(size_t)d * 16 + q * 4];
#pragma unroll
    for (int n = 0; n < 16; ++n) A[n] = -__expf(A[n]);
    float h[16];
    size_t e = ((size_t)(b * NCH + c) << 15) + (size_t)d * 16;
#pragma unroll
    for (int q = 0; q < 4; ++q) *(float4*)&h[q * 4] = *(float4*)deadp(xzbuf, e + q * 4);
    const float Dd = Dp[d];
    const int rowbase = b * SEQ + c * CHL;
    for (int t = 0; t < CHL; ++t) {
        const int row = rowbase + t;
        const float* xr = xdbl + (size_t)row * 96;
        float dtv = dt[(size_t)row * DIN + d];
        float xcv = xc[(size_t)row * DIN + d];
        float zv  = xz[(size_t)row * 4096 + DIN + d];
        float u = dtv * xcv;
        float y = 0.f;
#pragma unroll
        for (int n = 0; n < 16; ++n) {
            float dA = __expf(dtv * A[n]);
            h[n] = fmaf(dA, h[n], u * xr[64 + n]);
            y = fmaf(h[n], xr[80 + n], y);
        }
        op[(size_t)row * DIN + d] = (y + xcv * Dd) * zv * sigf(zv);
    }
}

extern "C" void kernel_launch(void* const* d_in, const int* in_sizes, int n_in,
                              void* d_out, int out_size, void* d_ws, size_t ws_size,
                              hipStream_t stream)
{
    const float* x    = (const float*)d_in[0];
    const float* wi   = (const float*)d_in[1];
    const float* cw   = (const float*)d_in[2];
    const float* cb   = (const float*)d_in[3];
    const float* wx   = (const float*)d_in[4];
    const float* wd   = (const float*)d_in[5];
    const float* bd   = (const float*)d_in[6];
    const float* alog = (const float*)d_in[7];
    const float* Dp   = (const float*)d_in[8];
    const float* wo   = (const float*)d_in[9];
    float* out = (float*)d_out;

    float* wsf  = (float*)d_ws;
    float* xz   = wsf;                          // [4096][4096] f32
    float* xc   = xz + (size_t)NROWS * 4096;    // [4096][2048] f32
    float* xdbl = xc + (size_t)NROWS * DIN;     // [4096][96]
    float* dt   = xdbl + (size_t)NROWS * 96;    // [4096][2048] f32
    float* op   = dt;                           // alias

    // fp16 operand buffers (region reuse; all dead before their region's next writer)
    unsigned short* xh  = (unsigned short*)xc;              // 4.2M (dead at conv)
    unsigned short* wih = (unsigned short*)dt;              // 4.2M (dead at dtproj)
    unsigned short* oph = (unsigned short*)xc;              // 8.4M (xc dead after scan_pass3)
    unsigned short* woh = (unsigned short*)xc + 8388608;    // 2.1M

    // dtproj operands in dead xs-cols of xz (ushort cols 0..127 per 8192-ushort row)
    unsigned short* xzU = (unsigned short*)xz;
    unsigned short* dlh = xzU + 0;     // [4096][64], stride 8192
    unsigned short* wdh = xzU + 64;    // [2048][64], stride 8192

    // 1) fp16 operands of in_proj
    cvt_h_k<<<4096, 256, 0, stream>>>(x, xh, 1048576);
    cvt_h_k<<<4096, 256, 0, stream>>>(wi, wih, 1048576);
    // 2) xz = x @ in_proj_w^T   (M=4096, N=4096, K=1024)
    gemm_mfma_h<<<1024, 256, 0, stream>>>(xh, wih, xz, 1024, 4096, 32, 1024, 1024, nullptr);
    // 3) xc = silu(conv(xs)+b)  (overwrites xh — dead)
    conv_silu_k<<<32768, 256, 0, stream>>>(xz, cw, cb, xc);
    // 4) x_dbl: K-split partials then reduce
    xproj_part_k<<<dim3(64, 8), 256, 0, stream>>>(xc, wx, xz);
    xproj_reduce_k<<<1536, 256, 0, stream>>>(xz, xdbl);
    // 5) dt = softplus(dt_low @ Wd^T + bd) on the MFMA pipe (overwrites wih — dead)
    cvt_h_strided_k<<<256, 256, 0, stream>>>(xdbl, 96, dlh, 8192, 16, 65536);
    cvt_h_strided_k<<<128, 256, 0, stream>>>(wd, 64, wdh, 8192, 16, 32768);
    gemm_mfma_h<<<512, 256, 0, stream>>>(dlh, wdh, dt, 64, 2048, 32, 8192, 8192, bd);
    // 6) chunked scan (register-resident states)
    scan_pass1<<<dim3(8, NCH, 2), 256, 0, stream>>>(dt, xc, xdbl, alog, xz);
    scan_pass2<<<256, 256, 0, stream>>>(xz);
    scan_pass3<<<dim3(8, NCH, 2), 256, 0, stream>>>(dt, xc, xz, xdbl, alog, Dp, xz, op);
    // 7) fp16 operands of out_proj (xc region dead after pass3)
    cvt_h_k<<<8192, 256, 0, stream>>>(op, oph, 2097152);
    cvt_h_k<<<2048, 256, 0, stream>>>(wo, woh, 524288);
    // 8) out = op @ out_proj_w^T (M=4096, N=1024, K=2048)
    gemm_mfma_h<<<256, 256, 0, stream>>>(oph, woh, out, 2048, 1024, 32, 2048, 2048, nullptr);
}

// Round 9
// 271.410 us; speedup vs baseline: 5.8595x; 1.0400x over previous
//
#include <hip/hip_runtime.h>

#define SEQ    2048
#define DIN    2048
#define DMODEL 1024
#define NROWS  4096   // BATCH*SEQ
#define NCH    32     // scan chunks
#define CHL    64     // chunk length

typedef __attribute__((ext_vector_type(8))) _Float16 half8v;
typedef __attribute__((ext_vector_type(4))) float f32x4;

__device__ __forceinline__ float sigf(float x) { return 1.0f / (1.0f + __expf(-x)); }
// inline softplus: no libm call (log1pf is a non-inlined OCML slow path — was a 100 µs pathology)
__device__ __forceinline__ float softplusf(float v) {
    return fmaxf(v, 0.f) + __logf(1.f + __expf(-fabsf(v)));
}

// dead xs-half of xz (rows 0..2047, cols 0..2047): h chunk states (+ dlh/wdh earlier)
__device__ __forceinline__ float* deadp(float* xzbuf, size_t j) {
    return xzbuf + ((j >> 11) << 12) + (j & 2047);
}
// second dead window (rows 2048..4095): xproj partials -> ap -> oph (sequential lifetimes)
__device__ __forceinline__ float* deadp2(float* xzbuf, size_t j) {
    return xzbuf + ((size_t)(2048 + (j >> 11)) << 12) + (j & 2047);
}

__device__ __forceinline__ void gload16(const void* g, const void* l) {
    __builtin_amdgcn_global_load_lds((const __attribute__((address_space(1))) void*)g,
                                     (__attribute__((address_space(3))) void*)l, 16, 0, 0);
}

__device__ __forceinline__ unsigned short f2h(float x) {
    _Float16 h = (_Float16)x;           // v_cvt_f16_f32, RNE
    unsigned short u;
    __builtin_memcpy(&u, &h, 2);
    return u;
}

// ---------------- fused fp32 -> fp16 convert for x and wi ----------------
__global__ __launch_bounds__(256) void cvt_in_k(
    const float* __restrict__ x, const float* __restrict__ wi,
    unsigned short* __restrict__ xh, unsigned short* __restrict__ wih)
{
    int i = blockIdx.x * 256 + threadIdx.x;    // 2 * 1048576
    const float* src = x;
    unsigned short* dst = xh;
    if (i >= 1048576) { i -= 1048576; src = wi; dst = wih; }
    float4 v = ((const float4*)src)[i];
    ushort4 h;
    h.x = f2h(v.x); h.y = f2h(v.y); h.z = f2h(v.z); h.w = f2h(v.w);
    ((ushort4*)dst)[i] = h;
}

__global__ __launch_bounds__(256) void cvt_h_k(
    const float* __restrict__ in, unsigned short* __restrict__ out, int n4)
{
    int i = blockIdx.x * 256 + threadIdx.x;
    if (i >= n4) return;
    float4 v = ((const float4*)in)[i];
    ushort4 h;
    h.x = f2h(v.x); h.y = f2h(v.y); h.z = f2h(v.z); h.w = f2h(v.w);
    ((ushort4*)out)[i] = h;
}

// strided: src rows of srcld floats (first ncol4*4 cols), dst rows of dstld ushorts
__global__ __launch_bounds__(256) void cvt_h_strided_k(
    const float* __restrict__ src, int srcld,
    unsigned short* __restrict__ dst, int dstld, int ncol4, int total4)
{
    int i = blockIdx.x * 256 + threadIdx.x;
    if (i >= total4) return;
    int row = i / ncol4, q = i - row * ncol4;
    float4 v = *(const float4*)(src + (size_t)row * srcld + q * 4);
    ushort4 h;
    h.x = f2h(v.x); h.y = f2h(v.y); h.z = f2h(v.z); h.w = f2h(v.w);
    *(ushort4*)(dst + (size_t)row * dstld + q * 4) = h;
}

// ---------------- fp16 MFMA GEMM: C[M][N] = A . W^T  [+bias, softplus] ----------------
// A row r at A + (r>>1)*sA2 + (r&1)*sA1  (sA2=2*lda, sA1=lda for plain layout).
// W: [N][ldw]. C: [M][N] f32. Tile 128x128, BK=64, 4 waves. mtiles%8==0, grid%8==0.
#define A_OFF 0
#define W_OFF 16384

__global__ __launch_bounds__(256) void gemm_mfma_h(
    const unsigned short* __restrict__ A, const unsigned short* __restrict__ W,
    float* __restrict__ C, int K, int N, int mtiles, int sA1, int sA2, int ldw,
    const float* __restrict__ bias)
{
    __shared__ uint4 ldsu4[2048];           // 32 KiB: A|W, each [128][64] fp16 swizzled
    char* lds = (char*)ldsu4;
    const int tid  = threadIdx.x;
    const int w    = tid >> 6, lane = tid & 63;

    // XCD-aware chunking, then GROUP_M=8 supertiles for L2 locality
    const int nwg = gridDim.x;
    const int cpx = nwg >> 3;
    const int bid = blockIdx.x;
    const int swz = (bid & 7) * cpx + (bid >> 3);
    const int ntiles = nwg / mtiles;
    const int per = 8 * ntiles;
    const int gid = swz / per;
    const int rem = swz - gid * per;
    const int m0 = (gid * 8 + (rem & 7)) * 128;
    const int n0 = (rem >> 3) * 128;

    const int wr = w >> 1, wc = w & 1;      // wave owns 64x64 at (wr*64, wc*64)

    f32x4 acc[4][4];
#pragma unroll
    for (int i = 0; i < 4; ++i)
#pragma unroll
        for (int j = 0; j < 4; ++j) { acc[i][j][0]=0.f; acc[i][j][1]=0.f; acc[i][j][2]=0.f; acc[i][j][3]=0.f; }

    const int rloc = w * 32 + (lane >> 3);
    const int xr8  = ((lane & 7) ^ (lane >> 3)) << 3;   // pre-swizzled k-chunk (elements)
    const int rowA = m0 + rloc;
    const unsigned short* gA = A + (size_t)(rowA >> 1) * sA2 + (size_t)(rowA & 1) * sA1 + xr8;
    const unsigned short* gW = W + (size_t)(n0 + rloc) * ldw + xr8;

    const int lm  = lane & 15;
    const int lk  = lane >> 4;
    const int lk4 = lk * 4;

    for (int kt = 0; kt < K; kt += 64) {
#pragma unroll
        for (int i = 0; i < 4; ++i) {
            const int rb = w * 32 + i * 8;
            gload16(gA + (size_t)i * 4 * sA2 + kt, lds + A_OFF + rb * 128);
            gload16(gW + (size_t)i * 8 * ldw + kt, lds + W_OFF + rb * 128);
        }
        __syncthreads();
#pragma unroll
        for (int h = 0; h < 2; ++h) {
            half8v af[4], wf[4];
            const int ch = h * 4 + lk;
#pragma unroll
            for (int t = 0; t < 4; ++t) {
                const int ar = wr * 64 + t * 16 + lm;
                const int wrw = wc * 64 + t * 16 + lm;
                af[t] = *(const half8v*)(lds + A_OFF + ar * 128 + ((ch ^ (ar & 7)) << 4));
                wf[t] = *(const half8v*)(lds + W_OFF + wrw * 128 + ((ch ^ (wrw & 7)) << 4));
            }
#pragma unroll
            for (int i = 0; i < 4; ++i)
#pragma unroll
                for (int j = 0; j < 4; ++j)
                    acc[i][j] = __builtin_amdgcn_mfma_f32_16x16x32_f16(af[i], wf[j], acc[i][j], 0, 0, 0);
        }
        __syncthreads();
    }

    if (bias) {
#pragma unroll
        for (int j = 0; j < 4; ++j) {
            const int n = n0 + wc * 64 + j * 16 + lm;
            const float bv = bias[n];
#pragma unroll
            for (int i = 0; i < 4; ++i)
#pragma unroll
                for (int r = 0; r < 4; ++r) {
                    float v = acc[i][j][r] + bv;
                    C[(size_t)(m0 + wr * 64 + i * 16 + lk4 + r) * N + n] = softplusf(v);
                }
        }
    } else {
#pragma unroll
        for (int i = 0; i < 4; ++i)
#pragma unroll
            for (int j = 0; j < 4; ++j)
#pragma unroll
                for (int r = 0; r < 4; ++r)
                    C[(size_t)(m0 + wr * 64 + i * 16 + lk4 + r) * N + (n0 + wc * 64 + j * 16 + lm)] = acc[i][j][r];
    }
}

// ---------------- causal depthwise conv(4) + bias + SiLU (x4 vectorized) ----------------
__global__ __launch_bounds__(256) void conv_silu_k(
    const float* __restrict__ xz, const float* __restrict__ cw,
    const float* __restrict__ cb, float* __restrict__ xc)
{
    int i = blockIdx.x * 256 + threadIdx.x;   // NROWS*512
    int d4 = (i & 511) << 2;
    int row = i >> 9;
    int l = row & (SEQ - 1);
    const float* base = xz + (size_t)row * 4096 + d4;
    float4 x0 = *(const float4*)base;
    float4 x1 = (l >= 1) ? *(const float4*)(base - 4096) : make_float4(0, 0, 0, 0);
    float4 x2 = (l >= 2) ? *(const float4*)(base - 8192) : make_float4(0, 0, 0, 0);
    float4 x3 = (l >= 3) ? *(const float4*)(base - 12288) : make_float4(0, 0, 0, 0);
    float4 bv = *(const float4*)(cb + d4);
    float out[4];
#pragma unroll
    for (int j = 0; j < 4; ++j) {
        float4 wv = *(const float4*)(cw + (size_t)(d4 + j) * 4);
        float a = ((const float*)&bv)[j];
        a = fmaf(((const float*)&x3)[j], wv.x, a);
        a = fmaf(((const float*)&x2)[j], wv.y, a);
        a = fmaf(((const float*)&x1)[j], wv.z, a);
        a = fmaf(((const float*)&x0)[j], wv.w, a);
        out[j] = a * sigf(a);
    }
    *(float4*)(xc + (size_t)row * DIN + d4) = *(const float4*)out;
}

// ---------------- xproj stage 1: partial x_dbl over K-split ----------------
__global__ __launch_bounds__(256) void xproj_part_k(
    const float* __restrict__ xc, const float* __restrict__ Wx, float* __restrict__ xzbuf)
{
    __shared__ float xs[64][68];
    __shared__ float wsh[96][68];
    const int tid = threadIdx.x;
    const int m0 = blockIdx.x * 64;
    const int ks = blockIdx.y;
    const int tx = tid & 15, rg = tid >> 4;
    float acc[4][6] = {};
    for (int k0 = ks * 256; k0 < ks * 256 + 256; k0 += 64) {
        for (int i = tid; i < 64 * 16; i += 256) {
            int r = i >> 4, c = i & 15;
            *(float4*)&xs[r][c * 4] = *(const float4*)&xc[(size_t)(m0 + r) * DIN + k0 + c * 4];
        }
        for (int i = tid; i < 96 * 16; i += 256) {
            int r = i >> 4, c = i & 15;
            *(float4*)&wsh[r][c * 4] = *(const float4*)&Wx[(size_t)r * DIN + k0 + c * 4];
        }
        __syncthreads();
#pragma unroll 2
        for (int c4 = 0; c4 < 16; ++c4) {
            float4 a[4];
#pragma unroll
            for (int i = 0; i < 4; ++i) a[i] = *(float4*)&xs[tx + i * 16][c4 * 4];
#pragma unroll
            for (int j = 0; j < 6; ++j) {
                float4 w = *(float4*)&wsh[rg * 6 + j][c4 * 4];
#pragma unroll
                for (int i = 0; i < 4; ++i) {
                    acc[i][j] = fmaf(a[i].x, w.x, acc[i][j]);
                    acc[i][j] = fmaf(a[i].y, w.y, acc[i][j]);
                    acc[i][j] = fmaf(a[i].z, w.z, acc[i][j]);
                    acc[i][j] = fmaf(a[i].w, w.w, acc[i][j]);
                }
            }
        }
        __syncthreads();
    }
#pragma unroll
    for (int i = 0; i < 4; ++i)
#pragma unroll
        for (int j = 0; j < 6; ++j) {
            size_t jj = (size_t)ks * (NROWS * 96) + (size_t)(m0 + tx + i * 16) * 96 + rg * 6 + j;
            *deadp2(xzbuf, jj) = acc[i][j];
        }
}

__global__ __launch_bounds__(256) void xproj_reduce_k(
    const float* __restrict__ xzbuf_c, float* __restrict__ xdbl)
{
    float* xzbuf = (float*)xzbuf_c;
    int i = blockIdx.x * 256 + threadIdx.x;
    if (i >= NROWS * 96) return;
    float s = 0.f;
#pragma unroll
    for (int ks = 0; ks < 8; ++ks)
        s += *deadp2(xzbuf, (size_t)ks * (NROWS * 96) + i);
    xdbl[i] = s;
}

// ---------------- chunked selective scan: register-resident 16-state ----------------
__global__ __launch_bounds__(256) void scan_pass1(
    const float* __restrict__ dt, const float* __restrict__ xc,
    const float* __restrict__ xdbl, const float* __restrict__ Alog,
    float* __restrict__ xzbuf)
{
    const int b = blockIdx.z, c = blockIdx.y;
    const int d = blockIdx.x * 256 + threadIdx.x;
    float A[16];
#pragma unroll
    for (int q = 0; q < 4; ++q) *(float4*)&A[q * 4] = *(const float4*)&Alog[(size_t)d * 16 + q * 4];
#pragma unroll
    for (int n = 0; n < 16; ++n) A[n] = -__expf(A[n]);
    float h[16] = {}, ap[16];
#pragma unroll
    for (int n = 0; n < 16; ++n) ap[n] = 1.f;
    const int rowbase = b * SEQ + c * CHL;
    for (int t = 0; t < CHL; ++t) {
        const int row = rowbase + t;
        const float* xr = xdbl + (size_t)row * 96;   // wave-uniform -> scalar loads
        float dtv = dt[(size_t)row * DIN + d];
        float xcv = xc[(size_t)row * DIN + d];
        float u = dtv * xcv;
#pragma unroll
        for (int n = 0; n < 16; ++n) {
            float dA = __expf(dtv * A[n]);
            h[n] = fmaf(dA, h[n], u * xr[64 + n]);
            ap[n] *= dA;
        }
    }
    size_t e = ((size_t)(b * NCH + c) << 15) + (size_t)d * 16;
#pragma unroll
    for (int q = 0; q < 4; ++q) {
        *(float4*)deadp(xzbuf, e + q * 4)  = *(float4*)&h[q * 4];
        *(float4*)deadp2(xzbuf, e + q * 4) = *(float4*)&ap[q * 4];
    }
}

__global__ __launch_bounds__(256) void scan_pass2(float* __restrict__ xzbuf)
{
    int idx = blockIdx.x * 256 + threadIdx.x;   // 65536
    int b = idx >> 15;
    int dn = idx & 32767;
    float carry = 0.f;
    for (int c = 0; c < NCH; ++c) {
        size_t e = ((size_t)(b * NCH + c) << 15) + dn;
        float* hp = deadp(xzbuf, e);
        float hl = *hp;
        float ap = *deadp2(xzbuf, e);
        *hp = carry;
        carry = fmaf(ap, carry, hl);
    }
}

// pass 3: re-scan from h_in; fused epilogue writes op directly as fp16 into the
// dead deadp2 window (op row r -> xz row 2048+(r>>1), ushort col (r&1)*2048+d).
__global__ __launch_bounds__(256) void scan_pass3(
    const float* __restrict__ dt, const float* __restrict__ xc,
    const float* __restrict__ xz, const float* __restrict__ xdbl,
    const float* __restrict__ Alog, const float* __restrict__ Dp,
    float* __restrict__ xzbuf, unsigned short* __restrict__ oph)
{
    const int b = blockIdx.z, c = blockIdx.y;
    const int d = blockIdx.x * 256 + threadIdx.x;
    float A[16];
#pragma unroll
    for (int q = 0; q < 4; ++q) *(float4*)&A[q * 4] = *(const float4*)&Alog[(size_t)d * 16 + q * 4];
#pragma unroll
    for (int n = 0; n < 16; ++n) A[n] = -__expf(A[n]);
    float h[16];
    size_t e = ((size_t)(b * NCH + c) << 15) + (size_t)d * 16;
#pragma unroll
    for (int q = 0; q < 4; ++q) *(float4*)&h[q * 4] = *(float4*)deadp(xzbuf, e + q * 4);
    const float Dd = Dp[d];
    const int rowbase = b * SEQ + c * CHL;
    for (int t = 0; t < CHL; ++t) {
        const int row = rowbase + t;
        const float* xr = xdbl + (size_t)row * 96;
        float dtv = dt[(size_t)row * DIN + d];
        float xcv = xc[(size_t)row * DIN + d];
        float zv  = xz[(size_t)row * 4096 + DIN + d];
        float u = dtv * xcv;
        float y = 0.f;
#pragma unroll
        for (int n = 0; n < 16; ++n) {
            float dA = __expf(dtv * A[n]);
            h[n] = fmaf(dA, h[n], u * xr[64 + n]);
            y = fmaf(h[n], xr[80 + n], y);
        }
        float val = (y + xcv * Dd) * zv * sigf(zv);
        oph[(size_t)(row >> 1) * 8192 + (size_t)(row & 1) * 2048 + d] = f2h(val);
    }
}

extern "C" void kernel_launch(void* const* d_in, const int* in_sizes, int n_in,
                              void* d_out, int out_size, void* d_ws, size_t ws_size,
                              hipStream_t stream)
{
    const float* x    = (const float*)d_in[0];
    const float* wi   = (const float*)d_in[1];
    const float* cw   = (const float*)d_in[2];
    const float* cb   = (const float*)d_in[3];
    const float* wx   = (const float*)d_in[4];
    const float* wd   = (const float*)d_in[5];
    const float* bd   = (const float*)d_in[6];
    const float* alog = (const float*)d_in[7];
    const float* Dp   = (const float*)d_in[8];
    const float* wo   = (const float*)d_in[9];
    float* out = (float*)d_out;

    float* wsf  = (float*)d_ws;
    float* xz   = wsf;                          // [4096][4096] f32
    float* xc   = xz + (size_t)NROWS * 4096;    // [4096][2048] f32
    float* xdbl = xc + (size_t)NROWS * DIN;     // [4096][96]
    float* dt   = xdbl + (size_t)NROWS * 96;    // [4096][2048] f32

    unsigned short* xzU = (unsigned short*)xz;
    unsigned short* xh  = (unsigned short*)xc;              // dead until conv
    unsigned short* wih = (unsigned short*)dt;              // dead until dtproj writes dt
    unsigned short* dlh = xzU + 0;                          // [4096][64] @ stride 8192 (dead xs cols)
    unsigned short* wdh = xzU + 64;                         // [2048][64] @ stride 8192
    unsigned short* oph = xzU + (size_t)2048 * 8192;        // deadp2 window (dead after pass2)
    unsigned short* woh = (unsigned short*)xc;              // xc dead after pass3

    // 1) fp16 operands of in_proj (fused)
    cvt_in_k<<<8192, 256, 0, stream>>>(x, wi, xh, wih);
    // 2) xz = x @ in_proj_w^T   (M=4096, N=4096, K=1024)
    gemm_mfma_h<<<1024, 256, 0, stream>>>(xh, wih, xz, 1024, 4096, 32, 1024, 2048, 1024, nullptr);
    // 3) xc = silu(conv(xs)+b)  (overwrites xh — dead)
    conv_silu_k<<<8192, 256, 0, stream>>>(xz, cw, cb, xc);
    // 4) x_dbl: K-split partials (deadp2) then reduce
    xproj_part_k<<<dim3(64, 8), 256, 0, stream>>>(xc, wx, xz);
    xproj_reduce_k<<<1536, 256, 0, stream>>>(xz, xdbl);
    // 5) dt = softplus(dt_low @ Wd^T + bd) on the MFMA pipe (overwrites wih — dead)
    cvt_h_strided_k<<<256, 256, 0, stream>>>(xdbl, 96, dlh, 8192, 16, 65536);
    cvt_h_strided_k<<<128, 256, 0, stream>>>(wd, 64, wdh, 8192, 16, 32768);
    gemm_mfma_h<<<512, 256, 0, stream>>>(dlh, wdh, dt, 64, 2048, 32, 8192, 16384, 8192, bd);
    // 6) chunked scan; pass3 writes op as fp16 into deadp2 overlay (fused cvt)
    scan_pass1<<<dim3(8, NCH, 2), 256, 0, stream>>>(dt, xc, xdbl, alog, xz);
    scan_pass2<<<256, 256, 0, stream>>>(xz);
    scan_pass3<<<dim3(8, NCH, 2), 256, 0, stream>>>(dt, xc, xz, xdbl, alog, Dp, xz, oph);
    // 7) wo -> fp16 (into xc region — dead after pass3)
    cvt_h_k<<<2048, 256, 0, stream>>>(wo, woh, 524288);
    // 8) out = op @ out_proj_w^T (M=4096, N=1024, K=2048); A via (r>>1)*8192+(r&1)*2048 map
    gemm_mfma_h<<<256, 256, 0, stream>>>(oph, woh, out, 2048, 1024, 32, 2048, 8192, 2048, nullptr);
}

// Round 10
// 258.904 us; speedup vs baseline: 6.1426x; 1.0483x over previous
//
#include <hip/hip_runtime.h>

#define SEQ    2048
#define DIN    2048
#define DMODEL 1024
#define NROWS  4096   // BATCH*SEQ
#define NCH    32     // scan chunks
#define CHL    64     // chunk length

typedef __attribute__((ext_vector_type(8))) _Float16 half8v;
typedef __attribute__((ext_vector_type(4))) float f32x4;

__device__ __forceinline__ float sigf(float x) { return 1.0f / (1.0f + __expf(-x)); }
// inline softplus: no libm call (log1pf is a non-inlined OCML slow path — was a 100 µs pathology)
__device__ __forceinline__ float softplusf(float v) {
    return fmaxf(v, 0.f) + __logf(1.f + __expf(-fabsf(v)));
}

// dead xs-half of xz (rows 0..2047, cols 0..2047): h chunk states (+ dlh/wdh earlier)
__device__ __forceinline__ float* deadp(float* xzbuf, size_t j) {
    return xzbuf + ((j >> 11) << 12) + (j & 2047);
}
// second dead window (rows 2048..4095): xproj partials -> ap -> oph (sequential lifetimes)
__device__ __forceinline__ float* deadp2(float* xzbuf, size_t j) {
    return xzbuf + ((size_t)(2048 + (j >> 11)) << 12) + (j & 2047);
}

__device__ __forceinline__ void gload16(const void* g, const void* l) {
    __builtin_amdgcn_global_load_lds((const __attribute__((address_space(1))) void*)g,
                                     (__attribute__((address_space(3))) void*)l, 16, 0, 0);
}

__device__ __forceinline__ unsigned short f2h(float x) {
    _Float16 h = (_Float16)x;           // v_cvt_f16_f32, RNE
    unsigned short u;
    __builtin_memcpy(&u, &h, 2);
    return u;
}

// ---------------- fused fp32 -> fp16 convert for x and wi ----------------
__global__ __launch_bounds__(256) void cvt_in_k(
    const float* __restrict__ x, const float* __restrict__ wi,
    unsigned short* __restrict__ xh, unsigned short* __restrict__ wih)
{
    int i = blockIdx.x * 256 + threadIdx.x;    // 2 * 1048576
    const float* src = x;
    unsigned short* dst = xh;
    if (i >= 1048576) { i -= 1048576; src = wi; dst = wih; }
    float4 v = ((const float4*)src)[i];
    ushort4 h;
    h.x = f2h(v.x); h.y = f2h(v.y); h.z = f2h(v.z); h.w = f2h(v.w);
    ((ushort4*)dst)[i] = h;
}

__global__ __launch_bounds__(256) void cvt_h_k(
    const float* __restrict__ in, unsigned short* __restrict__ out, int n4)
{
    int i = blockIdx.x * 256 + threadIdx.x;
    if (i >= n4) return;
    float4 v = ((const float4*)in)[i];
    ushort4 h;
    h.x = f2h(v.x); h.y = f2h(v.y); h.z = f2h(v.z); h.w = f2h(v.w);
    ((ushort4*)out)[i] = h;
}

// fused dtproj operand cvt: dl (xdbl[:, :64] -> dlh) and wd -> wdh, both stride-8192 dst
__global__ __launch_bounds__(256) void cvt_dt_k(
    const float* __restrict__ xdbl, const float* __restrict__ wd,
    unsigned short* __restrict__ dlh, unsigned short* __restrict__ wdh)
{
    int i = blockIdx.x * 256 + threadIdx.x;    // 65536 + 32768
    const float* src; unsigned short* dst; int srcld, row, q;
    if (i < 65536) { row = i >> 4; q = i & 15; src = xdbl; srcld = 96; dst = dlh; }
    else { i -= 65536; row = i >> 4; q = i & 15; src = wd; srcld = 64; dst = wdh; }
    float4 v = *(const float4*)(src + (size_t)row * srcld + q * 4);
    ushort4 h;
    h.x = f2h(v.x); h.y = f2h(v.y); h.z = f2h(v.z); h.w = f2h(v.w);
    *(ushort4*)(dst + (size_t)row * 8192 + q * 4) = h;
}

// ======== 8-phase 256x256 fp16 MFMA GEMM (T2+T3+T4+T5), for large square grids ========
// C[M][N] = A . W^T ; A:[M][lda], W:[N][ldw] fp16; 512 thr = 8 waves (2M x 4N), BK=64.
// LDS 128 KiB: 2 buffers x (A[256][64] | B[256][64]) fp16, XOR-swizzled.
// Counted vmcnt(4) before inter-phase barriers keeps prefetch in flight (never 0 in loop).
__global__ __launch_bounds__(512, 2) void gemm256_h(
    const unsigned short* __restrict__ A, const unsigned short* __restrict__ W,
    float* __restrict__ C, int K, int N, int mtiles, int lda, int ldw)
{
    __shared__ uint4 ldsu4[8192];          // 128 KiB
    char* lds = (char*)ldsu4;
    const int tid = threadIdx.x;
    const int w = tid >> 6, lane = tid & 63;

    // XCD chunking + GROUP_M=8 supertiles
    const int nwg = gridDim.x;
    const int cpx = nwg >> 3;
    const int bid = blockIdx.x;
    const int swz = (bid & 7) * cpx + (bid >> 3);
    const int ntiles = nwg / mtiles;
    const int per = 8 * ntiles;
    const int gid = swz / per;
    const int rem = swz - gid * per;
    const int m0 = (gid * 8 + (rem & 7)) * 256;
    const int n0 = (rem >> 3) * 256;

    const int wr = w >> 2, wc = w & 3;     // wave tile: 128x64 at (wr*128, wc*64)
    const int lm = lane & 15, lk = lane >> 4;

    f32x4 acc[8][4];
#pragma unroll
    for (int i = 0; i < 8; ++i)
#pragma unroll
        for (int j = 0; j < 4; ++j) { acc[i][j][0]=0.f; acc[i][j][1]=0.f; acc[i][j][2]=0.f; acc[i][j][3]=0.f; }

    // staging: thread stages row w*8+(lane>>3) (+64 for 2nd issue) of a 128-row half-tile
    const int rsub = w * 8 + (lane >> 3);
    const int xr8  = ((lane & 7) ^ (lane >> 3)) << 3;    // pre-swizzled col chunk
    const unsigned short* gA = A + (size_t)(m0 + rsub) * lda + xr8;
    const unsigned short* gW = W + (size_t)(n0 + rsub) * ldw + xr8;
    const int sdst = w * 1024;                            // + lane*16 appended by HW

    auto stageA = [&](int bb, int hi, int kt) {
        char* d = lds + bb * 65536 + hi * 16384 + sdst;
        const unsigned short* s = gA + (size_t)hi * 128 * lda + kt;
        gload16(s, d);
        gload16(s + (size_t)64 * lda, d + 8192);
    };
    auto stageB = [&](int bb, int hi, int kt) {
        char* d = lds + bb * 65536 + 32768 + hi * 16384 + sdst;
        const unsigned short* s = gW + (size_t)hi * 128 * ldw + kt;
        gload16(s, d);
        gload16(s + (size_t)64 * ldw, d + 8192);
    };

    half8v a[4][2], b[2][2][2];
    auto loadA = [&](int bb, int mh) {
#pragma unroll
        for (int mb = 0; mb < 4; ++mb)
#pragma unroll
            for (int kk = 0; kk < 2; ++kk) {
                int ar = wr * 128 + (mh * 4 + mb) * 16 + lm;
                a[mb][kk] = *(const half8v*)(lds + bb * 65536 + ar * 128 + (((kk * 4 + lk) ^ (lm & 7)) << 4));
            }
    };
    auto loadB = [&](int bb, int nh) {
#pragma unroll
        for (int nb = 0; nb < 2; ++nb)
#pragma unroll
            for (int kk = 0; kk < 2; ++kk) {
                int br = wc * 64 + (nh * 2 + nb) * 16 + lm;
                b[nh][nb][kk] = *(const half8v*)(lds + bb * 65536 + 32768 + br * 128 + (((kk * 4 + lk) ^ (lm & 7)) << 4));
            }
    };
    auto mm = [&](int mh, int nh) {
        __builtin_amdgcn_s_setprio(1);
#pragma unroll
        for (int mb = 0; mb < 4; ++mb)
#pragma unroll
            for (int nb = 0; nb < 2; ++nb)
#pragma unroll
                for (int kk = 0; kk < 2; ++kk)
                    acc[mh * 4 + mb][nh * 2 + nb] = __builtin_amdgcn_mfma_f32_16x16x32_f16(
                        a[mb][kk], b[nh][nb][kk], acc[mh * 4 + mb][nh * 2 + nb], 0, 0, 0);
        __builtin_amdgcn_s_setprio(0);
    };
#define VMW4() asm volatile("s_waitcnt vmcnt(4)" ::: "memory")
#define BAR()  __builtin_amdgcn_s_barrier()

    // prologue: stage tile 0 fully into buf0, full drain
    stageA(0, 0, 0); stageA(0, 1, 0); stageB(0, 0, 0); stageB(0, 1, 0);
    asm volatile("s_waitcnt vmcnt(0)" ::: "memory");
    BAR();

    const int NT = K >> 6;
    for (int t = 0; t < NT - 1; ++t) {
        const int cur = t & 1, nxt = cur ^ 1;
        const int kt = (t + 1) << 6;
        // ph0: quadrant (0,0)
        loadA(cur, 0); loadB(cur, 0);
        stageA(nxt, 0, kt);
        BAR();
        mm(0, 0);
        VMW4(); BAR();
        // ph1: quadrant (0,1)
        loadB(cur, 1);
        stageB(nxt, 0, kt);
        BAR();
        mm(0, 1);
        VMW4(); BAR();
        // ph2: quadrant (1,1)
        loadA(cur, 1);
        stageB(nxt, 1, kt);
        BAR();
        mm(1, 1);
        VMW4(); BAR();
        // ph3: quadrant (1,0) — b[0] still resident
        stageA(nxt, 1, kt);
        BAR();
        mm(1, 0);
        VMW4(); BAR();
    }
    // epilogue tile NT-1: drain once, then barrier-free compute
    {
        const int cur = (NT - 1) & 1;
        asm volatile("s_waitcnt vmcnt(0)" ::: "memory");
        BAR();
        loadA(cur, 0); loadB(cur, 0); mm(0, 0);
        loadB(cur, 1); mm(0, 1);
        loadA(cur, 1); mm(1, 1); mm(1, 0);
    }
#undef VMW4
#undef BAR

#pragma unroll
    for (int mb = 0; mb < 8; ++mb)
#pragma unroll
        for (int nb = 0; nb < 4; ++nb)
#pragma unroll
            for (int r = 0; r < 4; ++r)
                C[(size_t)(m0 + wr * 128 + mb * 16 + lk * 4 + r) * N + (n0 + wc * 64 + nb * 16 + lm)] = acc[mb][nb][r];
}

// ---------------- 128x128 fp16 MFMA GEMM (kept for dtproj / out_proj) ----------------
// A row r at A + (r>>1)*sA2 + (r&1)*sA1  (sA2=2*lda, sA1=lda for plain layout).
#define A_OFF 0
#define W_OFF 16384

__global__ __launch_bounds__(256) void gemm_mfma_h(
    const unsigned short* __restrict__ A, const unsigned short* __restrict__ W,
    float* __restrict__ C, int K, int N, int mtiles, int sA1, int sA2, int ldw,
    const float* __restrict__ bias)
{
    __shared__ uint4 ldsu4[2048];
    char* lds = (char*)ldsu4;
    const int tid  = threadIdx.x;
    const int w    = tid >> 6, lane = tid & 63;

    const int nwg = gridDim.x;
    const int cpx = nwg >> 3;
    const int bid = blockIdx.x;
    const int swz = (bid & 7) * cpx + (bid >> 3);
    const int ntiles = nwg / mtiles;
    const int per = 8 * ntiles;
    const int gid = swz / per;
    const int rem = swz - gid * per;
    const int m0 = (gid * 8 + (rem & 7)) * 128;
    const int n0 = (rem >> 3) * 128;

    const int wr = w >> 1, wc = w & 1;

    f32x4 acc[4][4];
#pragma unroll
    for (int i = 0; i < 4; ++i)
#pragma unroll
        for (int j = 0; j < 4; ++j) { acc[i][j][0]=0.f; acc[i][j][1]=0.f; acc[i][j][2]=0.f; acc[i][j][3]=0.f; }

    const int rloc = w * 32 + (lane >> 3);
    const int xr8  = ((lane & 7) ^ (lane >> 3)) << 3;
    const int rowA = m0 + rloc;
    const unsigned short* gA = A + (size_t)(rowA >> 1) * sA2 + (size_t)(rowA & 1) * sA1 + xr8;
    const unsigned short* gW = W + (size_t)(n0 + rloc) * ldw + xr8;

    const int lm  = lane & 15;
    const int lk  = lane >> 4;
    const int lk4 = lk * 4;

    for (int kt = 0; kt < K; kt += 64) {
#pragma unroll
        for (int i = 0; i < 4; ++i) {
            const int rb = w * 32 + i * 8;
            gload16(gA + (size_t)i * 4 * sA2 + kt, lds + A_OFF + rb * 128);
            gload16(gW + (size_t)i * 8 * ldw + kt, lds + W_OFF + rb * 128);
        }
        __syncthreads();
#pragma unroll
        for (int h = 0; h < 2; ++h) {
            half8v af[4], wf[4];
            const int ch = h * 4 + lk;
#pragma unroll
            for (int t = 0; t < 4; ++t) {
                const int ar = wr * 64 + t * 16 + lm;
                const int wrw = wc * 64 + t * 16 + lm;
                af[t] = *(const half8v*)(lds + A_OFF + ar * 128 + ((ch ^ (ar & 7)) << 4));
                wf[t] = *(const half8v*)(lds + W_OFF + wrw * 128 + ((ch ^ (wrw & 7)) << 4));
            }
#pragma unroll
            for (int i = 0; i < 4; ++i)
#pragma unroll
                for (int j = 0; j < 4; ++j)
                    acc[i][j] = __builtin_amdgcn_mfma_f32_16x16x32_f16(af[i], wf[j], acc[i][j], 0, 0, 0);
        }
        __syncthreads();
    }

    if (bias) {
#pragma unroll
        for (int j = 0; j < 4; ++j) {
            const int n = n0 + wc * 64 + j * 16 + lm;
            const float bv = bias[n];
#pragma unroll
            for (int i = 0; i < 4; ++i)
#pragma unroll
                for (int r = 0; r < 4; ++r) {
                    float v = acc[i][j][r] + bv;
                    C[(size_t)(m0 + wr * 64 + i * 16 + lk4 + r) * N + n] = softplusf(v);
                }
        }
    } else {
#pragma unroll
        for (int i = 0; i < 4; ++i)
#pragma unroll
            for (int j = 0; j < 4; ++j)
#pragma unroll
                for (int r = 0; r < 4; ++r)
                    C[(size_t)(m0 + wr * 64 + i * 16 + lk4 + r) * N + (n0 + wc * 64 + j * 16 + lm)] = acc[i][j][r];
    }
}

// ---------------- causal depthwise conv(4) + bias + SiLU (x4 vectorized) ----------------
__global__ __launch_bounds__(256) void conv_silu_k(
    const float* __restrict__ xz, const float* __restrict__ cw,
    const float* __restrict__ cb, float* __restrict__ xc)
{
    int i = blockIdx.x * 256 + threadIdx.x;   // NROWS*512
    int d4 = (i & 511) << 2;
    int row = i >> 9;
    int l = row & (SEQ - 1);
    const float* base = xz + (size_t)row * 4096 + d4;
    float4 x0 = *(const float4*)base;
    float4 x1 = (l >= 1) ? *(const float4*)(base - 4096) : make_float4(0, 0, 0, 0);
    float4 x2 = (l >= 2) ? *(const float4*)(base - 8192) : make_float4(0, 0, 0, 0);
    float4 x3 = (l >= 3) ? *(const float4*)(base - 12288) : make_float4(0, 0, 0, 0);
    float4 bv = *(const float4*)(cb + d4);
    float out[4];
#pragma unroll
    for (int j = 0; j < 4; ++j) {
        float4 wv = *(const float4*)(cw + (size_t)(d4 + j) * 4);
        float a = ((const float*)&bv)[j];
        a = fmaf(((const float*)&x3)[j], wv.x, a);
        a = fmaf(((const float*)&x2)[j], wv.y, a);
        a = fmaf(((const float*)&x1)[j], wv.z, a);
        a = fmaf(((const float*)&x0)[j], wv.w, a);
        out[j] = a * sigf(a);
    }
    *(float4*)(xc + (size_t)row * DIN + d4) = *(const float4*)out;
}

// ---------------- xproj stage 1: partial x_dbl over K-split ----------------
__global__ __launch_bounds__(256) void xproj_part_k(
    const float* __restrict__ xc, const float* __restrict__ Wx, float* __restrict__ xzbuf)
{
    __shared__ float xs[64][68];
    __shared__ float wsh[96][68];
    const int tid = threadIdx.x;
    const int m0 = blockIdx.x * 64;
    const int ks = blockIdx.y;
    const int tx = tid & 15, rg = tid >> 4;
    float acc[4][6] = {};
    for (int k0 = ks * 256; k0 < ks * 256 + 256; k0 += 64) {
        for (int i = tid; i < 64 * 16; i += 256) {
            int r = i >> 4, c = i & 15;
            *(float4*)&xs[r][c * 4] = *(const float4*)&xc[(size_t)(m0 + r) * DIN + k0 + c * 4];
        }
        for (int i = tid; i < 96 * 16; i += 256) {
            int r = i >> 4, c = i & 15;
            *(float4*)&wsh[r][c * 4] = *(const float4*)&Wx[(size_t)r * DIN + k0 + c * 4];
        }
        __syncthreads();
#pragma unroll 2
        for (int c4 = 0; c4 < 16; ++c4) {
            float4 a[4];
#pragma unroll
            for (int i = 0; i < 4; ++i) a[i] = *(float4*)&xs[tx + i * 16][c4 * 4];
#pragma unroll
            for (int j = 0; j < 6; ++j) {
                float4 w = *(float4*)&wsh[rg * 6 + j][c4 * 4];
#pragma unroll
                for (int i = 0; i < 4; ++i) {
                    acc[i][j] = fmaf(a[i].x, w.x, acc[i][j]);
                    acc[i][j] = fmaf(a[i].y, w.y, acc[i][j]);
                    acc[i][j] = fmaf(a[i].z, w.z, acc[i][j]);
                    acc[i][j] = fmaf(a[i].w, w.w, acc[i][j]);
                }
            }
        }
        __syncthreads();
    }
#pragma unroll
    for (int i = 0; i < 4; ++i)
#pragma unroll
        for (int j = 0; j < 6; ++j) {
            size_t jj = (size_t)ks * (NROWS * 96) + (size_t)(m0 + tx + i * 16) * 96 + rg * 6 + j;
            *deadp2(xzbuf, jj) = acc[i][j];
        }
}

__global__ __launch_bounds__(256) void xproj_reduce_k(
    const float* __restrict__ xzbuf_c, float* __restrict__ xdbl)
{
    float* xzbuf = (float*)xzbuf_c;
    int i = blockIdx.x * 256 + threadIdx.x;
    if (i >= NROWS * 96) return;
    float s = 0.f;
#pragma unroll
    for (int ks = 0; ks < 8; ++ks)
        s += *deadp2(xzbuf, (size_t)ks * (NROWS * 96) + i);
    xdbl[i] = s;
}

// ---------------- chunked selective scan: register-resident 16-state ----------------
__global__ __launch_bounds__(256) void scan_pass1(
    const float* __restrict__ dt, const float* __restrict__ xc,
    const float* __restrict__ xdbl, const float* __restrict__ Alog,
    float* __restrict__ xzbuf)
{
    const int b = blockIdx.z, c = blockIdx.y;
    const int d = blockIdx.x * 256 + threadIdx.x;
    float A[16];
#pragma unroll
    for (int q = 0; q < 4; ++q) *(float4*)&A[q * 4] = *(const float4*)&Alog[(size_t)d * 16 + q * 4];
#pragma unroll
    for (int n = 0; n < 16; ++n) A[n] = -__expf(A[n]);
    float h[16] = {}, ap[16];
#pragma unroll
    for (int n = 0; n < 16; ++n) ap[n] = 1.f;
    const int rowbase = b * SEQ + c * CHL;
    for (int t = 0; t < CHL; ++t) {
        const int row = rowbase + t;
        const float* xr = xdbl + (size_t)row * 96;   // wave-uniform -> scalar loads
        float dtv = dt[(size_t)row * DIN + d];
        float xcv = xc[(size_t)row * DIN + d];
        float u = dtv * xcv;
#pragma unroll
        for (int n = 0; n < 16; ++n) {
            float dA = __expf(dtv * A[n]);
            h[n] = fmaf(dA, h[n], u * xr[64 + n]);
            ap[n] *= dA;
        }
    }
    size_t e = ((size_t)(b * NCH + c) << 15) + (size_t)d * 16;
#pragma unroll
    for (int q = 0; q < 4; ++q) {
        *(float4*)deadp(xzbuf, e + q * 4)  = *(float4*)&h[q * 4];
        *(float4*)deadp2(xzbuf, e + q * 4) = *(float4*)&ap[q * 4];
    }
}

__global__ __launch_bounds__(256) void scan_pass2(float* __restrict__ xzbuf)
{
    int idx = blockIdx.x * 256 + threadIdx.x;   // 65536
    int b = idx >> 15;
    int dn = idx & 32767;
    float carry = 0.f;
    for (int c = 0; c < NCH; ++c) {
        size_t e = ((size_t)(b * NCH + c) << 15) + dn;
        float* hp = deadp(xzbuf, e);
        float hl = *hp;
        float ap = *deadp2(xzbuf, e);
        *hp = carry;
        carry = fmaf(ap, carry, hl);
    }
}

// pass 3: re-scan from h_in; fused epilogue writes op directly as fp16 into the
// dead deadp2 window (op row r -> xz row 2048+(r>>1), ushort col (r&1)*2048+d).
__global__ __launch_bounds__(256) void scan_pass3(
    const float* __restrict__ dt, const float* __restrict__ xc,
    const float* __restrict__ xz, const float* __restrict__ xdbl,
    const float* __restrict__ Alog, const float* __restrict__ Dp,
    float* __restrict__ xzbuf, unsigned short* __restrict__ oph)
{
    const int b = blockIdx.z, c = blockIdx.y;
    const int d = blockIdx.x * 256 + threadIdx.x;
    float A[16];
#pragma unroll
    for (int q = 0; q < 4; ++q) *(float4*)&A[q * 4] = *(const float4*)&Alog[(size_t)d * 16 + q * 4];
#pragma unroll
    for (int n = 0; n < 16; ++n) A[n] = -__expf(A[n]);
    float h[16];
    size_t e = ((size_t)(b * NCH + c) << 15) + (size_t)d * 16;
#pragma unroll
    for (int q = 0; q < 4; ++q) *(float4*)&h[q * 4] = *(float4*)deadp(xzbuf, e + q * 4);
    const float Dd = Dp[d];
    const int rowbase = b * SEQ + c * CHL;
    for (int t = 0; t < CHL; ++t) {
        const int row = rowbase + t;
        const float* xr = xdbl + (size_t)row * 96;
        float dtv = dt[(size_t)row * DIN + d];
        float xcv = xc[(size_t)row * DIN + d];
        float zv  = xz[(size_t)row * 4096 + DIN + d];
        float u = dtv * xcv;
        float y = 0.f;
#pragma unroll
        for (int n = 0; n < 16; ++n) {
            float dA = __expf(dtv * A[n]);
            h[n] = fmaf(dA, h[n], u * xr[64 + n]);
            y = fmaf(h[n], xr[80 + n], y);
        }
        float val = (y + xcv * Dd) * zv * sigf(zv);
        oph[(size_t)(row >> 1) * 8192 + (size_t)(row & 1) * 2048 + d] = f2h(val);
    }
}

extern "C" void kernel_launch(void* const* d_in, const int* in_sizes, int n_in,
                              void* d_out, int out_size, void* d_ws, size_t ws_size,
                              hipStream_t stream)
{
    const float* x    = (const float*)d_in[0];
    const float* wi   = (const float*)d_in[1];
    const float* cw   = (const float*)d_in[2];
    const float* cb   = (const float*)d_in[3];
    const float* wx   = (const float*)d_in[4];
    const float* wd   = (const float*)d_in[5];
    const float* bd   = (const float*)d_in[6];
    const float* alog = (const float*)d_in[7];
    const float* Dp   = (const float*)d_in[8];
    const float* wo   = (const float*)d_in[9];
    float* out = (float*)d_out;

    float* wsf  = (float*)d_ws;
    float* xz   = wsf;                          // [4096][4096] f32
    float* xc   = xz + (size_t)NROWS * 4096;    // [4096][2048] f32
    float* xdbl = xc + (size_t)NROWS * DIN;     // [4096][96]
    float* dt   = xdbl + (size_t)NROWS * 96;    // [4096][2048] f32

    unsigned short* xzU = (unsigned short*)xz;
    unsigned short* xh  = (unsigned short*)xc;              // dead until conv
    unsigned short* wih = (unsigned short*)dt;              // dead until dtproj writes dt
    unsigned short* dlh = xzU + 0;                          // [4096][64] @ stride 8192 (dead xs cols)
    unsigned short* wdh = xzU + 64;                         // [2048][64] @ stride 8192
    unsigned short* oph = xzU + (size_t)2048 * 8192;        // deadp2 window (dead after pass2)
    unsigned short* woh = (unsigned short*)xc;              // xc dead after pass3

    // 1) fp16 operands of in_proj (fused)
    cvt_in_k<<<8192, 256, 0, stream>>>(x, wi, xh, wih);
    // 2) xz = x @ in_proj_w^T   (M=4096, N=4096, K=1024) — 8-phase 256^2 schedule
    gemm256_h<<<256, 512, 0, stream>>>(xh, wih, xz, 1024, 4096, 16, 1024, 1024);
    // 3) xc = silu(conv(xs)+b)  (overwrites xh — dead)
    conv_silu_k<<<8192, 256, 0, stream>>>(xz, cw, cb, xc);
    // 4) x_dbl: K-split partials (deadp2) then reduce
    xproj_part_k<<<dim3(64, 8), 256, 0, stream>>>(xc, wx, xz);
    xproj_reduce_k<<<1536, 256, 0, stream>>>(xz, xdbl);
    // 5) dt = softplus(dt_low @ Wd^T + bd) on the MFMA pipe (overwrites wih — dead)
    cvt_dt_k<<<384, 256, 0, stream>>>(xdbl, wd, dlh, wdh);
    gemm_mfma_h<<<512, 256, 0, stream>>>(dlh, wdh, dt, 64, 2048, 32, 8192, 16384, 8192, bd);
    // 6) chunked scan; pass3 writes op as fp16 into deadp2 overlay (fused cvt)
    scan_pass1<<<dim3(8, NCH, 2), 256, 0, stream>>>(dt, xc, xdbl, alog, xz);
    scan_pass2<<<256, 256, 0, stream>>>(xz);
    scan_pass3<<<dim3(8, NCH, 2), 256, 0, stream>>>(dt, xc, xz, xdbl, alog, Dp, xz, oph);
    // 7) wo -> fp16 (into xc region — dead after pass3)
    cvt_h_k<<<2048, 256, 0, stream>>>(wo, woh, 524288);
    // 8) out = op @ out_proj_w^T (M=4096, N=1024, K=2048); A via (r>>1)*8192+(r&1)*2048 map
    gemm_mfma_h<<<256, 256, 0, stream>>>(oph, woh, out, 2048, 1024, 32, 2048, 8192, 2048, nullptr);
}

// Round 11
// 255.041 us; speedup vs baseline: 6.2356x; 1.0151x over previous
//
#include <hip/hip_runtime.h>

#define SEQ    2048
#define DIN    2048
#define DMODEL 1024
#define NROWS  4096   // BATCH*SEQ
#define NCH    32     // scan chunks
#define CHL    64     // chunk length

typedef __attribute__((ext_vector_type(8))) _Float16 half8v;
typedef __attribute__((ext_vector_type(4))) float f32x4;

__device__ __forceinline__ float sigf(float x) { return 1.0f / (1.0f + __expf(-x)); }
// inline softplus: no libm call (log1pf is a non-inlined OCML slow path — was a 100 µs pathology)
__device__ __forceinline__ float softplusf(float v) {
    return fmaxf(v, 0.f) + __logf(1.f + __expf(-fabsf(v)));
}

// dead xs-half of xz (rows 0..2047, cols 0..2047): h chunk states (+ dlh/wdh earlier)
__device__ __forceinline__ float* deadp(float* xzbuf, size_t j) {
    return xzbuf + ((j >> 11) << 12) + (j & 2047);
}
// second dead window (rows 2048..4095): ap -> oph (sequential lifetimes)
__device__ __forceinline__ float* deadp2(float* xzbuf, size_t j) {
    return xzbuf + ((size_t)(2048 + (j >> 11)) << 12) + (j & 2047);
}

__device__ __forceinline__ void gload16(const void* g, const void* l) {
    __builtin_amdgcn_global_load_lds((const __attribute__((address_space(1))) void*)g,
                                     (__attribute__((address_space(3))) void*)l, 16, 0, 0);
}

__device__ __forceinline__ unsigned short f2h(float x) {
    _Float16 h = (_Float16)x;           // v_cvt_f16_f32, RNE
    unsigned short u;
    __builtin_memcpy(&u, &h, 2);
    return u;
}
__device__ __forceinline__ float h2f(unsigned short u) {
    _Float16 h;
    __builtin_memcpy(&h, &u, 2);
    return (float)h;
}

// ---------------- fused fp32 -> fp16 convert: x, wi, Wx(zero-padded to 128 rows) ----------
__global__ __launch_bounds__(256) void cvt_in_k(
    const float* __restrict__ x, const float* __restrict__ wi, const float* __restrict__ wx,
    unsigned short* __restrict__ xh, unsigned short* __restrict__ wih,
    unsigned short* __restrict__ wxh)
{
    int i = blockIdx.x * 256 + threadIdx.x;    // 1048576 + 1048576 + 65536
    if (i < 1048576) {
        float4 v = ((const float4*)x)[i];
        ushort4 h; h.x = f2h(v.x); h.y = f2h(v.y); h.z = f2h(v.z); h.w = f2h(v.w);
        ((ushort4*)xh)[i] = h;
    } else if (i < 2097152) {
        i -= 1048576;
        float4 v = ((const float4*)wi)[i];
        ushort4 h; h.x = f2h(v.x); h.y = f2h(v.y); h.z = f2h(v.z); h.w = f2h(v.w);
        ((ushort4*)wih)[i] = h;
    } else if (i < 2162688) {
        i -= 2097152;
        int row = i >> 9, q = i & 511;        // [128][512 x float4]
        ushort4 h;
        if (row < 96) {
            float4 v = ((const float4*)wx)[(size_t)row * 512 + q];
            h.x = f2h(v.x); h.y = f2h(v.y); h.z = f2h(v.z); h.w = f2h(v.w);
        } else h = make_ushort4(0, 0, 0, 0);
        ((ushort4*)wxh)[(size_t)row * 512 + q] = h;
    }
}

// fused cvt: dl (xdbl[:, :64] -> dlh strided), wd -> wdh strided, wo -> woh
__global__ __launch_bounds__(256) void cvt_dt_k(
    const float* __restrict__ xdbl, const float* __restrict__ wd, const float* __restrict__ wo,
    unsigned short* __restrict__ dlh, unsigned short* __restrict__ wdh,
    unsigned short* __restrict__ woh)
{
    int i = blockIdx.x * 256 + threadIdx.x;    // 65536 + 32768 + 524288
    if (i < 65536) {
        int row = i >> 4, q = i & 15;
        float4 v = *(const float4*)(xdbl + (size_t)row * 96 + q * 4);
        ushort4 h; h.x = f2h(v.x); h.y = f2h(v.y); h.z = f2h(v.z); h.w = f2h(v.w);
        *(ushort4*)(dlh + (size_t)row * 8192 + q * 4) = h;
    } else if (i < 98304) {
        i -= 65536;
        int row = i >> 4, q = i & 15;
        float4 v = *(const float4*)(wd + (size_t)row * 64 + q * 4);
        ushort4 h; h.x = f2h(v.x); h.y = f2h(v.y); h.z = f2h(v.z); h.w = f2h(v.w);
        *(ushort4*)(wdh + (size_t)row * 8192 + q * 4) = h;
    } else if (i < 622592) {
        i -= 98304;
        float4 v = ((const float4*)wo)[i];
        ushort4 h; h.x = f2h(v.x); h.y = f2h(v.y); h.z = f2h(v.z); h.w = f2h(v.w);
        ((ushort4*)woh)[i] = h;
    }
}

// ======== 8-phase 256x256 fp16 MFMA GEMM (T2+T3+T4+T5), for large square grids ========
__global__ __launch_bounds__(512, 2) void gemm256_h(
    const unsigned short* __restrict__ A, const unsigned short* __restrict__ W,
    float* __restrict__ C, int K, int N, int mtiles, int lda, int ldw)
{
    __shared__ uint4 ldsu4[8192];          // 128 KiB
    char* lds = (char*)ldsu4;
    const int tid = threadIdx.x;
    const int w = tid >> 6, lane = tid & 63;

    const int nwg = gridDim.x;
    const int cpx = nwg >> 3;
    const int bid = blockIdx.x;
    const int swz = (bid & 7) * cpx + (bid >> 3);
    const int ntiles = nwg / mtiles;
    const int per = 8 * ntiles;
    const int gid = swz / per;
    const int rem = swz - gid * per;
    const int m0 = (gid * 8 + (rem & 7)) * 256;
    const int n0 = (rem >> 3) * 256;

    const int wr = w >> 2, wc = w & 3;
    const int lm = lane & 15, lk = lane >> 4;

    f32x4 acc[8][4];
#pragma unroll
    for (int i = 0; i < 8; ++i)
#pragma unroll
        for (int j = 0; j < 4; ++j) { acc[i][j][0]=0.f; acc[i][j][1]=0.f; acc[i][j][2]=0.f; acc[i][j][3]=0.f; }

    const int rsub = w * 8 + (lane >> 3);
    const int xr8  = ((lane & 7) ^ (lane >> 3)) << 3;
    const unsigned short* gA = A + (size_t)(m0 + rsub) * lda + xr8;
    const unsigned short* gW = W + (size_t)(n0 + rsub) * ldw + xr8;
    const int sdst = w * 1024;

    auto stageA = [&](int bb, int hi, int kt) {
        char* d = lds + bb * 65536 + hi * 16384 + sdst;
        const unsigned short* s = gA + (size_t)hi * 128 * lda + kt;
        gload16(s, d);
        gload16(s + (size_t)64 * lda, d + 8192);
    };
    auto stageB = [&](int bb, int hi, int kt) {
        char* d = lds + bb * 65536 + 32768 + hi * 16384 + sdst;
        const unsigned short* s = gW + (size_t)hi * 128 * ldw + kt;
        gload16(s, d);
        gload16(s + (size_t)64 * ldw, d + 8192);
    };

    half8v a[4][2], b[2][2][2];
    auto loadA = [&](int bb, int mh) {
#pragma unroll
        for (int mb = 0; mb < 4; ++mb)
#pragma unroll
            for (int kk = 0; kk < 2; ++kk) {
                int ar = wr * 128 + (mh * 4 + mb) * 16 + lm;
                a[mb][kk] = *(const half8v*)(lds + bb * 65536 + ar * 128 + (((kk * 4 + lk) ^ (lm & 7)) << 4));
            }
    };
    auto loadB = [&](int bb, int nh) {
#pragma unroll
        for (int nb = 0; nb < 2; ++nb)
#pragma unroll
            for (int kk = 0; kk < 2; ++kk) {
                int br = wc * 64 + (nh * 2 + nb) * 16 + lm;
                b[nh][nb][kk] = *(const half8v*)(lds + bb * 65536 + 32768 + br * 128 + (((kk * 4 + lk) ^ (lm & 7)) << 4));
            }
    };
    auto mm = [&](int mh, int nh) {
        __builtin_amdgcn_s_setprio(1);
#pragma unroll
        for (int mb = 0; mb < 4; ++mb)
#pragma unroll
            for (int nb = 0; nb < 2; ++nb)
#pragma unroll
                for (int kk = 0; kk < 2; ++kk)
                    acc[mh * 4 + mb][nh * 2 + nb] = __builtin_amdgcn_mfma_f32_16x16x32_f16(
                        a[mb][kk], b[nh][nb][kk], acc[mh * 4 + mb][nh * 2 + nb], 0, 0, 0);
        __builtin_amdgcn_s_setprio(0);
    };
#define VMW4() asm volatile("s_waitcnt vmcnt(4)" ::: "memory")
#define BAR()  __builtin_amdgcn_s_barrier()

    stageA(0, 0, 0); stageA(0, 1, 0); stageB(0, 0, 0); stageB(0, 1, 0);
    asm volatile("s_waitcnt vmcnt(0)" ::: "memory");
    BAR();

    const int NT = K >> 6;
    for (int t = 0; t < NT - 1; ++t) {
        const int cur = t & 1, nxt = cur ^ 1;
        const int kt = (t + 1) << 6;
        loadA(cur, 0); loadB(cur, 0);
        stageA(nxt, 0, kt);
        BAR();
        mm(0, 0);
        VMW4(); BAR();
        loadB(cur, 1);
        stageB(nxt, 0, kt);
        BAR();
        mm(0, 1);
        VMW4(); BAR();
        loadA(cur, 1);
        stageB(nxt, 1, kt);
        BAR();
        mm(1, 1);
        VMW4(); BAR();
        stageA(nxt, 1, kt);
        BAR();
        mm(1, 0);
        VMW4(); BAR();
    }
    {
        const int cur = (NT - 1) & 1;
        asm volatile("s_waitcnt vmcnt(0)" ::: "memory");
        BAR();
        loadA(cur, 0); loadB(cur, 0); mm(0, 0);
        loadB(cur, 1); mm(0, 1);
        loadA(cur, 1); mm(1, 1); mm(1, 0);
    }
#undef VMW4
#undef BAR

#pragma unroll
    for (int mb = 0; mb < 8; ++mb)
#pragma unroll
        for (int nb = 0; nb < 4; ++nb)
#pragma unroll
            for (int r = 0; r < 4; ++r)
                C[(size_t)(m0 + wr * 128 + mb * 16 + lk * 4 + r) * N + (n0 + wc * 64 + nb * 16 + lm)] = acc[mb][nb][r];
}

// ---------------- 128x128 fp16 MFMA GEMM (xproj / dtproj / out_proj) ----------------
// A row r at A + (r>>1)*sA2 + (r&1)*sA1. C: [M][ldc], store cols n < nmax only.
#define A_OFF 0
#define W_OFF 16384

__global__ __launch_bounds__(256) void gemm_mfma_h(
    const unsigned short* __restrict__ A, const unsigned short* __restrict__ W,
    float* __restrict__ C, int K, int ldc, int nmax, int mtiles, int sA1, int sA2, int ldw,
    const float* __restrict__ bias)
{
    __shared__ uint4 ldsu4[2048];
    char* lds = (char*)ldsu4;
    const int tid  = threadIdx.x;
    const int w    = tid >> 6, lane = tid & 63;

    const int nwg = gridDim.x;
    const int cpx = nwg >> 3;
    const int bid = blockIdx.x;
    const int swz = (bid & 7) * cpx + (bid >> 3);
    const int ntiles = nwg / mtiles;
    const int per = 8 * ntiles;
    const int gid = swz / per;
    const int rem = swz - gid * per;
    const int m0 = (gid * 8 + (rem & 7)) * 128;
    const int n0 = (rem >> 3) * 128;

    const int wr = w >> 1, wc = w & 1;

    f32x4 acc[4][4];
#pragma unroll
    for (int i = 0; i < 4; ++i)
#pragma unroll
        for (int j = 0; j < 4; ++j) { acc[i][j][0]=0.f; acc[i][j][1]=0.f; acc[i][j][2]=0.f; acc[i][j][3]=0.f; }

    const int rloc = w * 32 + (lane >> 3);
    const int xr8  = ((lane & 7) ^ (lane >> 3)) << 3;
    const int rowA = m0 + rloc;
    const unsigned short* gA = A + (size_t)(rowA >> 1) * sA2 + (size_t)(rowA & 1) * sA1 + xr8;
    const unsigned short* gW = W + (size_t)(n0 + rloc) * ldw + xr8;

    const int lm  = lane & 15;
    const int lk  = lane >> 4;
    const int lk4 = lk * 4;

    for (int kt = 0; kt < K; kt += 64) {
#pragma unroll
        for (int i = 0; i < 4; ++i) {
            const int rb = w * 32 + i * 8;
            gload16(gA + (size_t)i * 4 * sA2 + kt, lds + A_OFF + rb * 128);
            gload16(gW + (size_t)i * 8 * ldw + kt, lds + W_OFF + rb * 128);
        }
        __syncthreads();
#pragma unroll
        for (int h = 0; h < 2; ++h) {
            half8v af[4], wf[4];
            const int ch = h * 4 + lk;
#pragma unroll
            for (int t = 0; t < 4; ++t) {
                const int ar = wr * 64 + t * 16 + lm;
                const int wrw = wc * 64 + t * 16 + lm;
                af[t] = *(const half8v*)(lds + A_OFF + ar * 128 + ((ch ^ (ar & 7)) << 4));
                wf[t] = *(const half8v*)(lds + W_OFF + wrw * 128 + ((ch ^ (wrw & 7)) << 4));
            }
#pragma unroll
            for (int i = 0; i < 4; ++i)
#pragma unroll
                for (int j = 0; j < 4; ++j)
                    acc[i][j] = __builtin_amdgcn_mfma_f32_16x16x32_f16(af[i], wf[j], acc[i][j], 0, 0, 0);
        }
        __syncthreads();
    }

    if (bias) {
#pragma unroll
        for (int j = 0; j < 4; ++j) {
            const int n = n0 + wc * 64 + j * 16 + lm;
            const float bv = (n < nmax) ? bias[n] : 0.f;
#pragma unroll
            for (int i = 0; i < 4; ++i)
#pragma unroll
                for (int r = 0; r < 4; ++r) {
                    float v = acc[i][j][r] + bv;
                    if (n < nmax)
                        C[(size_t)(m0 + wr * 64 + i * 16 + lk4 + r) * ldc + n] = softplusf(v);
                }
        }
    } else {
#pragma unroll
        for (int i = 0; i < 4; ++i)
#pragma unroll
            for (int j = 0; j < 4; ++j) {
                const int n = n0 + wc * 64 + j * 16 + lm;
                if (n < nmax)
#pragma unroll
                    for (int r = 0; r < 4; ++r)
                        C[(size_t)(m0 + wr * 64 + i * 16 + lk4 + r) * ldc + n] = acc[i][j][r];
            }
    }
}

// ---------------- causal depthwise conv(4) + bias + SiLU -> fp16 xch ----------------
__global__ __launch_bounds__(256) void conv_silu_k(
    const float* __restrict__ xz, const float* __restrict__ cw,
    const float* __restrict__ cb, unsigned short* __restrict__ xch)
{
    int i = blockIdx.x * 256 + threadIdx.x;   // NROWS*512
    int d4 = (i & 511) << 2;
    int row = i >> 9;
    int l = row & (SEQ - 1);
    const float* base = xz + (size_t)row * 4096 + d4;
    float4 x0 = *(const float4*)base;
    float4 x1 = (l >= 1) ? *(const float4*)(base - 4096) : make_float4(0, 0, 0, 0);
    float4 x2 = (l >= 2) ? *(const float4*)(base - 8192) : make_float4(0, 0, 0, 0);
    float4 x3 = (l >= 3) ? *(const float4*)(base - 12288) : make_float4(0, 0, 0, 0);
    float4 bv = *(const float4*)(cb + d4);
    ushort4 out;
    unsigned short* op = (unsigned short*)&out;
#pragma unroll
    for (int j = 0; j < 4; ++j) {
        float4 wv = *(const float4*)(cw + (size_t)(d4 + j) * 4);
        float a = ((const float*)&bv)[j];
        a = fmaf(((const float*)&x3)[j], wv.x, a);
        a = fmaf(((const float*)&x2)[j], wv.y, a);
        a = fmaf(((const float*)&x1)[j], wv.z, a);
        a = fmaf(((const float*)&x0)[j], wv.w, a);
        op[j] = f2h(a * sigf(a));
    }
    *(ushort4*)(xch + (size_t)row * DIN + d4) = out;
}

// ---------------- chunked selective scan: register-resident 16-state ----------------
__global__ __launch_bounds__(256) void scan_pass1(
    const float* __restrict__ dt, const unsigned short* __restrict__ xch,
    const float* __restrict__ xdbl, const float* __restrict__ Alog,
    float* __restrict__ xzbuf)
{
    const int b = blockIdx.z, c = blockIdx.y;
    const int d = blockIdx.x * 256 + threadIdx.x;
    float A[16];
#pragma unroll
    for (int q = 0; q < 4; ++q) *(float4*)&A[q * 4] = *(const float4*)&Alog[(size_t)d * 16 + q * 4];
#pragma unroll
    for (int n = 0; n < 16; ++n) A[n] = -__expf(A[n]);
    float h[16] = {}, ap[16];
#pragma unroll
    for (int n = 0; n < 16; ++n) ap[n] = 1.f;
    const int rowbase = b * SEQ + c * CHL;
    for (int t = 0; t < CHL; ++t) {
        const int row = rowbase + t;
        const float* xr = xdbl + (size_t)row * 96;   // wave-uniform -> scalar loads
        float dtv = dt[(size_t)row * DIN + d];
        float xcv = h2f(xch[(size_t)row * DIN + d]);
        float u = dtv * xcv;
#pragma unroll
        for (int n = 0; n < 16; ++n) {
            float dA = __expf(dtv * A[n]);
            h[n] = fmaf(dA, h[n], u * xr[64 + n]);
            ap[n] *= dA;
        }
    }
    size_t e = ((size_t)(b * NCH + c) << 15) + (size_t)d * 16;
#pragma unroll
    for (int q = 0; q < 4; ++q) {
        *(float4*)deadp(xzbuf, e + q * 4)  = *(float4*)&h[q * 4];
        *(float4*)deadp2(xzbuf, e + q * 4) = *(float4*)&ap[q * 4];
    }
}

__global__ __launch_bounds__(256) void scan_pass2(float* __restrict__ xzbuf)
{
    int idx = blockIdx.x * 256 + threadIdx.x;   // 65536
    int b = idx >> 15;
    int dn = idx & 32767;
    float carry = 0.f;
    for (int c = 0; c < NCH; ++c) {
        size_t e = ((size_t)(b * NCH + c) << 15) + dn;
        float* hp = deadp(xzbuf, e);
        float hl = *hp;
        float ap = *deadp2(xzbuf, e);
        *hp = carry;
        carry = fmaf(ap, carry, hl);
    }
}

// pass 3: re-scan from h_in; fused epilogue writes op directly as fp16 into the
// dead deadp2 window (op row r -> xz row 2048+(r>>1), ushort col (r&1)*2048+d).
__global__ __launch_bounds__(256) void scan_pass3(
    const float* __restrict__ dt, const unsigned short* __restrict__ xch,
    const float* __restrict__ xz, const float* __restrict__ xdbl,
    const float* __restrict__ Alog, const float* __restrict__ Dp,
    float* __restrict__ xzbuf, unsigned short* __restrict__ oph)
{
    const int b = blockIdx.z, c = blockIdx.y;
    const int d = blockIdx.x * 256 + threadIdx.x;
    float A[16];
#pragma unroll
    for (int q = 0; q < 4; ++q) *(float4*)&A[q * 4] = *(const float4*)&Alog[(size_t)d * 16 + q * 4];
#pragma unroll
    for (int n = 0; n < 16; ++n) A[n] = -__expf(A[n]);
    float h[16];
    size_t e = ((size_t)(b * NCH + c) << 15) + (size_t)d * 16;
#pragma unroll
    for (int q = 0; q < 4; ++q) *(float4*)&h[q * 4] = *(float4*)deadp(xzbuf, e + q * 4);
    const float Dd = Dp[d];
    const int rowbase = b * SEQ + c * CHL;
    for (int t = 0; t < CHL; ++t) {
        const int row = rowbase + t;
        const float* xr = xdbl + (size_t)row * 96;
        float dtv = dt[(size_t)row * DIN + d];
        float xcv = h2f(xch[(size_t)row * DIN + d]);
        float zv  = xz[(size_t)row * 4096 + DIN + d];
        float u = dtv * xcv;
        float y = 0.f;
#pragma unroll
        for (int n = 0; n < 16; ++n) {
            float dA = __expf(dtv * A[n]);
            h[n] = fmaf(dA, h[n], u * xr[64 + n]);
            y = fmaf(h[n], xr[80 + n], y);
        }
        float val = (y + xcv * Dd) * zv * sigf(zv);
        oph[(size_t)(row >> 1) * 8192 + (size_t)(row & 1) * 2048 + d] = f2h(val);
    }
}

extern "C" void kernel_launch(void* const* d_in, const int* in_sizes, int n_in,
                              void* d_out, int out_size, void* d_ws, size_t ws_size,
                              hipStream_t stream)
{
    const float* x    = (const float*)d_in[0];
    const float* wi   = (const float*)d_in[1];
    const float* cw   = (const float*)d_in[2];
    const float* cb   = (const float*)d_in[3];
    const float* wx   = (const float*)d_in[4];
    const float* wd   = (const float*)d_in[5];
    const float* bd   = (const float*)d_in[6];
    const float* alog = (const float*)d_in[7];
    const float* Dp   = (const float*)d_in[8];
    const float* wo   = (const float*)d_in[9];
    float* out = (float*)d_out;

    float* wsf  = (float*)d_ws;
    float* xz   = wsf;                          // [4096][4096] f32
    float* xc   = xz + (size_t)NROWS * 4096;    // region: 8.4M floats
    float* xdbl = xc + (size_t)NROWS * DIN;     // [4096][96]
    float* dt   = xdbl + (size_t)NROWS * 96;    // [4096][2048] f32

    unsigned short* xzU = (unsigned short*)xz;
    unsigned short* xh  = (unsigned short*)xc;              // A of in_proj; dead after gemm256
    unsigned short* wih = (unsigned short*)dt;              // W of in_proj; dead after gemm256
    unsigned short* wxh = (unsigned short*)dt + 4194304;    // [128][2048] zero-padded Wx
    unsigned short* xch = (unsigned short*)xc;              // [4096][2048] fp16 conv output
    unsigned short* woh = (unsigned short*)xc + 12582912;   // wo fp16 (above xch, disjoint)
    unsigned short* dlh = xzU + 0;                          // [4096][64] @ stride 8192 (dead xs cols)
    unsigned short* wdh = xzU + 64;                         // [2048][64] @ stride 8192
    unsigned short* oph = xzU + (size_t)2048 * 8192;        // deadp2 window (dead after pass2)

    // 1) fp16 operands: x, wi, Wx (zero-padded)
    cvt_in_k<<<8448, 256, 0, stream>>>(x, wi, wx, xh, wih, wxh);
    // 2) xz = x @ in_proj_w^T   (M=4096, N=4096, K=1024) — 8-phase 256^2 schedule
    gemm256_h<<<256, 512, 0, stream>>>(xh, wih, xz, 1024, 4096, 16, 1024, 1024);
    // 3) xch = fp16 silu(conv(xs)+b)  (overwrites xh — dead)
    conv_silu_k<<<8192, 256, 0, stream>>>(xz, cw, cb, xch);
    // 4) x_dbl = xch @ Wx^T on the MFMA pipe (M=4096, N=96->128, K=2048)
    gemm_mfma_h<<<32, 256, 0, stream>>>(xch, wxh, xdbl, 2048, 96, 96, 32, 2048, 4096, 2048, nullptr);
    // 5) dt = softplus(dt_low @ Wd^T + bd); fused cvt also emits woh
    cvt_dt_k<<<2432, 256, 0, stream>>>(xdbl, wd, wo, dlh, wdh, woh);
    gemm_mfma_h<<<512, 256, 0, stream>>>(dlh, wdh, dt, 64, 2048, 2048, 32, 8192, 16384, 8192, bd);
    // 6) chunked scan; pass3 writes op as fp16 into deadp2 overlay (fused cvt)
    scan_pass1<<<dim3(8, NCH, 2), 256, 0, stream>>>(dt, xch, xdbl, alog, xz);
    scan_pass2<<<256, 256, 0, stream>>>(xz);
    scan_pass3<<<dim3(8, NCH, 2), 256, 0, stream>>>(dt, xch, xz, xdbl, alog, Dp, xz, oph);
    // 7) out = op @ out_proj_w^T (M=4096, N=1024, K=2048); A via (r>>1)*8192+(r&1)*2048 map
    gemm_mfma_h<<<256, 256, 0, stream>>>(oph, woh, out, 2048, 1024, 1024, 32, 2048, 8192, 2048, nullptr);
}

// Round 12
// 227.168 us; speedup vs baseline: 7.0007x; 1.1227x over previous
//
#include <hip/hip_runtime.h>

#define SEQ    2048
#define DIN    2048
#define DMODEL 1024
#define NROWS  4096   // BATCH*SEQ
#define NCH    32     // scan chunks
#define CHL    64     // chunk length

typedef __attribute__((ext_vector_type(8))) _Float16 half8v;
typedef __attribute__((ext_vector_type(4))) float f32x4;

__device__ __forceinline__ float sigf(float x) { return 1.0f / (1.0f + __expf(-x)); }
// inline softplus: no libm call (log1pf is a non-inlined OCML slow path — was a 100 µs pathology)
__device__ __forceinline__ float softplusf(float v) {
    return fmaxf(v, 0.f) + __logf(1.f + __expf(-fabsf(v)));
}

// dead xs-half of xz (rows 0..2047, cols 0..2047): h chunk states (+ dlh/wdh earlier)
__device__ __forceinline__ float* deadp(float* xzbuf, size_t j) {
    return xzbuf + ((j >> 11) << 12) + (j & 2047);
}
// second dead window (rows 2048..4095, float cols 0..2047): ap -> oph (sequential lifetimes)
__device__ __forceinline__ float* deadp2(float* xzbuf, size_t j) {
    return xzbuf + ((size_t)(2048 + (j >> 11)) << 12) + (j & 2047);
}

__device__ __forceinline__ void gload16(const void* g, const void* l) {
    __builtin_amdgcn_global_load_lds((const __attribute__((address_space(1))) void*)g,
                                     (__attribute__((address_space(3))) void*)l, 16, 0, 0);
}

__device__ __forceinline__ unsigned short f2h(float x) {
    _Float16 h = (_Float16)x;           // v_cvt_f16_f32, RNE
    unsigned short u;
    __builtin_memcpy(&u, &h, 2);
    return u;
}
__device__ __forceinline__ float h2f(unsigned short u) {
    _Float16 h;
    __builtin_memcpy(&h, &u, 2);
    return (float)h;
}

// ---------------- fused fp32 -> fp16 convert: x, wi, Wx(zero-padded to 128 rows) ----------
__global__ __launch_bounds__(256) void cvt_in_k(
    const float* __restrict__ x, const float* __restrict__ wi, const float* __restrict__ wx,
    unsigned short* __restrict__ xh, unsigned short* __restrict__ wih,
    unsigned short* __restrict__ wxh)
{
    int i = blockIdx.x * 256 + threadIdx.x;    // 1048576 + 1048576 + 65536
    if (i < 1048576) {
        float4 v = ((const float4*)x)[i];
        ushort4 h; h.x = f2h(v.x); h.y = f2h(v.y); h.z = f2h(v.z); h.w = f2h(v.w);
        ((ushort4*)xh)[i] = h;
    } else if (i < 2097152) {
        i -= 1048576;
        float4 v = ((const float4*)wi)[i];
        ushort4 h; h.x = f2h(v.x); h.y = f2h(v.y); h.z = f2h(v.z); h.w = f2h(v.w);
        ((ushort4*)wih)[i] = h;
    } else if (i < 2162688) {
        i -= 2097152;
        int row = i >> 9, q = i & 511;        // [128][512 x float4]
        ushort4 h;
        if (row < 96) {
            float4 v = ((const float4*)wx)[(size_t)row * 512 + q];
            h.x = f2h(v.x); h.y = f2h(v.y); h.z = f2h(v.z); h.w = f2h(v.w);
        } else h = make_ushort4(0, 0, 0, 0);
        ((ushort4*)wxh)[(size_t)row * 512 + q] = h;
    }
}

// fused cvt: dl (xdbl[:, :64] -> dlh strided), wd -> wdh strided, wo -> woh
__global__ __launch_bounds__(256) void cvt_dt_k(
    const float* __restrict__ xdbl, const float* __restrict__ wd, const float* __restrict__ wo,
    unsigned short* __restrict__ dlh, unsigned short* __restrict__ wdh,
    unsigned short* __restrict__ woh)
{
    int i = blockIdx.x * 256 + threadIdx.x;    // 65536 + 32768 + 524288
    if (i < 65536) {
        int row = i >> 4, q = i & 15;
        float4 v = *(const float4*)(xdbl + (size_t)row * 96 + q * 4);
        ushort4 h; h.x = f2h(v.x); h.y = f2h(v.y); h.z = f2h(v.z); h.w = f2h(v.w);
        *(ushort4*)(dlh + (size_t)row * 8192 + q * 4) = h;
    } else if (i < 98304) {
        i -= 65536;
        int row = i >> 4, q = i & 15;
        float4 v = *(const float4*)(wd + (size_t)row * 64 + q * 4);
        ushort4 h; h.x = f2h(v.x); h.y = f2h(v.y); h.z = f2h(v.z); h.w = f2h(v.w);
        *(ushort4*)(wdh + (size_t)row * 8192 + q * 4) = h;
    } else if (i < 622592) {
        i -= 98304;
        float4 v = ((const float4*)wo)[i];
        ushort4 h; h.x = f2h(v.x); h.y = f2h(v.y); h.z = f2h(v.z); h.w = f2h(v.w);
        ((ushort4*)woh)[i] = h;
    }
}

// ======== 8-phase 256x256 fp16 MFMA GEMM (T2+T3+T4+T5) — in_proj ========
__global__ __launch_bounds__(512, 2) void gemm256_h(
    const unsigned short* __restrict__ A, const unsigned short* __restrict__ W,
    float* __restrict__ C, int K, int N, int mtiles, int lda, int ldw)
{
    __shared__ uint4 ldsu4[8192];          // 128 KiB
    char* lds = (char*)ldsu4;
    const int tid = threadIdx.x;
    const int w = tid >> 6, lane = tid & 63;

    const int nwg = gridDim.x;
    const int cpx = nwg >> 3;
    const int bid = blockIdx.x;
    const int swz = (bid & 7) * cpx + (bid >> 3);
    const int ntiles = nwg / mtiles;
    const int per = 8 * ntiles;
    const int gid = swz / per;
    const int rem = swz - gid * per;
    const int m0 = (gid * 8 + (rem & 7)) * 256;
    const int n0 = (rem >> 3) * 256;

    const int wr = w >> 2, wc = w & 3;
    const int lm = lane & 15, lk = lane >> 4;

    f32x4 acc[8][4];
#pragma unroll
    for (int i = 0; i < 8; ++i)
#pragma unroll
        for (int j = 0; j < 4; ++j) { acc[i][j][0]=0.f; acc[i][j][1]=0.f; acc[i][j][2]=0.f; acc[i][j][3]=0.f; }

    const int rsub = w * 8 + (lane >> 3);
    const int xr8  = ((lane & 7) ^ (lane >> 3)) << 3;
    const unsigned short* gA = A + (size_t)(m0 + rsub) * lda + xr8;
    const unsigned short* gW = W + (size_t)(n0 + rsub) * ldw + xr8;
    const int sdst = w * 1024;

    auto stageA = [&](int bb, int hi, int kt) {
        char* d = lds + bb * 65536 + hi * 16384 + sdst;
        const unsigned short* s = gA + (size_t)hi * 128 * lda + kt;
        gload16(s, d);
        gload16(s + (size_t)64 * lda, d + 8192);
    };
    auto stageB = [&](int bb, int hi, int kt) {
        char* d = lds + bb * 65536 + 32768 + hi * 16384 + sdst;
        const unsigned short* s = gW + (size_t)hi * 128 * ldw + kt;
        gload16(s, d);
        gload16(s + (size_t)64 * ldw, d + 8192);
    };

    half8v a[4][2], b[2][2][2];
    auto loadA = [&](int bb, int mh) {
#pragma unroll
        for (int mb = 0; mb < 4; ++mb)
#pragma unroll
            for (int kk = 0; kk < 2; ++kk) {
                int ar = wr * 128 + (mh * 4 + mb) * 16 + lm;
                a[mb][kk] = *(const half8v*)(lds + bb * 65536 + ar * 128 + (((kk * 4 + lk) ^ (lm & 7)) << 4));
            }
    };
    auto loadB = [&](int bb, int nh) {
#pragma unroll
        for (int nb = 0; nb < 2; ++nb)
#pragma unroll
            for (int kk = 0; kk < 2; ++kk) {
                int br = wc * 64 + (nh * 2 + nb) * 16 + lm;
                b[nh][nb][kk] = *(const half8v*)(lds + bb * 65536 + 32768 + br * 128 + (((kk * 4 + lk) ^ (lm & 7)) << 4));
            }
    };
    auto mm = [&](int mh, int nh) {
        __builtin_amdgcn_s_setprio(1);
#pragma unroll
        for (int mb = 0; mb < 4; ++mb)
#pragma unroll
            for (int nb = 0; nb < 2; ++nb)
#pragma unroll
                for (int kk = 0; kk < 2; ++kk)
                    acc[mh * 4 + mb][nh * 2 + nb] = __builtin_amdgcn_mfma_f32_16x16x32_f16(
                        a[mb][kk], b[nh][nb][kk], acc[mh * 4 + mb][nh * 2 + nb], 0, 0, 0);
        __builtin_amdgcn_s_setprio(0);
    };
#define VMW4() asm volatile("s_waitcnt vmcnt(4)" ::: "memory")
#define BAR()  __builtin_amdgcn_s_barrier()

    stageA(0, 0, 0); stageA(0, 1, 0); stageB(0, 0, 0); stageB(0, 1, 0);
    asm volatile("s_waitcnt vmcnt(0)" ::: "memory");
    BAR();

    const int NT = K >> 6;
    for (int t = 0; t < NT - 1; ++t) {
        const int cur = t & 1, nxt = cur ^ 1;
        const int kt = (t + 1) << 6;
        loadA(cur, 0); loadB(cur, 0);
        stageA(nxt, 0, kt);
        BAR();
        mm(0, 0);
        VMW4(); BAR();
        loadB(cur, 1);
        stageB(nxt, 0, kt);
        BAR();
        mm(0, 1);
        VMW4(); BAR();
        loadA(cur, 1);
        stageB(nxt, 1, kt);
        BAR();
        mm(1, 1);
        VMW4(); BAR();
        stageA(nxt, 1, kt);
        BAR();
        mm(1, 0);
        VMW4(); BAR();
    }
    {
        const int cur = (NT - 1) & 1;
        asm volatile("s_waitcnt vmcnt(0)" ::: "memory");
        BAR();
        loadA(cur, 0); loadB(cur, 0); mm(0, 0);
        loadB(cur, 1); mm(0, 1);
        loadA(cur, 1); mm(1, 1); mm(1, 0);
    }
#undef VMW4
#undef BAR

#pragma unroll
    for (int mb = 0; mb < 8; ++mb)
#pragma unroll
        for (int nb = 0; nb < 4; ++nb)
#pragma unroll
            for (int r = 0; r < 4; ++r)
                C[(size_t)(m0 + wr * 128 + mb * 16 + lk * 4 + r) * N + (n0 + wc * 64 + nb * 16 + lm)] = acc[mb][nb][r];
}

// ---------------- 128x128 fp16 MFMA GEMM with split-K (xproj / dtproj / out_proj) ------
// A row r at A + (r>>1)*sA2 + (r&1)*sA1 + ks*K. W row n at W + n*ldw + ks*K.
// Split ks writes C + ks*cstride (fp32 partials, fixed-order reduce downstream).
#define A_OFF 0
#define W_OFF 16384

__global__ __launch_bounds__(256) void gemm_mfma_h(
    const unsigned short* __restrict__ A, const unsigned short* __restrict__ W,
    float* __restrict__ C, int K, int ldc, int nmax, int mtiles, int sA1, int sA2, int ldw,
    const float* __restrict__ bias, int kspl, int cstride)
{
    __shared__ uint4 ldsu4[2048];
    char* lds = (char*)ldsu4;
    const int tid  = threadIdx.x;
    const int w    = tid >> 6, lane = tid & 63;

    const int nwg = gridDim.x;
    const int cpx = nwg >> 3;
    const int bid = blockIdx.x;
    const int swz = (bid & 7) * cpx + (bid >> 3);
    const int nbp = nwg / kspl;            // blocks per split
    const int ks  = swz / nbp;
    const int tt  = swz - ks * nbp;
    const int ntiles = nbp / mtiles;
    const int per = 8 * ntiles;
    const int gid = tt / per;
    const int rem = tt - gid * per;
    const int m0 = (gid * 8 + (rem & 7)) * 128;
    const int n0 = (rem >> 3) * 128;
    const int kOff = ks * K;

    const int wr = w >> 1, wc = w & 1;

    f32x4 acc[4][4];
#pragma unroll
    for (int i = 0; i < 4; ++i)
#pragma unroll
        for (int j = 0; j < 4; ++j) { acc[i][j][0]=0.f; acc[i][j][1]=0.f; acc[i][j][2]=0.f; acc[i][j][3]=0.f; }

    const int rloc = w * 32 + (lane >> 3);
    const int xr8  = ((lane & 7) ^ (lane >> 3)) << 3;
    const int rowA = m0 + rloc;
    const unsigned short* gA = A + (size_t)(rowA >> 1) * sA2 + (size_t)(rowA & 1) * sA1 + kOff + xr8;
    const unsigned short* gW = W + (size_t)(n0 + rloc) * ldw + kOff + xr8;

    const int lm  = lane & 15;
    const int lk  = lane >> 4;
    const int lk4 = lk * 4;

    for (int kt = 0; kt < K; kt += 64) {
#pragma unroll
        for (int i = 0; i < 4; ++i) {
            const int rb = w * 32 + i * 8;
            gload16(gA + (size_t)i * 4 * sA2 + kt, lds + A_OFF + rb * 128);
            gload16(gW + (size_t)i * 8 * ldw + kt, lds + W_OFF + rb * 128);
        }
        __syncthreads();
#pragma unroll
        for (int h = 0; h < 2; ++h) {
            half8v af[4], wf[4];
            const int ch = h * 4 + lk;
#pragma unroll
            for (int t = 0; t < 4; ++t) {
                const int ar = wr * 64 + t * 16 + lm;
                const int wrw = wc * 64 + t * 16 + lm;
                af[t] = *(const half8v*)(lds + A_OFF + ar * 128 + ((ch ^ (ar & 7)) << 4));
                wf[t] = *(const half8v*)(lds + W_OFF + wrw * 128 + ((ch ^ (wrw & 7)) << 4));
            }
#pragma unroll
            for (int i = 0; i < 4; ++i)
#pragma unroll
                for (int j = 0; j < 4; ++j)
                    acc[i][j] = __builtin_amdgcn_mfma_f32_16x16x32_f16(af[i], wf[j], acc[i][j], 0, 0, 0);
        }
        __syncthreads();
    }

    float* Cp = C + (size_t)ks * cstride;
    if (bias) {
#pragma unroll
        for (int j = 0; j < 4; ++j) {
            const int n = n0 + wc * 64 + j * 16 + lm;
            const float bv = (n < nmax) ? bias[n] : 0.f;
#pragma unroll
            for (int i = 0; i < 4; ++i)
#pragma unroll
                for (int r = 0; r < 4; ++r) {
                    float v = acc[i][j][r] + bv;
                    if (n < nmax)
                        Cp[(size_t)(m0 + wr * 64 + i * 16 + lk4 + r) * ldc + n] = softplusf(v);
                }
        }
    } else {
#pragma unroll
        for (int i = 0; i < 4; ++i)
#pragma unroll
            for (int j = 0; j < 4; ++j) {
                const int n = n0 + wc * 64 + j * 16 + lm;
                if (n < nmax)
#pragma unroll
                    for (int r = 0; r < 4; ++r)
                        Cp[(size_t)(m0 + wr * 64 + i * 16 + lk4 + r) * ldc + n] = acc[i][j][r];
            }
    }
}

// xproj partial reduce: xdbl[row][c] = sum_ks part[ks][row][c] (part rows are 128 wide)
__global__ __launch_bounds__(256) void xproj_reduce_k(
    const float* __restrict__ part, float* __restrict__ xdbl)
{
    int i = blockIdx.x * 256 + threadIdx.x;   // 4096*24 float4s
    if (i >= NROWS * 24) return;
    int row = i / 24, q = i - row * 24;
    float4 s = make_float4(0.f, 0.f, 0.f, 0.f);
#pragma unroll
    for (int ks = 0; ks < 8; ++ks) {
        float4 v = *(const float4*)(part + (size_t)ks * (NROWS * 128) + (size_t)row * 128 + q * 4);
        s.x += v.x; s.y += v.y; s.z += v.z; s.w += v.w;
    }
    *(float4*)(xdbl + (size_t)row * 96 + q * 4) = s;
}

// out_proj partial reduce: out = p0 + p1
__global__ __launch_bounds__(256) void out_reduce_k(
    const float* __restrict__ p, float* __restrict__ out)
{
    int i = blockIdx.x * 256 + threadIdx.x;   // 1048576 float4s
    float4 a = ((const float4*)p)[i];
    float4 b = ((const float4*)(p + 4194304))[i];
    a.x += b.x; a.y += b.y; a.z += b.z; a.w += b.w;
    ((float4*)out)[i] = a;
}

// ---------------- causal depthwise conv(4) + bias + SiLU -> fp16 xch ----------------
__global__ __launch_bounds__(256) void conv_silu_k(
    const float* __restrict__ xz, const float* __restrict__ cw,
    const float* __restrict__ cb, unsigned short* __restrict__ xch)
{
    int i = blockIdx.x * 256 + threadIdx.x;   // NROWS*512
    int d4 = (i & 511) << 2;
    int row = i >> 9;
    int l = row & (SEQ - 1);
    const float* base = xz + (size_t)row * 4096 + d4;
    float4 x0 = *(const float4*)base;
    float4 x1 = (l >= 1) ? *(const float4*)(base - 4096) : make_float4(0, 0, 0, 0);
    float4 x2 = (l >= 2) ? *(const float4*)(base - 8192) : make_float4(0, 0, 0, 0);
    float4 x3 = (l >= 3) ? *(const float4*)(base - 12288) : make_float4(0, 0, 0, 0);
    float4 bv = *(const float4*)(cb + d4);
    ushort4 out;
    unsigned short* op = (unsigned short*)&out;
#pragma unroll
    for (int j = 0; j < 4; ++j) {
        float4 wv = *(const float4*)(cw + (size_t)(d4 + j) * 4);
        float a = ((const float*)&bv)[j];
        a = fmaf(((const float*)&x3)[j], wv.x, a);
        a = fmaf(((const float*)&x2)[j], wv.y, a);
        a = fmaf(((const float*)&x1)[j], wv.z, a);
        a = fmaf(((const float*)&x0)[j], wv.w, a);
        op[j] = f2h(a * sigf(a));
    }
    *(ushort4*)(xch + (size_t)row * DIN + d4) = out;
}

// ---------------- chunked selective scan: register-resident 16-state ----------------
__global__ __launch_bounds__(256) void scan_pass1(
    const float* __restrict__ dt, const unsigned short* __restrict__ xch,
    const float* __restrict__ xdbl, const float* __restrict__ Alog,
    float* __restrict__ xzbuf)
{
    const int b = blockIdx.z, c = blockIdx.y;
    const int d = blockIdx.x * 256 + threadIdx.x;
    float A[16];
#pragma unroll
    for (int q = 0; q < 4; ++q) *(float4*)&A[q * 4] = *(const float4*)&Alog[(size_t)d * 16 + q * 4];
#pragma unroll
    for (int n = 0; n < 16; ++n) A[n] = -__expf(A[n]);
    float h[16] = {}, ap[16];
#pragma unroll
    for (int n = 0; n < 16; ++n) ap[n] = 1.f;
    const int rowbase = b * SEQ + c * CHL;
    for (int t = 0; t < CHL; ++t) {
        const int row = rowbase + t;
        const float* xr = xdbl + (size_t)row * 96;   // wave-uniform -> scalar loads
        float dtv = dt[(size_t)row * DIN + d];
        float xcv = h2f(xch[(size_t)row * DIN + d]);
        float u = dtv * xcv;
#pragma unroll
        for (int n = 0; n < 16; ++n) {
            float dA = __expf(dtv * A[n]);
            h[n] = fmaf(dA, h[n], u * xr[64 + n]);
            ap[n] *= dA;
        }
    }
    size_t e = ((size_t)(b * NCH + c) << 15) + (size_t)d * 16;
#pragma unroll
    for (int q = 0; q < 4; ++q) {
        *(float4*)deadp(xzbuf, e + q * 4)  = *(float4*)&h[q * 4];
        *(float4*)deadp2(xzbuf, e + q * 4) = *(float4*)&ap[q * 4];
    }
}

__global__ __launch_bounds__(256) void scan_pass2(float* __restrict__ xzbuf)
{
    int idx = blockIdx.x * 256 + threadIdx.x;   // 65536
    int b = idx >> 15;
    int dn = idx & 32767;
    float carry = 0.f;
    for (int c = 0; c < NCH; ++c) {
        size_t e = ((size_t)(b * NCH + c) << 15) + dn;
        float* hp = deadp(xzbuf, e);
        float hl = *hp;
        float ap = *deadp2(xzbuf, e);
        *hp = carry;
        carry = fmaf(ap, carry, hl);
    }
}

// pass 3: re-scan from h_in; fused epilogue writes op directly as fp16 into the
// dead deadp2 window (op row r -> xz row 2048+(r>>1), ushort col (r&1)*2048+d).
__global__ __launch_bounds__(256) void scan_pass3(
    const float* __restrict__ dt, const unsigned short* __restrict__ xch,
    const float* __restrict__ xz, const float* __restrict__ xdbl,
    const float* __restrict__ Alog, const float* __restrict__ Dp,
    float* __restrict__ xzbuf, unsigned short* __restrict__ oph)
{
    const int b = blockIdx.z, c = blockIdx.y;
    const int d = blockIdx.x * 256 + threadIdx.x;
    float A[16];
#pragma unroll
    for (int q = 0; q < 4; ++q) *(float4*)&A[q * 4] = *(const float4*)&Alog[(size_t)d * 16 + q * 4];
#pragma unroll
    for (int n = 0; n < 16; ++n) A[n] = -__expf(A[n]);
    float h[16];
    size_t e = ((size_t)(b * NCH + c) << 15) + (size_t)d * 16;
#pragma unroll
    for (int q = 0; q < 4; ++q) *(float4*)&h[q * 4] = *(float4*)deadp(xzbuf, e + q * 4);
    const float Dd = Dp[d];
    const int rowbase = b * SEQ + c * CHL;
    for (int t = 0; t < CHL; ++t) {
        const int row = rowbase + t;
        const float* xr = xdbl + (size_t)row * 96;
        float dtv = dt[(size_t)row * DIN + d];
        float xcv = h2f(xch[(size_t)row * DIN + d]);
        float zv  = xz[(size_t)row * 4096 + DIN + d];
        float u = dtv * xcv;
        float y = 0.f;
#pragma unroll
        for (int n = 0; n < 16; ++n) {
            float dA = __expf(dtv * A[n]);
            h[n] = fmaf(dA, h[n], u * xr[64 + n]);
            y = fmaf(h[n], xr[80 + n], y);
        }
        float val = (y + xcv * Dd) * zv * sigf(zv);
        oph[(size_t)(row >> 1) * 8192 + (size_t)(row & 1) * 2048 + d] = f2h(val);
    }
}

extern "C" void kernel_launch(void* const* d_in, const int* in_sizes, int n_in,
                              void* d_out, int out_size, void* d_ws, size_t ws_size,
                              hipStream_t stream)
{
    const float* x    = (const float*)d_in[0];
    const float* wi   = (const float*)d_in[1];
    const float* cw   = (const float*)d_in[2];
    const float* cb   = (const float*)d_in[3];
    const float* wx   = (const float*)d_in[4];
    const float* wd   = (const float*)d_in[5];
    const float* bd   = (const float*)d_in[6];
    const float* alog = (const float*)d_in[7];
    const float* Dp   = (const float*)d_in[8];
    const float* wo   = (const float*)d_in[9];
    float* out = (float*)d_out;

    float* wsf  = (float*)d_ws;
    float* xz   = wsf;                          // [4096][4096] f32
    float* xc   = xz + (size_t)NROWS * 4096;    // region: 8.4M floats
    float* xdbl = xc + (size_t)NROWS * DIN;     // [4096][96]
    float* dt   = xdbl + (size_t)NROWS * 96;    // [4096][2048] f32 region

    unsigned short* xzU = (unsigned short*)xz;
    unsigned short* xh  = (unsigned short*)xc;              // A of in_proj; dead after gemm256
    unsigned short* wih = (unsigned short*)dt;              // W of in_proj; dead after gemm256
    unsigned short* wxh = (unsigned short*)dt + 4194304;    // [128][2048] zero-padded Wx (f32 2.10M-2.23M)
    unsigned short* xch = (unsigned short*)xc;              // [4096][2048] fp16 conv output
    unsigned short* woh = (unsigned short*)xc + 12582912;   // wo fp16 (above xch, disjoint)
    unsigned short* dlh = xzU + 0;                          // [4096][64] @ stride 8192 (dead xs cols)
    unsigned short* wdh = xzU + 64;                         // [2048][64] @ stride 8192
    unsigned short* oph = xzU + (size_t)2048 * 8192;        // deadp2 window (dead after pass2)
    float* xpart = dt + 4194304;                            // [8][4096][128] f32 xproj partials (above wxh)
    float* opart = dt;                                      // [2][4096][1024] f32 out partials (dt dead after pass3)

    // 1) fp16 operands: x, wi, Wx (zero-padded)
    cvt_in_k<<<8448, 256, 0, stream>>>(x, wi, wx, xh, wih, wxh);
    // 2) xz = x @ in_proj_w^T   (M=4096, N=4096, K=1024) — 8-phase 256^2 schedule
    gemm256_h<<<256, 512, 0, stream>>>(xh, wih, xz, 1024, 4096, 16, 1024, 1024);
    // 3) xch = fp16 silu(conv(xs)+b)  (overwrites xh — dead)
    conv_silu_k<<<8192, 256, 0, stream>>>(xz, cw, cb, xch);
    // 4) x_dbl = xch @ Wx^T, split-K 8x256 (partials in dt 2nd half) + reduce
    gemm_mfma_h<<<256, 256, 0, stream>>>(xch, wxh, xpart, 256, 128, 128, 32, 2048, 4096, 2048,
                                         nullptr, 8, NROWS * 128);
    xproj_reduce_k<<<384, 256, 0, stream>>>(xpart, xdbl);
    // 5) dt = softplus(dt_low @ Wd^T + bd); fused cvt also emits woh
    cvt_dt_k<<<2432, 256, 0, stream>>>(xdbl, wd, wo, dlh, wdh, woh);
    gemm_mfma_h<<<512, 256, 0, stream>>>(dlh, wdh, dt, 64, 2048, 2048, 32, 8192, 16384, 8192,
                                         bd, 1, 0);
    // 6) chunked scan; pass3 writes op as fp16 into deadp2 overlay (fused cvt)
    scan_pass1<<<dim3(8, NCH, 2), 256, 0, stream>>>(dt, xch, xdbl, alog, xz);
    scan_pass2<<<256, 256, 0, stream>>>(xz);
    scan_pass3<<<dim3(8, NCH, 2), 256, 0, stream>>>(dt, xch, xz, xdbl, alog, Dp, xz, oph);
    // 7) out = op @ out_proj_w^T, split-K 2x1024 (partials in dead dt region) + reduce
    gemm_mfma_h<<<512, 256, 0, stream>>>(oph, woh, opart, 1024, 1024, 1024, 32, 2048, 8192, 2048,
                                         nullptr, 2, 4194304);
    out_reduce_k<<<4096, 256, 0, stream>>>(opart, out);
}

// Round 13
// 219.434 us; speedup vs baseline: 7.2474x; 1.0352x over previous
//
#include <hip/hip_runtime.h>

#define SEQ    2048
#define DIN    2048
#define DMODEL 1024
#define NROWS  4096   // BATCH*SEQ
#define NCH    32     // scan chunks
#define CHL    64     // chunk length

typedef __attribute__((ext_vector_type(8))) _Float16 half8v;
typedef __attribute__((ext_vector_type(8))) unsigned short ushort8v;
typedef __attribute__((ext_vector_type(4))) float f32x4;

__device__ __forceinline__ float sigf(float x) { return 1.0f / (1.0f + __expf(-x)); }
// inline softplus: no libm call (log1pf is a non-inlined OCML slow path — was a 100 µs pathology)
__device__ __forceinline__ float softplusf(float v) {
    return fmaxf(v, 0.f) + __logf(1.f + __expf(-fabsf(v)));
}

__device__ __forceinline__ void gload16(const void* g, const void* l) {
    __builtin_amdgcn_global_load_lds((const __attribute__((address_space(1))) void*)g,
                                     (__attribute__((address_space(3))) void*)l, 16, 0, 0);
}

__device__ __forceinline__ unsigned short f2h(float x) {
    _Float16 h = (_Float16)x;           // v_cvt_f16_f32, RNE
    unsigned short u;
    __builtin_memcpy(&u, &h, 2);
    return u;
}
__device__ __forceinline__ float h2f(unsigned short u) {
    _Float16 h;
    __builtin_memcpy(&h, &u, 2);
    return (float)h;
}

// ---------------- fused fp32 -> fp16 convert: x, wi, Wx(pad 128), wd, wo ----------------
__global__ __launch_bounds__(256) void cvt_in_k(
    const float* __restrict__ x, const float* __restrict__ wi, const float* __restrict__ wx,
    const float* __restrict__ wd, const float* __restrict__ wo,
    unsigned short* __restrict__ xh, unsigned short* __restrict__ wih,
    unsigned short* __restrict__ wxh, unsigned short* __restrict__ wdh,
    unsigned short* __restrict__ woh)
{
    int i = blockIdx.x * 256 + threadIdx.x;    // 2719744 total float4s
    if (i < 1048576) {
        float4 v = ((const float4*)x)[i];
        ushort4 h; h.x = f2h(v.x); h.y = f2h(v.y); h.z = f2h(v.z); h.w = f2h(v.w);
        ((ushort4*)xh)[i] = h;
    } else if (i < 2097152) {
        i -= 1048576;
        float4 v = ((const float4*)wi)[i];
        ushort4 h; h.x = f2h(v.x); h.y = f2h(v.y); h.z = f2h(v.z); h.w = f2h(v.w);
        ((ushort4*)wih)[i] = h;
    } else if (i < 2162688) {
        i -= 2097152;
        int row = i >> 9, q = i & 511;        // [128][512 x float4]
        ushort4 h;
        if (row < 96) {
            float4 v = ((const float4*)wx)[(size_t)row * 512 + q];
            h.x = f2h(v.x); h.y = f2h(v.y); h.z = f2h(v.z); h.w = f2h(v.w);
        } else h = make_ushort4(0, 0, 0, 0);
        ((ushort4*)wxh)[(size_t)row * 512 + q] = h;
    } else if (i < 2195456) {
        i -= 2162688;                          // wd: 2048x64 -> dense
        float4 v = ((const float4*)wd)[i];
        ushort4 h; h.x = f2h(v.x); h.y = f2h(v.y); h.z = f2h(v.z); h.w = f2h(v.w);
        ((ushort4*)wdh)[i] = h;
    } else {
        i -= 2195456;                          // wo: 1024x2048
        float4 v = ((const float4*)wo)[i];
        ushort4 h; h.x = f2h(v.x); h.y = f2h(v.y); h.z = f2h(v.z); h.w = f2h(v.w);
        ((ushort4*)woh)[i] = h;
    }
}

// ======== 8-phase 256x256 fp16 MFMA GEMM, fp16 output (in_proj) ========
__global__ __launch_bounds__(512, 2) void gemm256_h(
    const unsigned short* __restrict__ A, const unsigned short* __restrict__ W,
    unsigned short* __restrict__ C, int K, int N, int mtiles, int lda, int ldw)
{
    __shared__ uint4 ldsu4[8192];          // 128 KiB
    char* lds = (char*)ldsu4;
    const int tid = threadIdx.x;
    const int w = tid >> 6, lane = tid & 63;

    const int nwg = gridDim.x;
    const int cpx = nwg >> 3;
    const int bid = blockIdx.x;
    const int swz = (bid & 7) * cpx + (bid >> 3);
    const int ntiles = nwg / mtiles;
    const int per = 8 * ntiles;
    const int gid = swz / per;
    const int rem = swz - gid * per;
    const int m0 = (gid * 8 + (rem & 7)) * 256;
    const int n0 = (rem >> 3) * 256;

    const int wr = w >> 2, wc = w & 3;
    const int lm = lane & 15, lk = lane >> 4;

    f32x4 acc[8][4];
#pragma unroll
    for (int i = 0; i < 8; ++i)
#pragma unroll
        for (int j = 0; j < 4; ++j) { acc[i][j][0]=0.f; acc[i][j][1]=0.f; acc[i][j][2]=0.f; acc[i][j][3]=0.f; }

    const int rsub = w * 8 + (lane >> 3);
    const int xr8  = ((lane & 7) ^ (lane >> 3)) << 3;
    const unsigned short* gA = A + (size_t)(m0 + rsub) * lda + xr8;
    const unsigned short* gW = W + (size_t)(n0 + rsub) * ldw + xr8;
    const int sdst = w * 1024;

    auto stageA = [&](int bb, int hi, int kt) {
        char* d = lds + bb * 65536 + hi * 16384 + sdst;
        const unsigned short* s = gA + (size_t)hi * 128 * lda + kt;
        gload16(s, d);
        gload16(s + (size_t)64 * lda, d + 8192);
    };
    auto stageB = [&](int bb, int hi, int kt) {
        char* d = lds + bb * 65536 + 32768 + hi * 16384 + sdst;
        const unsigned short* s = gW + (size_t)hi * 128 * ldw + kt;
        gload16(s, d);
        gload16(s + (size_t)64 * ldw, d + 8192);
    };

    half8v a[4][2], b[2][2][2];
    auto loadA = [&](int bb, int mh) {
#pragma unroll
        for (int mb = 0; mb < 4; ++mb)
#pragma unroll
            for (int kk = 0; kk < 2; ++kk) {
                int ar = wr * 128 + (mh * 4 + mb) * 16 + lm;
                a[mb][kk] = *(const half8v*)(lds + bb * 65536 + ar * 128 + (((kk * 4 + lk) ^ (lm & 7)) << 4));
            }
    };
    auto loadB = [&](int bb, int nh) {
#pragma unroll
        for (int nb = 0; nb < 2; ++nb)
#pragma unroll
            for (int kk = 0; kk < 2; ++kk) {
                int br = wc * 64 + (nh * 2 + nb) * 16 + lm;
                b[nh][nb][kk] = *(const half8v*)(lds + bb * 65536 + 32768 + br * 128 + (((kk * 4 + lk) ^ (lm & 7)) << 4));
            }
    };
    auto mm = [&](int mh, int nh) {
        __builtin_amdgcn_s_setprio(1);
#pragma unroll
        for (int mb = 0; mb < 4; ++mb)
#pragma unroll
            for (int nb = 0; nb < 2; ++nb)
#pragma unroll
                for (int kk = 0; kk < 2; ++kk)
                    acc[mh * 4 + mb][nh * 2 + nb] = __builtin_amdgcn_mfma_f32_16x16x32_f16(
                        a[mb][kk], b[nh][nb][kk], acc[mh * 4 + mb][nh * 2 + nb], 0, 0, 0);
        __builtin_amdgcn_s_setprio(0);
    };
#define VMW4() asm volatile("s_waitcnt vmcnt(4)" ::: "memory")
#define BAR()  __builtin_amdgcn_s_barrier()

    stageA(0, 0, 0); stageA(0, 1, 0); stageB(0, 0, 0); stageB(0, 1, 0);
    asm volatile("s_waitcnt vmcnt(0)" ::: "memory");
    BAR();

    const int NT = K >> 6;
    for (int t = 0; t < NT - 1; ++t) {
        const int cur = t & 1, nxt = cur ^ 1;
        const int kt = (t + 1) << 6;
        loadA(cur, 0); loadB(cur, 0);
        stageA(nxt, 0, kt);
        BAR();
        mm(0, 0);
        VMW4(); BAR();
        loadB(cur, 1);
        stageB(nxt, 0, kt);
        BAR();
        mm(0, 1);
        VMW4(); BAR();
        loadA(cur, 1);
        stageB(nxt, 1, kt);
        BAR();
        mm(1, 1);
        VMW4(); BAR();
        stageA(nxt, 1, kt);
        BAR();
        mm(1, 0);
        VMW4(); BAR();
    }
    {
        const int cur = (NT - 1) & 1;
        asm volatile("s_waitcnt vmcnt(0)" ::: "memory");
        BAR();
        loadA(cur, 0); loadB(cur, 0); mm(0, 0);
        loadB(cur, 1); mm(0, 1);
        loadA(cur, 1); mm(1, 1); mm(1, 0);
    }
#undef VMW4
#undef BAR

#pragma unroll
    for (int mb = 0; mb < 8; ++mb)
#pragma unroll
        for (int nb = 0; nb < 4; ++nb)
#pragma unroll
            for (int r = 0; r < 4; ++r)
                C[(size_t)(m0 + wr * 128 + mb * 16 + lk * 4 + r) * N + (n0 + wc * 64 + nb * 16 + lm)]
                    = f2h(acc[mb][nb][r]);
}

// ---------------- 128x128 fp16 MFMA GEMM with split-K (xproj / dtproj / out_proj) ------
// A row r at A + (r>>1)*sA2 + (r&1)*sA1 + ks*K. W row n at W + n*ldw + ks*K.
#define A_OFF 0
#define W_OFF 16384

__global__ __launch_bounds__(256) void gemm_mfma_h(
    const unsigned short* __restrict__ A, const unsigned short* __restrict__ W,
    float* __restrict__ C, int K, int ldc, int nmax, int mtiles, int sA1, int sA2, int ldw,
    const float* __restrict__ bias, int kspl, int cstride)
{
    __shared__ uint4 ldsu4[2048];
    char* lds = (char*)ldsu4;
    const int tid  = threadIdx.x;
    const int w    = tid >> 6, lane = tid & 63;

    const int nwg = gridDim.x;
    const int cpx = nwg >> 3;
    const int bid = blockIdx.x;
    const int swz = (bid & 7) * cpx + (bid >> 3);
    const int nbp = nwg / kspl;
    const int ks  = swz / nbp;
    const int tt  = swz - ks * nbp;
    const int ntiles = nbp / mtiles;
    const int per = 8 * ntiles;
    const int gid = tt / per;
    const int rem = tt - gid * per;
    const int m0 = (gid * 8 + (rem & 7)) * 128;
    const int n0 = (rem >> 3) * 128;
    const int kOff = ks * K;

    const int wr = w >> 1, wc = w & 1;

    f32x4 acc[4][4];
#pragma unroll
    for (int i = 0; i < 4; ++i)
#pragma unroll
        for (int j = 0; j < 4; ++j) { acc[i][j][0]=0.f; acc[i][j][1]=0.f; acc[i][j][2]=0.f; acc[i][j][3]=0.f; }

    const int rloc = w * 32 + (lane >> 3);
    const int xr8  = ((lane & 7) ^ (lane >> 3)) << 3;
    const int rowA = m0 + rloc;
    const unsigned short* gA = A + (size_t)(rowA >> 1) * sA2 + (size_t)(rowA & 1) * sA1 + kOff + xr8;
    const unsigned short* gW = W + (size_t)(n0 + rloc) * ldw + kOff + xr8;

    const int lm  = lane & 15;
    const int lk  = lane >> 4;
    const int lk4 = lk * 4;

    for (int kt = 0; kt < K; kt += 64) {
#pragma unroll
        for (int i = 0; i < 4; ++i) {
            const int rb = w * 32 + i * 8;
            gload16(gA + (size_t)i * 4 * sA2 + kt, lds + A_OFF + rb * 128);
            gload16(gW + (size_t)i * 8 * ldw + kt, lds + W_OFF + rb * 128);
        }
        __syncthreads();
#pragma unroll
        for (int h = 0; h < 2; ++h) {
            half8v af[4], wf[4];
            const int ch = h * 4 + lk;
#pragma unroll
            for (int t = 0; t < 4; ++t) {
                const int ar = wr * 64 + t * 16 + lm;
                const int wrw = wc * 64 + t * 16 + lm;
                af[t] = *(const half8v*)(lds + A_OFF + ar * 128 + ((ch ^ (ar & 7)) << 4));
                wf[t] = *(const half8v*)(lds + W_OFF + wrw * 128 + ((ch ^ (wrw & 7)) << 4));
            }
#pragma unroll
            for (int i = 0; i < 4; ++i)
#pragma unroll
                for (int j = 0; j < 4; ++j)
                    acc[i][j] = __builtin_amdgcn_mfma_f32_16x16x32_f16(af[i], wf[j], acc[i][j], 0, 0, 0);
        }
        __syncthreads();
    }

    float* Cp = C + (size_t)ks * cstride;
    if (bias) {
#pragma unroll
        for (int j = 0; j < 4; ++j) {
            const int n = n0 + wc * 64 + j * 16 + lm;
            const float bv = (n < nmax) ? bias[n] : 0.f;
#pragma unroll
            for (int i = 0; i < 4; ++i)
#pragma unroll
                for (int r = 0; r < 4; ++r) {
                    float v = acc[i][j][r] + bv;
                    if (n < nmax)
                        Cp[(size_t)(m0 + wr * 64 + i * 16 + lk4 + r) * ldc + n] = softplusf(v);
                }
        }
    } else {
#pragma unroll
        for (int i = 0; i < 4; ++i)
#pragma unroll
            for (int j = 0; j < 4; ++j) {
                const int n = n0 + wc * 64 + j * 16 + lm;
                if (n < nmax)
#pragma unroll
                    for (int r = 0; r < 4; ++r)
                        Cp[(size_t)(m0 + wr * 64 + i * 16 + lk4 + r) * ldc + n] = acc[i][j][r];
            }
    }
}

// xproj reduce: sum 8 partials; cols 0..63 -> dlh fp16 (dense), cols 64..95 -> xdbl f32
__global__ __launch_bounds__(256) void xproj_reduce_k(
    const float* __restrict__ part, float* __restrict__ xdbl, unsigned short* __restrict__ dlh)
{
    int i = blockIdx.x * 256 + threadIdx.x;   // 4096*24 float4s
    if (i >= NROWS * 24) return;
    int row = i / 24, q = i - row * 24;
    float4 s = make_float4(0.f, 0.f, 0.f, 0.f);
#pragma unroll
    for (int ks = 0; ks < 8; ++ks) {
        float4 v = *(const float4*)(part + (size_t)ks * (NROWS * 128) + (size_t)row * 128 + q * 4);
        s.x += v.x; s.y += v.y; s.z += v.z; s.w += v.w;
    }
    if (q < 16) {
        ushort4 h; h.x = f2h(s.x); h.y = f2h(s.y); h.z = f2h(s.z); h.w = f2h(s.w);
        *(ushort4*)(dlh + (size_t)row * 64 + q * 4) = h;
    } else {
        *(float4*)(xdbl + (size_t)row * 96 + q * 4) = s;
    }
}

// out_proj partial reduce: out = p0 + p1
__global__ __launch_bounds__(256) void out_reduce_k(
    const float* __restrict__ p, float* __restrict__ out)
{
    int i = blockIdx.x * 256 + threadIdx.x;   // 1048576 float4s
    float4 a = ((const float4*)p)[i];
    float4 b = ((const float4*)(p + 4194304))[i];
    a.x += b.x; a.y += b.y; a.z += b.z; a.w += b.w;
    ((float4*)out)[i] = a;
}

// ---------------- causal depthwise conv(4) + bias + SiLU, fp16 in -> fp16 out ----------
__global__ __launch_bounds__(256) void conv_silu_k(
    const unsigned short* __restrict__ xzh, const float* __restrict__ cw,
    const float* __restrict__ cb, unsigned short* __restrict__ xch)
{
    int i = blockIdx.x * 256 + threadIdx.x;   // NROWS*256
    int d8 = (i & 255) << 3;
    int row = i >> 8;
    int l = row & (SEQ - 1);
    const unsigned short* base = xzh + (size_t)row * 4096 + d8;
    ushort8v x0 = *(const ushort8v*)base;
    ushort8v x1 = {}, x2 = {}, x3 = {};
    if (l >= 1) x1 = *(const ushort8v*)(base - 4096);
    if (l >= 2) x2 = *(const ushort8v*)(base - 8192);
    if (l >= 3) x3 = *(const ushort8v*)(base - 12288);
    ushort8v out;
#pragma unroll
    for (int j = 0; j < 8; ++j) {
        float4 wv = *(const float4*)(cw + (size_t)(d8 + j) * 4);
        float a = cb[d8 + j];
        a = fmaf(h2f(x3[j]), wv.x, a);
        a = fmaf(h2f(x2[j]), wv.y, a);
        a = fmaf(h2f(x1[j]), wv.z, a);
        a = fmaf(h2f(x0[j]), wv.w, a);
        out[j] = f2h(a * sigf(a));
    }
    *(ushort8v*)(xch + (size_t)row * DIN + d8) = out;
}

// ---------------- chunked selective scan: register-resident 16-state ----------------
// hbuf/apbuf: [2][NCH][2048][16] f32 dense.
__global__ __launch_bounds__(256) void scan_pass1(
    const float* __restrict__ dt, const unsigned short* __restrict__ xch,
    const float* __restrict__ xdbl, const float* __restrict__ Alog,
    float* __restrict__ hbuf, float* __restrict__ apbuf)
{
    const int b = blockIdx.z, c = blockIdx.y;
    const int d = blockIdx.x * 256 + threadIdx.x;
    float A[16];
#pragma unroll
    for (int q = 0; q < 4; ++q) *(float4*)&A[q * 4] = *(const float4*)&Alog[(size_t)d * 16 + q * 4];
#pragma unroll
    for (int n = 0; n < 16; ++n) A[n] = -__expf(A[n]);
    float h[16] = {}, ap[16];
#pragma unroll
    for (int n = 0; n < 16; ++n) ap[n] = 1.f;
    const int rowbase = b * SEQ + c * CHL;
    for (int t = 0; t < CHL; ++t) {
        const int row = rowbase + t;
        const float* xr = xdbl + (size_t)row * 96;   // wave-uniform -> scalar loads
        float dtv = dt[(size_t)row * DIN + d];
        float xcv = h2f(xch[(size_t)row * DIN + d]);
        float u = dtv * xcv;
#pragma unroll
        for (int n = 0; n < 16; ++n) {
            float dA = __expf(dtv * A[n]);
            h[n] = fmaf(dA, h[n], u * xr[64 + n]);
            ap[n] *= dA;
        }
    }
    size_t e = ((size_t)(b * NCH + c) << 15) + (size_t)d * 16;
#pragma unroll
    for (int q = 0; q < 4; ++q) {
        *(float4*)(hbuf + e + q * 4)  = *(float4*)&h[q * 4];
        *(float4*)(apbuf + e + q * 4) = *(float4*)&ap[q * 4];
    }
}

__global__ __launch_bounds__(256) void scan_pass2(
    float* __restrict__ hbuf, const float* __restrict__ apbuf)
{
    int idx = blockIdx.x * 256 + threadIdx.x;   // 65536
    int b = idx >> 15;
    int dn = idx & 32767;
    float carry = 0.f;
    for (int c = 0; c < NCH; ++c) {
        size_t e = ((size_t)(b * NCH + c) << 15) + dn;
        float hl = hbuf[e];
        float ap = apbuf[e];
        hbuf[e] = carry;
        carry = fmaf(ap, carry, hl);
    }
}

// pass 3: re-scan from h_in; fused epilogue writes op fp16 (dense [4096][2048])
__global__ __launch_bounds__(256) void scan_pass3(
    const float* __restrict__ dt, const unsigned short* __restrict__ xch,
    const unsigned short* __restrict__ xzh, const float* __restrict__ xdbl,
    const float* __restrict__ Alog, const float* __restrict__ Dp,
    const float* __restrict__ hbuf, unsigned short* __restrict__ oph)
{
    const int b = blockIdx.z, c = blockIdx.y;
    const int d = blockIdx.x * 256 + threadIdx.x;
    float A[16];
#pragma unroll
    for (int q = 0; q < 4; ++q) *(float4*)&A[q * 4] = *(const float4*)&Alog[(size_t)d * 16 + q * 4];
#pragma unroll
    for (int n = 0; n < 16; ++n) A[n] = -__expf(A[n]);
    float h[16];
    size_t e = ((size_t)(b * NCH + c) << 15) + (size_t)d * 16;
#pragma unroll
    for (int q = 0; q < 4; ++q) *(float4*)&h[q * 4] = *(const float4*)(hbuf + e + q * 4);
    const float Dd = Dp[d];
    const int rowbase = b * SEQ + c * CHL;
    for (int t = 0; t < CHL; ++t) {
        const int row = rowbase + t;
        const float* xr = xdbl + (size_t)row * 96;
        float dtv = dt[(size_t)row * DIN + d];
        float xcv = h2f(xch[(size_t)row * DIN + d]);
        float zv  = h2f(xzh[(size_t)row * 4096 + DIN + d]);
        float u = dtv * xcv;
        float y = 0.f;
#pragma unroll
        for (int n = 0; n < 16; ++n) {
            float dA = __expf(dtv * A[n]);
            h[n] = fmaf(dA, h[n], u * xr[64 + n]);
            y = fmaf(h[n], xr[80 + n], y);
        }
        float val = (y + xcv * Dd) * zv * sigf(zv);
        oph[(size_t)row * DIN + d] = f2h(val);
    }
}

extern "C" void kernel_launch(void* const* d_in, const int* in_sizes, int n_in,
                              void* d_out, int out_size, void* d_ws, size_t ws_size,
                              hipStream_t stream)
{
    const float* x    = (const float*)d_in[0];
    const float* wi   = (const float*)d_in[1];
    const float* cw   = (const float*)d_in[2];
    const float* cb   = (const float*)d_in[3];
    const float* wx   = (const float*)d_in[4];
    const float* wd   = (const float*)d_in[5];
    const float* bd   = (const float*)d_in[6];
    const float* alog = (const float*)d_in[7];
    const float* Dp   = (const float*)d_in[8];
    const float* wo   = (const float*)d_in[9];
    float* out = (float*)d_out;

    float* wsf  = (float*)d_ws;
    float* xzr  = wsf;                          // region 16,777,216 f32
    float* xcr  = wsf + 16777216;               // region  8,388,608 f32
    float* xdbl = wsf + 25165824;               // [4096][96] f32
    float* dt   = wsf + 25559040;               // region  8,388,608 f32

    // xz region: first half = fp16 xz [4096][4096]; second half = clean scratch
    unsigned short* xzh = (unsigned short*)xzr;
    float* scr = xzr + 8388608;
    unsigned short* oph = (unsigned short*)scr;                 // [4096][2048] fp16 (pass3 out)
    float* hbuf         = scr + 4194304;                        // 2,097,152 f32 chunk states
    unsigned short* dlh = (unsigned short*)(scr + 6291456);     // [4096][64] fp16 dense
    unsigned short* wdh = (unsigned short*)(scr + 6422528);     // [2048][64] fp16 dense
    unsigned short* woh = (unsigned short*)(scr + 6488064);     // [1024][2048] fp16

    // xc region: xch fp16 [4096][2048] in first half; ap in the free slot above it
    unsigned short* xh  = (unsigned short*)xcr;                 // in_proj A; dead after gemm256
    unsigned short* xch = (unsigned short*)xcr;                 // conv output (overwrites xh)
    float* apbuf        = xcr + 4194304;                        // 2,097,152 f32 (pass1->pass2)

    // dt region: wih/wxh before dt exists; xpart above wxh; opart after dt dies
    unsigned short* wih = (unsigned short*)dt;                  // in_proj W; dead after gemm256
    unsigned short* wxh = (unsigned short*)dt + 4194304;        // [128][2048] zero-padded Wx
    float* xpart = dt + 4194304;                                // [8][4096][128] f32 partials
    float* opart = dt;                                          // [2][4096][1024] f32 partials

    // 1) fp16 operands: x, wi, Wx(pad), wd, wo
    cvt_in_k<<<10624, 256, 0, stream>>>(x, wi, wx, wd, wo, xh, wih, wxh, wdh, woh);
    // 2) xz = x @ in_proj_w^T  -> fp16 (M=4096, N=4096, K=1024), 8-phase 256^2
    gemm256_h<<<256, 512, 0, stream>>>(xh, wih, xzh, 1024, 4096, 16, 1024, 1024);
    // 3) xch = fp16 silu(conv(xs)+b)  (overwrites xh — dead)
    conv_silu_k<<<4096, 256, 0, stream>>>(xzh, cw, cb, xch);
    // 4) x_dbl = xch @ Wx^T, split-K 8x256 -> partials; reduce emits xdbl f32 + dlh fp16
    gemm_mfma_h<<<256, 256, 0, stream>>>(xch, wxh, xpart, 256, 128, 128, 32, 2048, 4096, 2048,
                                         nullptr, 8, NROWS * 128);
    xproj_reduce_k<<<384, 256, 0, stream>>>(xpart, xdbl, dlh);
    // 5) dt = softplus(dt_low @ Wd^T + bd)  (dense fp16 operands)
    gemm_mfma_h<<<512, 256, 0, stream>>>(dlh, wdh, dt, 64, 2048, 2048, 32, 64, 128, 64,
                                         bd, 1, 0);
    // 6) chunked scan; pass3 writes op fp16 dense
    scan_pass1<<<dim3(8, NCH, 2), 256, 0, stream>>>(dt, xch, xdbl, alog, hbuf, apbuf);
    scan_pass2<<<256, 256, 0, stream>>>(hbuf, apbuf);
    scan_pass3<<<dim3(8, NCH, 2), 256, 0, stream>>>(dt, xch, xzh, xdbl, alog, Dp, hbuf, oph);
    // 7) out = op @ out_proj_w^T, split-K 2x1024 (partials in dead dt region) + reduce
    gemm_mfma_h<<<512, 256, 0, stream>>>(oph, woh, opart, 1024, 1024, 1024, 32, 2048, 4096, 2048,
                                         nullptr, 2, 4194304);
    out_reduce_k<<<4096, 256, 0, stream>>>(opart, out);
}

// Round 14
// 214.935 us; speedup vs baseline: 7.3991x; 1.0209x over previous
//
#include <hip/hip_runtime.h>

#define SEQ    2048
#define DIN    2048
#define DMODEL 1024
#define NROWS  4096   // BATCH*SEQ
#define NCH    32     // scan chunks
#define CHL    64     // chunk length

typedef __attribute__((ext_vector_type(8))) _Float16 half8v;
typedef __attribute__((ext_vector_type(8))) unsigned short ushort8v;
typedef __attribute__((ext_vector_type(4))) float f32x4;

__device__ __forceinline__ float sigf(float x) { return 1.0f / (1.0f + __expf(-x)); }
// inline softplus: no libm call (log1pf is a non-inlined OCML slow path — was a 100 µs pathology)
__device__ __forceinline__ float softplusf(float v) {
    return fmaxf(v, 0.f) + __logf(1.f + __expf(-fabsf(v)));
}

__device__ __forceinline__ void gload16(const void* g, const void* l) {
    __builtin_amdgcn_global_load_lds((const __attribute__((address_space(1))) void*)g,
                                     (__attribute__((address_space(3))) void*)l, 16, 0, 0);
}

__device__ __forceinline__ unsigned short f2h(float x) {
    _Float16 h = (_Float16)x;           // v_cvt_f16_f32, RNE
    unsigned short u;
    __builtin_memcpy(&u, &h, 2);
    return u;
}
__device__ __forceinline__ float h2f(unsigned short u) {
    _Float16 h;
    __builtin_memcpy(&h, &u, 2);
    return (float)h;
}

// ---------------- fused fp32 -> fp16 convert: x, wi, Wx(pad 128), wd, wo ----------------
__global__ __launch_bounds__(256) void cvt_in_k(
    const float* __restrict__ x, const float* __restrict__ wi, const float* __restrict__ wx,
    const float* __restrict__ wd, const float* __restrict__ wo,
    unsigned short* __restrict__ xh, unsigned short* __restrict__ wih,
    unsigned short* __restrict__ wxh, unsigned short* __restrict__ wdh,
    unsigned short* __restrict__ woh)
{
    int i = blockIdx.x * 256 + threadIdx.x;    // 2719744 total float4s
    if (i < 1048576) {
        float4 v = ((const float4*)x)[i];
        ushort4 h; h.x = f2h(v.x); h.y = f2h(v.y); h.z = f2h(v.z); h.w = f2h(v.w);
        ((ushort4*)xh)[i] = h;
    } else if (i < 2097152) {
        i -= 1048576;
        float4 v = ((const float4*)wi)[i];
        ushort4 h; h.x = f2h(v.x); h.y = f2h(v.y); h.z = f2h(v.z); h.w = f2h(v.w);
        ((ushort4*)wih)[i] = h;
    } else if (i < 2162688) {
        i -= 2097152;
        int row = i >> 9, q = i & 511;        // [128][512 x float4]
        ushort4 h;
        if (row < 96) {
            float4 v = ((const float4*)wx)[(size_t)row * 512 + q];
            h.x = f2h(v.x); h.y = f2h(v.y); h.z = f2h(v.z); h.w = f2h(v.w);
        } else h = make_ushort4(0, 0, 0, 0);
        ((ushort4*)wxh)[(size_t)row * 512 + q] = h;
    } else if (i < 2195456) {
        i -= 2162688;                          // wd: 2048x64 dense
        float4 v = ((const float4*)wd)[i];
        ushort4 h; h.x = f2h(v.x); h.y = f2h(v.y); h.z = f2h(v.z); h.w = f2h(v.w);
        ((ushort4*)wdh)[i] = h;
    } else {
        i -= 2195456;                          // wo: 1024x2048
        float4 v = ((const float4*)wo)[i];
        ushort4 h; h.x = f2h(v.x); h.y = f2h(v.y); h.z = f2h(v.z); h.w = f2h(v.w);
        ((ushort4*)woh)[i] = h;
    }
}

// ======== 8-phase 256x256 fp16 MFMA GEMM, fp16 output (in_proj) ========
__global__ __launch_bounds__(512, 2) void gemm256_h(
    const unsigned short* __restrict__ A, const unsigned short* __restrict__ W,
    unsigned short* __restrict__ C, int K, int N, int mtiles, int lda, int ldw)
{
    __shared__ uint4 ldsu4[8192];          // 128 KiB
    char* lds = (char*)ldsu4;
    const int tid = threadIdx.x;
    const int w = tid >> 6, lane = tid & 63;

    const int nwg = gridDim.x;
    const int cpx = nwg >> 3;
    const int bid = blockIdx.x;
    const int swz = (bid & 7) * cpx + (bid >> 3);
    const int ntiles = nwg / mtiles;
    const int per = 8 * ntiles;
    const int gid = swz / per;
    const int rem = swz - gid * per;
    const int m0 = (gid * 8 + (rem & 7)) * 256;
    const int n0 = (rem >> 3) * 256;

    const int wr = w >> 2, wc = w & 3;
    const int lm = lane & 15, lk = lane >> 4;

    f32x4 acc[8][4];
#pragma unroll
    for (int i = 0; i < 8; ++i)
#pragma unroll
        for (int j = 0; j < 4; ++j) { acc[i][j][0]=0.f; acc[i][j][1]=0.f; acc[i][j][2]=0.f; acc[i][j][3]=0.f; }

    const int rsub = w * 8 + (lane >> 3);
    const int xr8  = ((lane & 7) ^ (lane >> 3)) << 3;
    const unsigned short* gA = A + (size_t)(m0 + rsub) * lda + xr8;
    const unsigned short* gW = W + (size_t)(n0 + rsub) * ldw + xr8;
    const int sdst = w * 1024;

    auto stageA = [&](int bb, int hi, int kt) {
        char* d = lds + bb * 65536 + hi * 16384 + sdst;
        const unsigned short* s = gA + (size_t)hi * 128 * lda + kt;
        gload16(s, d);
        gload16(s + (size_t)64 * lda, d + 8192);
    };
    auto stageB = [&](int bb, int hi, int kt) {
        char* d = lds + bb * 65536 + 32768 + hi * 16384 + sdst;
        const unsigned short* s = gW + (size_t)hi * 128 * ldw + kt;
        gload16(s, d);
        gload16(s + (size_t)64 * ldw, d + 8192);
    };

    half8v a[4][2], b[2][2][2];
    auto loadA = [&](int bb, int mh) {
#pragma unroll
        for (int mb = 0; mb < 4; ++mb)
#pragma unroll
            for (int kk = 0; kk < 2; ++kk) {
                int ar = wr * 128 + (mh * 4 + mb) * 16 + lm;
                a[mb][kk] = *(const half8v*)(lds + bb * 65536 + ar * 128 + (((kk * 4 + lk) ^ (lm & 7)) << 4));
            }
    };
    auto loadB = [&](int bb, int nh) {
#pragma unroll
        for (int nb = 0; nb < 2; ++nb)
#pragma unroll
            for (int kk = 0; kk < 2; ++kk) {
                int br = wc * 64 + (nh * 2 + nb) * 16 + lm;
                b[nh][nb][kk] = *(const half8v*)(lds + bb * 65536 + 32768 + br * 128 + (((kk * 4 + lk) ^ (lm & 7)) << 4));
            }
    };
    auto mm = [&](int mh, int nh) {
        __builtin_amdgcn_s_setprio(1);
#pragma unroll
        for (int mb = 0; mb < 4; ++mb)
#pragma unroll
            for (int nb = 0; nb < 2; ++nb)
#pragma unroll
                for (int kk = 0; kk < 2; ++kk)
                    acc[mh * 4 + mb][nh * 2 + nb] = __builtin_amdgcn_mfma_f32_16x16x32_f16(
                        a[mb][kk], b[nh][nb][kk], acc[mh * 4 + mb][nh * 2 + nb], 0, 0, 0);
        __builtin_amdgcn_s_setprio(0);
    };
#define VMW4() asm volatile("s_waitcnt vmcnt(4)" ::: "memory")
#define BAR()  __builtin_amdgcn_s_barrier()

    stageA(0, 0, 0); stageA(0, 1, 0); stageB(0, 0, 0); stageB(0, 1, 0);
    asm volatile("s_waitcnt vmcnt(0)" ::: "memory");
    BAR();

    const int NT = K >> 6;
    for (int t = 0; t < NT - 1; ++t) {
        const int cur = t & 1, nxt = cur ^ 1;
        const int kt = (t + 1) << 6;
        loadA(cur, 0); loadB(cur, 0);
        stageA(nxt, 0, kt);
        BAR();
        mm(0, 0);
        VMW4(); BAR();
        loadB(cur, 1);
        stageB(nxt, 0, kt);
        BAR();
        mm(0, 1);
        VMW4(); BAR();
        loadA(cur, 1);
        stageB(nxt, 1, kt);
        BAR();
        mm(1, 1);
        VMW4(); BAR();
        stageA(nxt, 1, kt);
        BAR();
        mm(1, 0);
        VMW4(); BAR();
    }
    {
        const int cur = (NT - 1) & 1;
        asm volatile("s_waitcnt vmcnt(0)" ::: "memory");
        BAR();
        loadA(cur, 0); loadB(cur, 0); mm(0, 0);
        loadB(cur, 1); mm(0, 1);
        loadA(cur, 1); mm(1, 1); mm(1, 0);
    }
#undef VMW4
#undef BAR

#pragma unroll
    for (int mb = 0; mb < 8; ++mb)
#pragma unroll
        for (int nb = 0; nb < 4; ++nb)
#pragma unroll
            for (int r = 0; r < 4; ++r)
                C[(size_t)(m0 + wr * 128 + mb * 16 + lk * 4 + r) * N + (n0 + wc * 64 + nb * 16 + lm)]
                    = f2h(acc[mb][nb][r]);
}

// ---------------- 128x128 fp16 MFMA GEMM, split-K, fp16 output ----------------
// A row r at A + (r>>1)*sA2 + (r&1)*sA1 + ks*K. W row n at W + n*ldw + ks*K.
// Output fp16 at C + ks*cstride (cstride in ushort elements); optional bias+softplus.
#define A_OFF 0
#define W_OFF 16384

__global__ __launch_bounds__(256) void gemm_mfma_h(
    const unsigned short* __restrict__ A, const unsigned short* __restrict__ W,
    unsigned short* __restrict__ C, int K, int ldc, int nmax, int mtiles,
    int sA1, int sA2, int ldw, const float* __restrict__ bias, int kspl, int cstride)
{
    __shared__ uint4 ldsu4[2048];
    char* lds = (char*)ldsu4;
    const int tid  = threadIdx.x;
    const int w    = tid >> 6, lane = tid & 63;

    const int nwg = gridDim.x;
    const int cpx = nwg >> 3;
    const int bid = blockIdx.x;
    const int swz = (bid & 7) * cpx + (bid >> 3);
    const int nbp = nwg / kspl;
    const int ks  = swz / nbp;
    const int tt  = swz - ks * nbp;
    const int ntiles = nbp / mtiles;
    const int per = 8 * ntiles;
    const int gid = tt / per;
    const int rem = tt - gid * per;
    const int m0 = (gid * 8 + (rem & 7)) * 128;
    const int n0 = (rem >> 3) * 128;
    const int kOff = ks * K;

    const int wr = w >> 1, wc = w & 1;

    f32x4 acc[4][4];
#pragma unroll
    for (int i = 0; i < 4; ++i)
#pragma unroll
        for (int j = 0; j < 4; ++j) { acc[i][j][0]=0.f; acc[i][j][1]=0.f; acc[i][j][2]=0.f; acc[i][j][3]=0.f; }

    const int rloc = w * 32 + (lane >> 3);
    const int xr8  = ((lane & 7) ^ (lane >> 3)) << 3;
    const int rowA = m0 + rloc;
    const unsigned short* gA = A + (size_t)(rowA >> 1) * sA2 + (size_t)(rowA & 1) * sA1 + kOff + xr8;
    const unsigned short* gW = W + (size_t)(n0 + rloc) * ldw + kOff + xr8;

    const int lm  = lane & 15;
    const int lk  = lane >> 4;
    const int lk4 = lk * 4;

    for (int kt = 0; kt < K; kt += 64) {
#pragma unroll
        for (int i = 0; i < 4; ++i) {
            const int rb = w * 32 + i * 8;
            gload16(gA + (size_t)i * 4 * sA2 + kt, lds + A_OFF + rb * 128);
            gload16(gW + (size_t)i * 8 * ldw + kt, lds + W_OFF + rb * 128);
        }
        __syncthreads();
#pragma unroll
        for (int h = 0; h < 2; ++h) {
            half8v af[4], wf[4];
            const int ch = h * 4 + lk;
#pragma unroll
            for (int t = 0; t < 4; ++t) {
                const int ar = wr * 64 + t * 16 + lm;
                const int wrw = wc * 64 + t * 16 + lm;
                af[t] = *(const half8v*)(lds + A_OFF + ar * 128 + ((ch ^ (ar & 7)) << 4));
                wf[t] = *(const half8v*)(lds + W_OFF + wrw * 128 + ((ch ^ (wrw & 7)) << 4));
            }
#pragma unroll
            for (int i = 0; i < 4; ++i)
#pragma unroll
                for (int j = 0; j < 4; ++j)
                    acc[i][j] = __builtin_amdgcn_mfma_f32_16x16x32_f16(af[i], wf[j], acc[i][j], 0, 0, 0);
        }
        __syncthreads();
    }

    unsigned short* Cp = C + (size_t)ks * cstride;
    if (bias) {
#pragma unroll
        for (int j = 0; j < 4; ++j) {
            const int n = n0 + wc * 64 + j * 16 + lm;
            const float bv = (n < nmax) ? bias[n] : 0.f;
#pragma unroll
            for (int i = 0; i < 4; ++i)
#pragma unroll
                for (int r = 0; r < 4; ++r) {
                    float v = acc[i][j][r] + bv;
                    if (n < nmax)
                        Cp[(size_t)(m0 + wr * 64 + i * 16 + lk4 + r) * ldc + n] = f2h(softplusf(v));
                }
        }
    } else {
#pragma unroll
        for (int i = 0; i < 4; ++i)
#pragma unroll
            for (int j = 0; j < 4; ++j) {
                const int n = n0 + wc * 64 + j * 16 + lm;
                if (n < nmax)
#pragma unroll
                    for (int r = 0; r < 4; ++r)
                        Cp[(size_t)(m0 + wr * 64 + i * 16 + lk4 + r) * ldc + n] = f2h(acc[i][j][r]);
            }
    }
}

// xproj reduce: sum 8 fp16 partials; cols 0..63 -> dlh fp16, cols 64..95 -> xdbl f32
__global__ __launch_bounds__(256) void xproj_reduce_k(
    const unsigned short* __restrict__ part, float* __restrict__ xdbl,
    unsigned short* __restrict__ dlh)
{
    int i = blockIdx.x * 256 + threadIdx.x;   // NROWS*32 quads
    if (i >= NROWS * 32) return;
    int row = i >> 5, q = i & 31;
    float s0 = 0.f, s1 = 0.f, s2 = 0.f, s3 = 0.f;
#pragma unroll
    for (int ks = 0; ks < 8; ++ks) {
        ushort4 v = *(const ushort4*)(part + (size_t)ks * (NROWS * 128) + (size_t)row * 128 + q * 4);
        s0 += h2f(v.x); s1 += h2f(v.y); s2 += h2f(v.z); s3 += h2f(v.w);
    }
    if (q < 16) {
        ushort4 h; h.x = f2h(s0); h.y = f2h(s1); h.z = f2h(s2); h.w = f2h(s3);
        *(ushort4*)(dlh + (size_t)row * 64 + q * 4) = h;
    } else {
        *(float4*)(xdbl + (size_t)row * 96 + q * 4) = make_float4(s0, s1, s2, s3);
    }
}

// out_proj partial reduce: out = p0 + p1 (fp16 partials -> f32 out)
__global__ __launch_bounds__(256) void out_reduce_k(
    const unsigned short* __restrict__ p, float* __restrict__ out)
{
    int i = blockIdx.x * 256 + threadIdx.x;   // 1048576 quads (4096*1024/4)
    ushort4 a = ((const ushort4*)p)[i];
    ushort4 b = ((const ushort4*)(p + 4194304))[i];
    float4 v;
    v.x = h2f(a.x) + h2f(b.x);
    v.y = h2f(a.y) + h2f(b.y);
    v.z = h2f(a.z) + h2f(b.z);
    v.w = h2f(a.w) + h2f(b.w);
    ((float4*)out)[i] = v;
}

// ---------------- causal depthwise conv(4) + bias + SiLU, fp16 in -> fp16 out ----------
__global__ __launch_bounds__(256) void conv_silu_k(
    const unsigned short* __restrict__ xzh, const float* __restrict__ cw,
    const float* __restrict__ cb, unsigned short* __restrict__ xch)
{
    int i = blockIdx.x * 256 + threadIdx.x;   // NROWS*256
    int d8 = (i & 255) << 3;
    int row = i >> 8;
    int l = row & (SEQ - 1);
    const unsigned short* base = xzh + (size_t)row * 4096 + d8;
    ushort8v x0 = *(const ushort8v*)base;
    ushort8v x1 = {}, x2 = {}, x3 = {};
    if (l >= 1) x1 = *(const ushort8v*)(base - 4096);
    if (l >= 2) x2 = *(const ushort8v*)(base - 8192);
    if (l >= 3) x3 = *(const ushort8v*)(base - 12288);
    ushort8v out;
#pragma unroll
    for (int j = 0; j < 8; ++j) {
        float4 wv = *(const float4*)(cw + (size_t)(d8 + j) * 4);
        float a = cb[d8 + j];
        a = fmaf(h2f(x3[j]), wv.x, a);
        a = fmaf(h2f(x2[j]), wv.y, a);
        a = fmaf(h2f(x1[j]), wv.z, a);
        a = fmaf(h2f(x0[j]), wv.w, a);
        out[j] = f2h(a * sigf(a));
    }
    *(ushort8v*)(xch + (size_t)row * DIN + d8) = out;
}

// ---------------- chunked selective scan: register-resident 16-state ----------------
__global__ __launch_bounds__(256) void scan_pass1(
    const unsigned short* __restrict__ dth, const unsigned short* __restrict__ xch,
    const float* __restrict__ xdbl, const float* __restrict__ Alog,
    float* __restrict__ hbuf, float* __restrict__ apbuf)
{
    const int b = blockIdx.z, c = blockIdx.y;
    const int d = blockIdx.x * 256 + threadIdx.x;
    float A[16];
#pragma unroll
    for (int q = 0; q < 4; ++q) *(float4*)&A[q * 4] = *(const float4*)&Alog[(size_t)d * 16 + q * 4];
#pragma unroll
    for (int n = 0; n < 16; ++n) A[n] = -__expf(A[n]);
    float h[16] = {}, ap[16];
#pragma unroll
    for (int n = 0; n < 16; ++n) ap[n] = 1.f;
    const int rowbase = b * SEQ + c * CHL;
    for (int t = 0; t < CHL; ++t) {
        const int row = rowbase + t;
        const float* xr = xdbl + (size_t)row * 96;   // wave-uniform -> scalar loads
        float dtv = h2f(dth[(size_t)row * DIN + d]);
        float xcv = h2f(xch[(size_t)row * DIN + d]);
        float u = dtv * xcv;
#pragma unroll
        for (int n = 0; n < 16; ++n) {
            float dA = __expf(dtv * A[n]);
            h[n] = fmaf(dA, h[n], u * xr[64 + n]);
            ap[n] *= dA;
        }
    }
    size_t e = ((size_t)(b * NCH + c) << 15) + (size_t)d * 16;
#pragma unroll
    for (int q = 0; q < 4; ++q) {
        *(float4*)(hbuf + e + q * 4)  = *(float4*)&h[q * 4];
        *(float4*)(apbuf + e + q * 4) = *(float4*)&ap[q * 4];
    }
}

__global__ __launch_bounds__(256) void scan_pass2(
    float* __restrict__ hbuf, const float* __restrict__ apbuf)
{
    int idx = blockIdx.x * 256 + threadIdx.x;   // 65536
    int b = idx >> 15;
    int dn = idx & 32767;
    float carry = 0.f;
    for (int c = 0; c < NCH; ++c) {
        size_t e = ((size_t)(b * NCH + c) << 15) + dn;
        float hl = hbuf[e];
        float ap = apbuf[e];
        hbuf[e] = carry;
        carry = fmaf(ap, carry, hl);
    }
}

// pass 3: re-scan from h_in; fused epilogue writes op fp16 (dense [4096][2048])
__global__ __launch_bounds__(256) void scan_pass3(
    const unsigned short* __restrict__ dth, const unsigned short* __restrict__ xch,
    const unsigned short* __restrict__ xzh, const float* __restrict__ xdbl,
    const float* __restrict__ Alog, const float* __restrict__ Dp,
    const float* __restrict__ hbuf, unsigned short* __restrict__ oph)
{
    const int b = blockIdx.z, c = blockIdx.y;
    const int d = blockIdx.x * 256 + threadIdx.x;
    float A[16];
#pragma unroll
    for (int q = 0; q < 4; ++q) *(float4*)&A[q * 4] = *(const float4*)&Alog[(size_t)d * 16 + q * 4];
#pragma unroll
    for (int n = 0; n < 16; ++n) A[n] = -__expf(A[n]);
    float h[16];
    size_t e = ((size_t)(b * NCH + c) << 15) + (size_t)d * 16;
#pragma unroll
    for (int q = 0; q < 4; ++q) *(float4*)&h[q * 4] = *(const float4*)(hbuf + e + q * 4);
    const float Dd = Dp[d];
    const int rowbase = b * SEQ + c * CHL;
    for (int t = 0; t < CHL; ++t) {
        const int row = rowbase + t;
        const float* xr = xdbl + (size_t)row * 96;
        float dtv = h2f(dth[(size_t)row * DIN + d]);
        float xcv = h2f(xch[(size_t)row * DIN + d]);
        float zv  = h2f(xzh[(size_t)row * 4096 + DIN + d]);
        float u = dtv * xcv;
        float y = 0.f;
#pragma unroll
        for (int n = 0; n < 16; ++n) {
            float dA = __expf(dtv * A[n]);
            h[n] = fmaf(dA, h[n], u * xr[64 + n]);
            y = fmaf(h[n], xr[80 + n], y);
        }
        float val = (y + xcv * Dd) * zv * sigf(zv);
        oph[(size_t)row * DIN + d] = f2h(val);
    }
}

extern "C" void kernel_launch(void* const* d_in, const int* in_sizes, int n_in,
                              void* d_out, int out_size, void* d_ws, size_t ws_size,
                              hipStream_t stream)
{
    const float* x    = (const float*)d_in[0];
    const float* wi   = (const float*)d_in[1];
    const float* cw   = (const float*)d_in[2];
    const float* cb   = (const float*)d_in[3];
    const float* wx   = (const float*)d_in[4];
    const float* wd   = (const float*)d_in[5];
    const float* bd   = (const float*)d_in[6];
    const float* alog = (const float*)d_in[7];
    const float* Dp   = (const float*)d_in[8];
    const float* wo   = (const float*)d_in[9];
    float* out = (float*)d_out;

    float* wsf  = (float*)d_ws;
    float* xzr  = wsf;                          // region 16,777,216 f32
    float* xcr  = wsf + 16777216;               // region  8,388,608 f32
    float* xdbl = wsf + 25165824;               // [4096][96] f32
    float* dtr  = wsf + 25559040;               // region  8,388,608 f32

    // xz region: fp16 xz [4096][4096] in first half; clean scratch in second half
    unsigned short* xzh = (unsigned short*)xzr;
    float* scr = xzr + 8388608;
    unsigned short* oph = (unsigned short*)scr;                 // [4096][2048] fp16 (pass3 out)
    float* hbuf         = scr + 4194304;                        // 2,097,152 f32 chunk states
    unsigned short* dlh = (unsigned short*)(scr + 6291456);     // [4096][64] fp16
    unsigned short* wdh = (unsigned short*)(scr + 6422528);     // [2048][64] fp16
    unsigned short* woh = (unsigned short*)(scr + 6488064);     // [1024][2048] fp16

    // xc region: xch fp16 [4096][2048] in first half; ap above it
    unsigned short* xh  = (unsigned short*)xcr;                 // in_proj A; dead after gemm256
    unsigned short* xch = (unsigned short*)xcr;                 // conv output (overwrites xh)
    float* apbuf        = xcr + 4194304;                        // 2,097,152 f32 (pass1->pass2)

    // dt region (all fp16 now, sequential lifetimes):
    unsigned short* wih    = (unsigned short*)dtr;                 // in_proj W; dead after gemm256
    unsigned short* wxh    = (unsigned short*)dtr + 4194304;      // [128][2048] padded Wx (f32 2.10-2.16M)
    unsigned short* xparth = (unsigned short*)(dtr + 2162688);    // [8][4096][128] fp16; dead after reduce
    unsigned short* dth    = (unsigned short*)dtr;                 // [4096][2048] fp16 dt; dead after pass3
    unsigned short* oparth = (unsigned short*)(dtr + 4194304);    // [2][4096][1024] fp16 out partials

    // 1) fp16 operands: x, wi, Wx(pad), wd, wo
    cvt_in_k<<<10624, 256, 0, stream>>>(x, wi, wx, wd, wo, xh, wih, wxh, wdh, woh);
    // 2) xz = x @ in_proj_w^T  -> fp16 (M=4096, N=4096, K=1024), 8-phase 256^2
    gemm256_h<<<256, 512, 0, stream>>>(xh, wih, xzh, 1024, 4096, 16, 1024, 1024);
    // 3) xch = fp16 silu(conv(xs)+b)  (overwrites xh — dead)
    conv_silu_k<<<4096, 256, 0, stream>>>(xzh, cw, cb, xch);
    // 4) x_dbl = xch @ Wx^T, split-K 8x256 -> fp16 partials; reduce -> xdbl f32 + dlh fp16
    gemm_mfma_h<<<256, 256, 0, stream>>>(xch, wxh, xparth, 256, 128, 128, 32, 2048, 4096, 2048,
                                         nullptr, 8, NROWS * 128);
    xproj_reduce_k<<<512, 256, 0, stream>>>(xparth, xdbl, dlh);
    // 5) dt = fp16 softplus(dt_low @ Wd^T + bd)  (overwrites wih/xparth — both dead)
    gemm_mfma_h<<<512, 256, 0, stream>>>(dlh, wdh, dth, 64, 2048, 2048, 32, 64, 128, 64,
                                         bd, 1, 0);
    // 6) chunked scan; pass3 writes op fp16 dense
    scan_pass1<<<dim3(8, NCH, 2), 256, 0, stream>>>(dth, xch, xdbl, alog, hbuf, apbuf);
    scan_pass2<<<256, 256, 0, stream>>>(hbuf, apbuf);
    scan_pass3<<<dim3(8, NCH, 2), 256, 0, stream>>>(dth, xch, xzh, xdbl, alog, Dp, hbuf, oph);
    // 7) out = op @ out_proj_w^T, split-K 2x1024 -> fp16 partials (dth dead) + reduce
    gemm_mfma_h<<<512, 256, 0, stream>>>(oph, woh, oparth, 1024, 1024, 1024, 32, 2048, 4096, 2048,
                                         nullptr, 2, 4194304);
    out_reduce_k<<<4096, 256, 0, stream>>>(oparth, out);
}

// Round 15
// 194.315 us; speedup vs baseline: 8.1843x; 1.1061x over previous
//
#include <hip/hip_runtime.h>

#define SEQ    2048
#define DIN    2048
#define DMODEL 1024
#define NROWS  4096   // BATCH*SEQ
#define NCH    64     // scan chunks
#define CHL    32     // chunk length

typedef __attribute__((ext_vector_type(8))) _Float16 half8v;
typedef __attribute__((ext_vector_type(8))) unsigned short ushort8v;
typedef __attribute__((ext_vector_type(4))) float f32x4;

__device__ __forceinline__ float sigf(float x) { return 1.0f / (1.0f + __expf(-x)); }
// inline softplus: no libm call (log1pf is a non-inlined OCML slow path — was a 100 µs pathology)
__device__ __forceinline__ float softplusf(float v) {
    return fmaxf(v, 0.f) + __logf(1.f + __expf(-fabsf(v)));
}

__device__ __forceinline__ void gload16(const void* g, const void* l) {
    __builtin_amdgcn_global_load_lds((const __attribute__((address_space(1))) void*)g,
                                     (__attribute__((address_space(3))) void*)l, 16, 0, 0);
}

__device__ __forceinline__ unsigned short f2h(float x) {
    _Float16 h = (_Float16)x;           // v_cvt_f16_f32, RNE
    unsigned short u;
    __builtin_memcpy(&u, &h, 2);
    return u;
}
__device__ __forceinline__ float h2f(unsigned short u) {
    _Float16 h;
    __builtin_memcpy(&h, &u, 2);
    return (float)h;
}

// ---------------- fused fp32 -> fp16 convert: x, wi, Wx(pad 128), wd, wo ----------------
__global__ __launch_bounds__(256) void cvt_in_k(
    const float* __restrict__ x, const float* __restrict__ wi, const float* __restrict__ wx,
    const float* __restrict__ wd, const float* __restrict__ wo,
    unsigned short* __restrict__ xh, unsigned short* __restrict__ wih,
    unsigned short* __restrict__ wxh, unsigned short* __restrict__ wdh,
    unsigned short* __restrict__ woh)
{
    int i = blockIdx.x * 256 + threadIdx.x;    // 2719744 total float4s
    if (i < 1048576) {
        float4 v = ((const float4*)x)[i];
        ushort4 h; h.x = f2h(v.x); h.y = f2h(v.y); h.z = f2h(v.z); h.w = f2h(v.w);
        ((ushort4*)xh)[i] = h;
    } else if (i < 2097152) {
        i -= 1048576;
        float4 v = ((const float4*)wi)[i];
        ushort4 h; h.x = f2h(v.x); h.y = f2h(v.y); h.z = f2h(v.z); h.w = f2h(v.w);
        ((ushort4*)wih)[i] = h;
    } else if (i < 2162688) {
        i -= 2097152;
        int row = i >> 9, q = i & 511;        // [128][512 x float4]
        ushort4 h;
        if (row < 96) {
            float4 v = ((const float4*)wx)[(size_t)row * 512 + q];
            h.x = f2h(v.x); h.y = f2h(v.y); h.z = f2h(v.z); h.w = f2h(v.w);
        } else h = make_ushort4(0, 0, 0, 0);
        ((ushort4*)wxh)[(size_t)row * 512 + q] = h;
    } else if (i < 2195456) {
        i -= 2162688;                          // wd: 2048x64 dense
        float4 v = ((const float4*)wd)[i];
        ushort4 h; h.x = f2h(v.x); h.y = f2h(v.y); h.z = f2h(v.z); h.w = f2h(v.w);
        ((ushort4*)wdh)[i] = h;
    } else {
        i -= 2195456;                          // wo: 1024x2048
        float4 v = ((const float4*)wo)[i];
        ushort4 h; h.x = f2h(v.x); h.y = f2h(v.y); h.z = f2h(v.z); h.w = f2h(v.w);
        ((ushort4*)woh)[i] = h;
    }
}

// ======== 8-phase 256x256 fp16 MFMA GEMM, fp16 output (in_proj) ========
__global__ __launch_bounds__(512, 2) void gemm256_h(
    const unsigned short* __restrict__ A, const unsigned short* __restrict__ W,
    unsigned short* __restrict__ C, int K, int N, int mtiles, int lda, int ldw)
{
    __shared__ uint4 ldsu4[8192];          // 128 KiB
    char* lds = (char*)ldsu4;
    const int tid = threadIdx.x;
    const int w = tid >> 6, lane = tid & 63;

    const int nwg = gridDim.x;
    const int cpx = nwg >> 3;
    const int bid = blockIdx.x;
    const int swz = (bid & 7) * cpx + (bid >> 3);
    const int ntiles = nwg / mtiles;
    const int per = 8 * ntiles;
    const int gid = swz / per;
    const int rem = swz - gid * per;
    const int m0 = (gid * 8 + (rem & 7)) * 256;
    const int n0 = (rem >> 3) * 256;

    const int wr = w >> 2, wc = w & 3;
    const int lm = lane & 15, lk = lane >> 4;

    f32x4 acc[8][4];
#pragma unroll
    for (int i = 0; i < 8; ++i)
#pragma unroll
        for (int j = 0; j < 4; ++j) { acc[i][j][0]=0.f; acc[i][j][1]=0.f; acc[i][j][2]=0.f; acc[i][j][3]=0.f; }

    const int rsub = w * 8 + (lane >> 3);
    const int xr8  = ((lane & 7) ^ (lane >> 3)) << 3;
    const unsigned short* gA = A + (size_t)(m0 + rsub) * lda + xr8;
    const unsigned short* gW = W + (size_t)(n0 + rsub) * ldw + xr8;
    const int sdst = w * 1024;

    auto stageA = [&](int bb, int hi, int kt) {
        char* d = lds + bb * 65536 + hi * 16384 + sdst;
        const unsigned short* s = gA + (size_t)hi * 128 * lda + kt;
        gload16(s, d);
        gload16(s + (size_t)64 * lda, d + 8192);
    };
    auto stageB = [&](int bb, int hi, int kt) {
        char* d = lds + bb * 65536 + 32768 + hi * 16384 + sdst;
        const unsigned short* s = gW + (size_t)hi * 128 * ldw + kt;
        gload16(s, d);
        gload16(s + (size_t)64 * ldw, d + 8192);
    };

    half8v a[4][2], b[2][2][2];
    auto loadA = [&](int bb, int mh) {
#pragma unroll
        for (int mb = 0; mb < 4; ++mb)
#pragma unroll
            for (int kk = 0; kk < 2; ++kk) {
                int ar = wr * 128 + (mh * 4 + mb) * 16 + lm;
                a[mb][kk] = *(const half8v*)(lds + bb * 65536 + ar * 128 + (((kk * 4 + lk) ^ (lm & 7)) << 4));
            }
    };
    auto loadB = [&](int bb, int nh) {
#pragma unroll
        for (int nb = 0; nb < 2; ++nb)
#pragma unroll
            for (int kk = 0; kk < 2; ++kk) {
                int br = wc * 64 + (nh * 2 + nb) * 16 + lm;
                b[nh][nb][kk] = *(const half8v*)(lds + bb * 65536 + 32768 + br * 128 + (((kk * 4 + lk) ^ (lm & 7)) << 4));
            }
    };
    auto mm = [&](int mh, int nh) {
        __builtin_amdgcn_s_setprio(1);
#pragma unroll
        for (int mb = 0; mb < 4; ++mb)
#pragma unroll
            for (int nb = 0; nb < 2; ++nb)
#pragma unroll
                for (int kk = 0; kk < 2; ++kk)
                    acc[mh * 4 + mb][nh * 2 + nb] = __builtin_amdgcn_mfma_f32_16x16x32_f16(
                        a[mb][kk], b[nh][nb][kk], acc[mh * 4 + mb][nh * 2 + nb], 0, 0, 0);
        __builtin_amdgcn_s_setprio(0);
    };
#define VMW4() asm volatile("s_waitcnt vmcnt(4)" ::: "memory")
#define BAR()  __builtin_amdgcn_s_barrier()

    stageA(0, 0, 0); stageA(0, 1, 0); stageB(0, 0, 0); stageB(0, 1, 0);
    asm volatile("s_waitcnt vmcnt(0)" ::: "memory");
    BAR();

    const int NT = K >> 6;
    for (int t = 0; t < NT - 1; ++t) {
        const int cur = t & 1, nxt = cur ^ 1;
        const int kt = (t + 1) << 6;
        loadA(cur, 0); loadB(cur, 0);
        stageA(nxt, 0, kt);
        BAR();
        mm(0, 0);
        VMW4(); BAR();
        loadB(cur, 1);
        stageB(nxt, 0, kt);
        BAR();
        mm(0, 1);
        VMW4(); BAR();
        loadA(cur, 1);
        stageB(nxt, 1, kt);
        BAR();
        mm(1, 1);
        VMW4(); BAR();
        stageA(nxt, 1, kt);
        BAR();
        mm(1, 0);
        VMW4(); BAR();
    }
    {
        const int cur = (NT - 1) & 1;
        asm volatile("s_waitcnt vmcnt(0)" ::: "memory");
        BAR();
        loadA(cur, 0); loadB(cur, 0); mm(0, 0);
        loadB(cur, 1); mm(0, 1);
        loadA(cur, 1); mm(1, 1); mm(1, 0);
    }
#undef VMW4
#undef BAR

#pragma unroll
    for (int mb = 0; mb < 8; ++mb)
#pragma unroll
        for (int nb = 0; nb < 4; ++nb)
#pragma unroll
            for (int r = 0; r < 4; ++r)
                C[(size_t)(m0 + wr * 128 + mb * 16 + lk * 4 + r) * N + (n0 + wc * 64 + nb * 16 + lm)]
                    = f2h(acc[mb][nb][r]);
}

// ---------------- 128x128 fp16 MFMA GEMM, split-K, fp16 output ----------------
#define A_OFF 0
#define W_OFF 16384

__global__ __launch_bounds__(256) void gemm_mfma_h(
    const unsigned short* __restrict__ A, const unsigned short* __restrict__ W,
    unsigned short* __restrict__ C, int K, int ldc, int nmax, int mtiles,
    int sA1, int sA2, int ldw, const float* __restrict__ bias, int kspl, int cstride)
{
    __shared__ uint4 ldsu4[2048];
    char* lds = (char*)ldsu4;
    const int tid  = threadIdx.x;
    const int w    = tid >> 6, lane = tid & 63;

    const int nwg = gridDim.x;
    const int cpx = nwg >> 3;
    const int bid = blockIdx.x;
    const int swz = (bid & 7) * cpx + (bid >> 3);
    const int nbp = nwg / kspl;
    const int ks  = swz / nbp;
    const int tt  = swz - ks * nbp;
    const int ntiles = nbp / mtiles;
    const int per = 8 * ntiles;
    const int gid = tt / per;
    const int rem = tt - gid * per;
    const int m0 = (gid * 8 + (rem & 7)) * 128;
    const int n0 = (rem >> 3) * 128;
    const int kOff = ks * K;

    const int wr = w >> 1, wc = w & 1;

    f32x4 acc[4][4];
#pragma unroll
    for (int i = 0; i < 4; ++i)
#pragma unroll
        for (int j = 0; j < 4; ++j) { acc[i][j][0]=0.f; acc[i][j][1]=0.f; acc[i][j][2]=0.f; acc[i][j][3]=0.f; }

    const int rloc = w * 32 + (lane >> 3);
    const int xr8  = ((lane & 7) ^ (lane >> 3)) << 3;
    const int rowA = m0 + rloc;
    const unsigned short* gA = A + (size_t)(rowA >> 1) * sA2 + (size_t)(rowA & 1) * sA1 + kOff + xr8;
    const unsigned short* gW = W + (size_t)(n0 + rloc) * ldw + kOff + xr8;

    const int lm  = lane & 15;
    const int lk  = lane >> 4;
    const int lk4 = lk * 4;

    for (int kt = 0; kt < K; kt += 64) {
#pragma unroll
        for (int i = 0; i < 4; ++i) {
            const int rb = w * 32 + i * 8;
            gload16(gA + (size_t)i * 4 * sA2 + kt, lds + A_OFF + rb * 128);
            gload16(gW + (size_t)i * 8 * ldw + kt, lds + W_OFF + rb * 128);
        }
        __syncthreads();
#pragma unroll
        for (int h = 0; h < 2; ++h) {
            half8v af[4], wf[4];
            const int ch = h * 4 + lk;
#pragma unroll
            for (int t = 0; t < 4; ++t) {
                const int ar = wr * 64 + t * 16 + lm;
                const int wrw = wc * 64 + t * 16 + lm;
                af[t] = *(const half8v*)(lds + A_OFF + ar * 128 + ((ch ^ (ar & 7)) << 4));
                wf[t] = *(const half8v*)(lds + W_OFF + wrw * 128 + ((ch ^ (wrw & 7)) << 4));
            }
#pragma unroll
            for (int i = 0; i < 4; ++i)
#pragma unroll
                for (int j = 0; j < 4; ++j)
                    acc[i][j] = __builtin_amdgcn_mfma_f32_16x16x32_f16(af[i], wf[j], acc[i][j], 0, 0, 0);
        }
        __syncthreads();
    }

    unsigned short* Cp = C + (size_t)ks * cstride;
    if (bias) {
#pragma unroll
        for (int j = 0; j < 4; ++j) {
            const int n = n0 + wc * 64 + j * 16 + lm;
            const float bv = (n < nmax) ? bias[n] : 0.f;
#pragma unroll
            for (int i = 0; i < 4; ++i)
#pragma unroll
                for (int r = 0; r < 4; ++r) {
                    float v = acc[i][j][r] + bv;
                    if (n < nmax)
                        Cp[(size_t)(m0 + wr * 64 + i * 16 + lk4 + r) * ldc + n] = f2h(softplusf(v));
                }
        }
    } else {
#pragma unroll
        for (int i = 0; i < 4; ++i)
#pragma unroll
            for (int j = 0; j < 4; ++j) {
                const int n = n0 + wc * 64 + j * 16 + lm;
                if (n < nmax)
#pragma unroll
                    for (int r = 0; r < 4; ++r)
                        Cp[(size_t)(m0 + wr * 64 + i * 16 + lk4 + r) * ldc + n] = f2h(acc[i][j][r]);
            }
    }
}

// xproj reduce: sum 8 fp16 partials; cols 0..63 -> dlh fp16, cols 64..95 -> xdbl f32
__global__ __launch_bounds__(256) void xproj_reduce_k(
    const unsigned short* __restrict__ part, float* __restrict__ xdbl,
    unsigned short* __restrict__ dlh)
{
    int i = blockIdx.x * 256 + threadIdx.x;   // NROWS*32 quads
    if (i >= NROWS * 32) return;
    int row = i >> 5, q = i & 31;
    float s0 = 0.f, s1 = 0.f, s2 = 0.f, s3 = 0.f;
#pragma unroll
    for (int ks = 0; ks < 8; ++ks) {
        ushort4 v = *(const ushort4*)(part + (size_t)ks * (NROWS * 128) + (size_t)row * 128 + q * 4);
        s0 += h2f(v.x); s1 += h2f(v.y); s2 += h2f(v.z); s3 += h2f(v.w);
    }
    if (q < 16) {
        ushort4 h; h.x = f2h(s0); h.y = f2h(s1); h.z = f2h(s2); h.w = f2h(s3);
        *(ushort4*)(dlh + (size_t)row * 64 + q * 4) = h;
    } else {
        *(float4*)(xdbl + (size_t)row * 96 + q * 4) = make_float4(s0, s1, s2, s3);
    }
}

// out_proj partial reduce: out = p0 + p1 (fp16 partials -> f32 out)
__global__ __launch_bounds__(256) void out_reduce_k(
    const unsigned short* __restrict__ p, float* __restrict__ out)
{
    int i = blockIdx.x * 256 + threadIdx.x;   // 1048576 quads
    ushort4 a = ((const ushort4*)p)[i];
    ushort4 b = ((const ushort4*)(p + 4194304))[i];
    float4 v;
    v.x = h2f(a.x) + h2f(b.x);
    v.y = h2f(a.y) + h2f(b.y);
    v.z = h2f(a.z) + h2f(b.z);
    v.w = h2f(a.w) + h2f(b.w);
    ((float4*)out)[i] = v;
}

// ---------------- causal depthwise conv(4) + bias + SiLU, fp16 in -> fp16 out ----------
__global__ __launch_bounds__(256) void conv_silu_k(
    const unsigned short* __restrict__ xzh, const float* __restrict__ cw,
    const float* __restrict__ cb, unsigned short* __restrict__ xch)
{
    int i = blockIdx.x * 256 + threadIdx.x;   // NROWS*256
    int d8 = (i & 255) << 3;
    int row = i >> 8;
    int l = row & (SEQ - 1);
    const unsigned short* base = xzh + (size_t)row * 4096 + d8;
    ushort8v x0 = *(const ushort8v*)base;
    ushort8v x1 = {}, x2 = {}, x3 = {};
    if (l >= 1) x1 = *(const ushort8v*)(base - 4096);
    if (l >= 2) x2 = *(const ushort8v*)(base - 8192);
    if (l >= 3) x3 = *(const ushort8v*)(base - 12288);
    ushort8v out;
#pragma unroll
    for (int j = 0; j < 8; ++j) {
        float4 wv = *(const float4*)(cw + (size_t)(d8 + j) * 4);
        float a = cb[d8 + j];
        a = fmaf(h2f(x3[j]), wv.x, a);
        a = fmaf(h2f(x2[j]), wv.y, a);
        a = fmaf(h2f(x1[j]), wv.z, a);
        a = fmaf(h2f(x0[j]), wv.w, a);
        out[j] = f2h(a * sigf(a));
    }
    *(ushort8v*)(xch + (size_t)row * DIN + d8) = out;
}

// ---------------- chunked selective scan: register-resident 16-state ----------------
// A[n] = -(n+1) for the given inputs (A_log = log(tile(arange(1,17)))) -> dA via power
// chain (1 exp + 15 muls, guarded by runtime check; fallback = 16 exps).
__global__ __launch_bounds__(256) void scan_pass1(
    const unsigned short* __restrict__ dth, const unsigned short* __restrict__ xch,
    const float* __restrict__ xdbl, const float* __restrict__ Alog,
    float* __restrict__ hbuf, float* __restrict__ apbuf)
{
    const int b = blockIdx.z, c = blockIdx.y;
    const int d = blockIdx.x * 256 + threadIdx.x;
    float A[16];
#pragma unroll
    for (int q = 0; q < 4; ++q) *(float4*)&A[q * 4] = *(const float4*)&Alog[(size_t)d * 16 + q * 4];
    bool seq = true;
#pragma unroll
    for (int n = 0; n < 16; ++n) {
        A[n] = -__expf(A[n]);
        seq = seq && (fabsf(A[n] + (float)(n + 1)) < 1e-5f * (float)(n + 1));
    }
    float h[16] = {};
    float sumdt = 0.f;
    const int rowbase = b * SEQ + c * CHL;
    int row = rowbase;
    float dtv = h2f(dth[(size_t)row * DIN + d]);
    float xcv = h2f(xch[(size_t)row * DIN + d]);
    if (seq) {
        for (int t = 0; t < CHL; ++t) {
            const int nrow = row + ((t + 1) < CHL ? 1 : 0);
            float dtv2 = h2f(dth[(size_t)nrow * DIN + d]);
            float xcv2 = h2f(xch[(size_t)nrow * DIN + d]);
            const float* xr = xdbl + (size_t)row * 96;
            float u = dtv * xcv;
            sumdt += dtv;
            float r = __expf(-dtv);
            float dA = r;
#pragma unroll
            for (int n = 0; n < 16; ++n) {
                h[n] = fmaf(dA, h[n], u * xr[64 + n]);
                dA *= r;
            }
            dtv = dtv2; xcv = xcv2; row = nrow;
        }
    } else {
        for (int t = 0; t < CHL; ++t) {
            const int nrow = row + ((t + 1) < CHL ? 1 : 0);
            float dtv2 = h2f(dth[(size_t)nrow * DIN + d]);
            float xcv2 = h2f(xch[(size_t)nrow * DIN + d]);
            const float* xr = xdbl + (size_t)row * 96;
            float u = dtv * xcv;
            sumdt += dtv;
#pragma unroll
            for (int n = 0; n < 16; ++n) {
                float dA = __expf(dtv * A[n]);
                h[n] = fmaf(dA, h[n], u * xr[64 + n]);
            }
            dtv = dtv2; xcv = xcv2; row = nrow;
        }
    }
    float ap[16];
    if (seq) {
        float R = __expf(-sumdt);
        float a = R;
#pragma unroll
        for (int n = 0; n < 16; ++n) { ap[n] = a; a *= R; }
    } else {
#pragma unroll
        for (int n = 0; n < 16; ++n) ap[n] = __expf(sumdt * A[n]);
    }
    size_t e = ((size_t)(b * NCH + c) << 15) + (size_t)d * 16;
#pragma unroll
    for (int q = 0; q < 4; ++q) {
        *(float4*)(hbuf + e + q * 4)  = *(float4*)&h[q * 4];
        *(float4*)(apbuf + e + q * 4) = *(float4*)&ap[q * 4];
    }
}

__global__ __launch_bounds__(256) void scan_pass2(
    float* __restrict__ hbuf, const float* __restrict__ apbuf)
{
    int idx = blockIdx.x * 256 + threadIdx.x;   // 65536
    int b = idx >> 15;
    int dn = idx & 32767;
    float carry = 0.f;
    for (int c = 0; c < NCH; ++c) {
        size_t e = ((size_t)(b * NCH + c) << 15) + dn;
        float hl = hbuf[e];
        float ap = apbuf[e];
        hbuf[e] = carry;
        carry = fmaf(ap, carry, hl);
    }
}

// pass 3: re-scan from h_in; fused epilogue writes op fp16 (dense [4096][2048])
__global__ __launch_bounds__(256) void scan_pass3(
    const unsigned short* __restrict__ dth, const unsigned short* __restrict__ xch,
    const unsigned short* __restrict__ xzh, const float* __restrict__ xdbl,
    const float* __restrict__ Alog, const float* __restrict__ Dp,
    const float* __restrict__ hbuf, unsigned short* __restrict__ oph)
{
    const int b = blockIdx.z, c = blockIdx.y;
    const int d = blockIdx.x * 256 + threadIdx.x;
    float A[16];
#pragma unroll
    for (int q = 0; q < 4; ++q) *(float4*)&A[q * 4] = *(const float4*)&Alog[(size_t)d * 16 + q * 4];
    bool seq = true;
#pragma unroll
    for (int n = 0; n < 16; ++n) {
        A[n] = -__expf(A[n]);
        seq = seq && (fabsf(A[n] + (float)(n + 1)) < 1e-5f * (float)(n + 1));
    }
    float h[16];
    size_t e = ((size_t)(b * NCH + c) << 15) + (size_t)d * 16;
#pragma unroll
    for (int q = 0; q < 4; ++q) *(float4*)&h[q * 4] = *(const float4*)(hbuf + e + q * 4);
    const float Dd = Dp[d];
    const int rowbase = b * SEQ + c * CHL;
    int row = rowbase;
    float dtv = h2f(dth[(size_t)row * DIN + d]);
    float xcv = h2f(xch[(size_t)row * DIN + d]);
    float zv  = h2f(xzh[(size_t)row * 4096 + DIN + d]);
    if (seq) {
        for (int t = 0; t < CHL; ++t) {
            const int nrow = row + ((t + 1) < CHL ? 1 : 0);
            float dtv2 = h2f(dth[(size_t)nrow * DIN + d]);
            float xcv2 = h2f(xch[(size_t)nrow * DIN + d]);
            float zv2  = h2f(xzh[(size_t)nrow * 4096 + DIN + d]);
            const float* xr = xdbl + (size_t)row * 96;
            float u = dtv * xcv;
            float r = __expf(-dtv);
            float dA = r;
            float y = 0.f;
#pragma unroll
            for (int n = 0; n < 16; ++n) {
                h[n] = fmaf(dA, h[n], u * xr[64 + n]);
                y = fmaf(h[n], xr[80 + n], y);
                dA *= r;
            }
            float val = (y + xcv * Dd) * zv * sigf(zv);
            oph[(size_t)row * DIN + d] = f2h(val);
            dtv = dtv2; xcv = xcv2; zv = zv2; row = nrow;
        }
    } else {
        for (int t = 0; t < CHL; ++t) {
            const int nrow = row + ((t + 1) < CHL ? 1 : 0);
            float dtv2 = h2f(dth[(size_t)nrow * DIN + d]);
            float xcv2 = h2f(xch[(size_t)nrow * DIN + d]);
            float zv2  = h2f(xzh[(size_t)nrow * 4096 + DIN + d]);
            const float* xr = xdbl + (size_t)row * 96;
            float u = dtv * xcv;
            float y = 0.f;
#pragma unroll
            for (int n = 0; n < 16; ++n) {
                float dA = __expf(dtv * A[n]);
                h[n] = fmaf(dA, h[n], u * xr[64 + n]);
                y = fmaf(h[n], xr[80 + n], y);
            }
            float val = (y + xcv * Dd) * zv * sigf(zv);
            oph[(size_t)row * DIN + d] = f2h(val);
            dtv = dtv2; xcv = xcv2; zv = zv2; row = nrow;
        }
    }
}

extern "C" void kernel_launch(void* const* d_in, const int* in_sizes, int n_in,
                              void* d_out, int out_size, void* d_ws, size_t ws_size,
                              hipStream_t stream)
{
    const float* x    = (const float*)d_in[0];
    const float* wi   = (const float*)d_in[1];
    const float* cw   = (const float*)d_in[2];
    const float* cb   = (const float*)d_in[3];
    const float* wx   = (const float*)d_in[4];
    const float* wd   = (const float*)d_in[5];
    const float* bd   = (const float*)d_in[6];
    const float* alog = (const float*)d_in[7];
    const float* Dp   = (const float*)d_in[8];
    const float* wo   = (const float*)d_in[9];
    float* out = (float*)d_out;

    float* wsf  = (float*)d_ws;
    float* xzr  = wsf;                          // region 16,777,216 f32
    float* xcr  = wsf + 16777216;               // region  8,388,608 f32
    float* xdbl = wsf + 25165824;               // [4096][96] f32
    float* dtr  = wsf + 25559040;               // region  8,388,608 f32

    // xz region: fp16 xz [4096][4096] in first half; oph + hbuf fill the second half
    unsigned short* xzh = (unsigned short*)xzr;
    float* scr = xzr + 8388608;
    unsigned short* oph = (unsigned short*)scr;                 // [4096][2048] fp16
    float* hbuf         = scr + 4194304;                        // 4,194,304 f32 (NCH=64)

    // xc region: xch fp16 first half; apbuf second half
    unsigned short* xh  = (unsigned short*)xcr;                 // in_proj A; dead after gemm256
    unsigned short* xch = (unsigned short*)xcr;                 // conv output (overwrites xh)
    float* apbuf        = xcr + 4194304;                        // 4,194,304 f32 (NCH=64)

    // dt region (sequential lifetimes, all offsets in f32 units):
    unsigned short* wih    = (unsigned short*)dtr;               // [0,4.19M) in_proj W; dead after gemm256
    unsigned short* dth    = (unsigned short*)dtr;               // [0,4.19M) dt fp16; dead after pass3
    unsigned short* oparth = (unsigned short*)dtr;               // [0,4.19M) out partials (after pass3)
    unsigned short* wxh    = (unsigned short*)(dtr + 4194304);   // [4.19M,4.33M) padded Wx
    unsigned short* xparth = (unsigned short*)(dtr + 4325376);   // [4.33M,6.42M) xproj partials
    unsigned short* woh    = (unsigned short*)(dtr + 6422528);   // [6.42M,7.47M) wo fp16
    unsigned short* wdh    = (unsigned short*)(dtr + 7471104);   // [7.47M,7.54M) wd fp16
    unsigned short* dlh    = (unsigned short*)(dtr + 7536640);   // [7.54M,7.67M) dt_low fp16

    // 1) fp16 operands: x, wi, Wx(pad), wd, wo
    cvt_in_k<<<10624, 256, 0, stream>>>(x, wi, wx, wd, wo, xh, wih, wxh, wdh, woh);
    // 2) xz = x @ in_proj_w^T  -> fp16 (M=4096, N=4096, K=1024), 8-phase 256^2
    gemm256_h<<<256, 512, 0, stream>>>(xh, wih, xzh, 1024, 4096, 16, 1024, 1024);
    // 3) xch = fp16 silu(conv(xs)+b)  (overwrites xh — dead)
    conv_silu_k<<<4096, 256, 0, stream>>>(xzh, cw, cb, xch);
    // 4) x_dbl = xch @ Wx^T, split-K 8x256 -> fp16 partials; reduce -> xdbl f32 + dlh fp16
    gemm_mfma_h<<<256, 256, 0, stream>>>(xch, wxh, xparth, 256, 128, 128, 32, 2048, 4096, 2048,
                                         nullptr, 8, NROWS * 128);
    xproj_reduce_k<<<512, 256, 0, stream>>>(xparth, xdbl, dlh);
    // 5) dt = fp16 softplus(dt_low @ Wd^T + bd)  (overwrites wih/xparth region [0,4.19M) only)
    gemm_mfma_h<<<512, 256, 0, stream>>>(dlh, wdh, dth, 64, 2048, 2048, 32, 64, 128, 64,
                                         bd, 1, 0);
    // 6) chunked scan (NCH=64, CHL=32); pass3 writes op fp16 dense
    scan_pass1<<<dim3(8, NCH, 2), 256, 0, stream>>>(dth, xch, xdbl, alog, hbuf, apbuf);
    scan_pass2<<<256, 256, 0, stream>>>(hbuf, apbuf);
    scan_pass3<<<dim3(8, NCH, 2), 256, 0, stream>>>(dth, xch, xzh, xdbl, alog, Dp, hbuf, oph);
    // 7) out = op @ out_proj_w^T, split-K 2x1024 -> fp16 partials (dth dead) + reduce
    gemm_mfma_h<<<512, 256, 0, stream>>>(oph, woh, oparth, 1024, 1024, 1024, 32, 2048, 4096, 2048,
                                         nullptr, 2, 4194304);
    out_reduce_k<<<4096, 256, 0, stream>>>(oparth, out);
}

// Round 16
// 193.734 us; speedup vs baseline: 8.2088x; 1.0030x over previous
//
#include <hip/hip_runtime.h>

#define SEQ    2048
#define DIN    2048
#define DMODEL 1024
#define NROWS  4096   // BATCH*SEQ
#define NCH    64     // scan chunks
#define CHL    32     // chunk length

typedef __attribute__((ext_vector_type(8))) _Float16 half8v;
typedef __attribute__((ext_vector_type(8))) unsigned short ushort8v;
typedef __attribute__((ext_vector_type(4))) float f32x4;

__device__ __forceinline__ float sigf(float x) { return 1.0f / (1.0f + __expf(-x)); }
// inline softplus: no libm call (log1pf is a non-inlined OCML slow path — was a 100 µs pathology)
__device__ __forceinline__ float softplusf(float v) {
    return fmaxf(v, 0.f) + __logf(1.f + __expf(-fabsf(v)));
}

__device__ __forceinline__ void gload16(const void* g, const void* l) {
    __builtin_amdgcn_global_load_lds((const __attribute__((address_space(1))) void*)g,
                                     (__attribute__((address_space(3))) void*)l, 16, 0, 0);
}

__device__ __forceinline__ unsigned short f2h(float x) {
    _Float16 h = (_Float16)x;           // v_cvt_f16_f32, RNE
    unsigned short u;
    __builtin_memcpy(&u, &h, 2);
    return u;
}
__device__ __forceinline__ float h2f(unsigned short u) {
    _Float16 h;
    __builtin_memcpy(&h, &u, 2);
    return (float)h;
}

// ---------------- fused fp32 -> fp16 convert: x, wi, Wx(pad 128), wd, wo ----------------
__global__ __launch_bounds__(256) void cvt_in_k(
    const float* __restrict__ x, const float* __restrict__ wi, const float* __restrict__ wx,
    const float* __restrict__ wd, const float* __restrict__ wo,
    unsigned short* __restrict__ xh, unsigned short* __restrict__ wih,
    unsigned short* __restrict__ wxh, unsigned short* __restrict__ wdh,
    unsigned short* __restrict__ woh)
{
    int i = blockIdx.x * 256 + threadIdx.x;    // 2719744 total float4s
    if (i < 1048576) {
        float4 v = ((const float4*)x)[i];
        ushort4 h; h.x = f2h(v.x); h.y = f2h(v.y); h.z = f2h(v.z); h.w = f2h(v.w);
        ((ushort4*)xh)[i] = h;
    } else if (i < 2097152) {
        i -= 1048576;
        float4 v = ((const float4*)wi)[i];
        ushort4 h; h.x = f2h(v.x); h.y = f2h(v.y); h.z = f2h(v.z); h.w = f2h(v.w);
        ((ushort4*)wih)[i] = h;
    } else if (i < 2162688) {
        i -= 2097152;
        int row = i >> 9, q = i & 511;        // [128][512 x float4]
        ushort4 h;
        if (row < 96) {
            float4 v = ((const float4*)wx)[(size_t)row * 512 + q];
            h.x = f2h(v.x); h.y = f2h(v.y); h.z = f2h(v.z); h.w = f2h(v.w);
        } else h = make_ushort4(0, 0, 0, 0);
        ((ushort4*)wxh)[(size_t)row * 512 + q] = h;
    } else if (i < 2195456) {
        i -= 2162688;                          // wd: 2048x64 dense
        float4 v = ((const float4*)wd)[i];
        ushort4 h; h.x = f2h(v.x); h.y = f2h(v.y); h.z = f2h(v.z); h.w = f2h(v.w);
        ((ushort4*)wdh)[i] = h;
    } else {
        i -= 2195456;                          // wo: 1024x2048
        float4 v = ((const float4*)wo)[i];
        ushort4 h; h.x = f2h(v.x); h.y = f2h(v.y); h.z = f2h(v.z); h.w = f2h(v.w);
        ((ushort4*)woh)[i] = h;
    }
}

// ======== 256x256 fp16 MFMA GEMM, tile-granular counted-vmcnt schedule (in_proj) ========
// Per K-tile: {stage first next-half; vmcnt(2); BAR; ds_reads+4 MFMA quadrants interleaved
// with remaining stages (free-run); BAR}. 2 barriers + 1 counted vmcnt per tile — loads
// stay in flight a full tile (~600+ cyc) before being waited on.
__global__ __launch_bounds__(512, 2) void gemm256_h(
    const unsigned short* __restrict__ A, const unsigned short* __restrict__ W,
    unsigned short* __restrict__ C, int K, int N, int mtiles, int lda, int ldw)
{
    __shared__ uint4 ldsu4[8192];          // 128 KiB
    char* lds = (char*)ldsu4;
    const int tid = threadIdx.x;
    const int w = tid >> 6, lane = tid & 63;

    const int nwg = gridDim.x;
    const int cpx = nwg >> 3;
    const int bid = blockIdx.x;
    const int swz = (bid & 7) * cpx + (bid >> 3);
    const int ntiles = nwg / mtiles;
    const int per = 8 * ntiles;
    const int gid = swz / per;
    const int rem = swz - gid * per;
    const int m0 = (gid * 8 + (rem & 7)) * 256;
    const int n0 = (rem >> 3) * 256;

    const int wr = w >> 2, wc = w & 3;
    const int lm = lane & 15, lk = lane >> 4;

    f32x4 acc[8][4];
#pragma unroll
    for (int i = 0; i < 8; ++i)
#pragma unroll
        for (int j = 0; j < 4; ++j) { acc[i][j][0]=0.f; acc[i][j][1]=0.f; acc[i][j][2]=0.f; acc[i][j][3]=0.f; }

    const int rsub = w * 8 + (lane >> 3);
    const int xr8  = ((lane & 7) ^ (lane >> 3)) << 3;
    const unsigned short* gA = A + (size_t)(m0 + rsub) * lda + xr8;
    const unsigned short* gW = W + (size_t)(n0 + rsub) * ldw + xr8;
    const int sdst = w * 1024;

    auto stageA = [&](int bb, int hi, int kt) {
        char* d = lds + bb * 65536 + hi * 16384 + sdst;
        const unsigned short* s = gA + (size_t)hi * 128 * lda + kt;
        gload16(s, d);
        gload16(s + (size_t)64 * lda, d + 8192);
    };
    auto stageB = [&](int bb, int hi, int kt) {
        char* d = lds + bb * 65536 + 32768 + hi * 16384 + sdst;
        const unsigned short* s = gW + (size_t)hi * 128 * ldw + kt;
        gload16(s, d);
        gload16(s + (size_t)64 * ldw, d + 8192);
    };

    half8v a[4][2], b[2][2][2];
    auto loadA = [&](int bb, int mh) {
#pragma unroll
        for (int mb = 0; mb < 4; ++mb)
#pragma unroll
            for (int kk = 0; kk < 2; ++kk) {
                int ar = wr * 128 + (mh * 4 + mb) * 16 + lm;
                a[mb][kk] = *(const half8v*)(lds + bb * 65536 + ar * 128 + (((kk * 4 + lk) ^ (lm & 7)) << 4));
            }
    };
    auto loadB = [&](int bb, int nh) {
#pragma unroll
        for (int nb = 0; nb < 2; ++nb)
#pragma unroll
            for (int kk = 0; kk < 2; ++kk) {
                int br = wc * 64 + (nh * 2 + nb) * 16 + lm;
                b[nh][nb][kk] = *(const half8v*)(lds + bb * 65536 + 32768 + br * 128 + (((kk * 4 + lk) ^ (lm & 7)) << 4));
            }
    };
    auto mm = [&](int mh, int nh) {
        __builtin_amdgcn_s_setprio(1);
#pragma unroll
        for (int mb = 0; mb < 4; ++mb)
#pragma unroll
            for (int nb = 0; nb < 2; ++nb)
#pragma unroll
                for (int kk = 0; kk < 2; ++kk)
                    acc[mh * 4 + mb][nh * 2 + nb] = __builtin_amdgcn_mfma_f32_16x16x32_f16(
                        a[mb][kk], b[nh][nb][kk], acc[mh * 4 + mb][nh * 2 + nb], 0, 0, 0);
        __builtin_amdgcn_s_setprio(0);
    };
#define BAR()  __builtin_amdgcn_s_barrier()

    // prologue: stage tile 0 fully into buf0, full drain
    stageA(0, 0, 0); stageA(0, 1, 0); stageB(0, 0, 0); stageB(0, 1, 0);
    asm volatile("s_waitcnt vmcnt(0)" ::: "memory");
    BAR();

    const int NT = K >> 6;
    for (int t = 0; t < NT - 1; ++t) {
        const int cur = t & 1, nxt = cur ^ 1;
        const int kt = (t + 1) << 6;
        // tile head: issue first next-tile stage, then guarantee ALL cur loads landed.
        // vmcnt(2): only the 2 loads of stageA(nxt,0) may remain in flight.
        stageA(nxt, 0, kt);
        asm volatile("s_waitcnt vmcnt(2)" ::: "memory");
        BAR();
        // free-run phases: ds_reads of cur + remaining stages of nxt + 4 MFMA quadrants
        loadA(cur, 0); loadB(cur, 0);
        stageB(nxt, 0, kt);
        mm(0, 0);
        loadB(cur, 1);
        stageB(nxt, 1, kt);
        mm(0, 1);
        loadA(cur, 1);
        stageA(nxt, 1, kt);
        mm(1, 1);
        mm(1, 0);
        // tile end: all waves' cur reads are lgkm-complete (consumed by mm) before any
        // wave starts overwriting buf[cur] at the next tile head.
        BAR();
    }
    // epilogue tile NT-1: drain once, then barrier-free compute
    {
        const int cur = (NT - 1) & 1;
        asm volatile("s_waitcnt vmcnt(0)" ::: "memory");
        BAR();
        loadA(cur, 0); loadB(cur, 0); mm(0, 0);
        loadB(cur, 1); mm(0, 1);
        loadA(cur, 1); mm(1, 1); mm(1, 0);
    }
#undef BAR

#pragma unroll
    for (int mb = 0; mb < 8; ++mb)
#pragma unroll
        for (int nb = 0; nb < 4; ++nb)
#pragma unroll
            for (int r = 0; r < 4; ++r)
                C[(size_t)(m0 + wr * 128 + mb * 16 + lk * 4 + r) * N + (n0 + wc * 64 + nb * 16 + lm)]
                    = f2h(acc[mb][nb][r]);
}

// ---------------- 128x128 fp16 MFMA GEMM, split-K, fp16 output ----------------
#define A_OFF 0
#define W_OFF 16384

__global__ __launch_bounds__(256) void gemm_mfma_h(
    const unsigned short* __restrict__ A, const unsigned short* __restrict__ W,
    unsigned short* __restrict__ C, int K, int ldc, int nmax, int mtiles,
    int sA1, int sA2, int ldw, const float* __restrict__ bias, int kspl, int cstride)
{
    __shared__ uint4 ldsu4[2048];
    char* lds = (char*)ldsu4;
    const int tid  = threadIdx.x;
    const int w    = tid >> 6, lane = tid & 63;

    const int nwg = gridDim.x;
    const int cpx = nwg >> 3;
    const int bid = blockIdx.x;
    const int swz = (bid & 7) * cpx + (bid >> 3);
    const int nbp = nwg / kspl;
    const int ks  = swz / nbp;
    const int tt  = swz - ks * nbp;
    const int ntiles = nbp / mtiles;
    const int per = 8 * ntiles;
    const int gid = tt / per;
    const int rem = tt - gid * per;
    const int m0 = (gid * 8 + (rem & 7)) * 128;
    const int n0 = (rem >> 3) * 128;
    const int kOff = ks * K;

    const int wr = w >> 1, wc = w & 1;

    f32x4 acc[4][4];
#pragma unroll
    for (int i = 0; i < 4; ++i)
#pragma unroll
        for (int j = 0; j < 4; ++j) { acc[i][j][0]=0.f; acc[i][j][1]=0.f; acc[i][j][2]=0.f; acc[i][j][3]=0.f; }

    const int rloc = w * 32 + (lane >> 3);
    const int xr8  = ((lane & 7) ^ (lane >> 3)) << 3;
    const int rowA = m0 + rloc;
    const unsigned short* gA = A + (size_t)(rowA >> 1) * sA2 + (size_t)(rowA & 1) * sA1 + kOff + xr8;
    const unsigned short* gW = W + (size_t)(n0 + rloc) * ldw + kOff + xr8;

    const int lm  = lane & 15;
    const int lk  = lane >> 4;
    const int lk4 = lk * 4;

    for (int kt = 0; kt < K; kt += 64) {
#pragma unroll
        for (int i = 0; i < 4; ++i) {
            const int rb = w * 32 + i * 8;
            gload16(gA + (size_t)i * 4 * sA2 + kt, lds + A_OFF + rb * 128);
            gload16(gW + (size_t)i * 8 * ldw + kt, lds + W_OFF + rb * 128);
        }
        __syncthreads();
#pragma unroll
        for (int h = 0; h < 2; ++h) {
            half8v af[4], wf[4];
            const int ch = h * 4 + lk;
#pragma unroll
            for (int t = 0; t < 4; ++t) {
                const int ar = wr * 64 + t * 16 + lm;
                const int wrw = wc * 64 + t * 16 + lm;
                af[t] = *(const half8v*)(lds + A_OFF + ar * 128 + ((ch ^ (ar & 7)) << 4));
                wf[t] = *(const half8v*)(lds + W_OFF + wrw * 128 + ((ch ^ (wrw & 7)) << 4));
            }
#pragma unroll
            for (int i = 0; i < 4; ++i)
#pragma unroll
                for (int j = 0; j < 4; ++j)
                    acc[i][j] = __builtin_amdgcn_mfma_f32_16x16x32_f16(af[i], wf[j], acc[i][j], 0, 0, 0);
        }
        __syncthreads();
    }

    unsigned short* Cp = C + (size_t)ks * cstride;
    if (bias) {
#pragma unroll
        for (int j = 0; j < 4; ++j) {
            const int n = n0 + wc * 64 + j * 16 + lm;
            const float bv = (n < nmax) ? bias[n] : 0.f;
#pragma unroll
            for (int i = 0; i < 4; ++i)
#pragma unroll
                for (int r = 0; r < 4; ++r) {
                    float v = acc[i][j][r] + bv;
                    if (n < nmax)
                        Cp[(size_t)(m0 + wr * 64 + i * 16 + lk4 + r) * ldc + n] = f2h(softplusf(v));
                }
        }
    } else {
#pragma unroll
        for (int i = 0; i < 4; ++i)
#pragma unroll
            for (int j = 0; j < 4; ++j) {
                const int n = n0 + wc * 64 + j * 16 + lm;
                if (n < nmax)
#pragma unroll
                    for (int r = 0; r < 4; ++r)
                        Cp[(size_t)(m0 + wr * 64 + i * 16 + lk4 + r) * ldc + n] = f2h(acc[i][j][r]);
            }
    }
}

// xproj reduce: sum 8 fp16 partials; cols 0..63 -> dlh fp16, cols 64..95 -> xdbl f32
__global__ __launch_bounds__(256) void xproj_reduce_k(
    const unsigned short* __restrict__ part, float* __restrict__ xdbl,
    unsigned short* __restrict__ dlh)
{
    int i = blockIdx.x * 256 + threadIdx.x;   // NROWS*32 quads
    if (i >= NROWS * 32) return;
    int row = i >> 5, q = i & 31;
    float s0 = 0.f, s1 = 0.f, s2 = 0.f, s3 = 0.f;
#pragma unroll
    for (int ks = 0; ks < 8; ++ks) {
        ushort4 v = *(const ushort4*)(part + (size_t)ks * (NROWS * 128) + (size_t)row * 128 + q * 4);
        s0 += h2f(v.x); s1 += h2f(v.y); s2 += h2f(v.z); s3 += h2f(v.w);
    }
    if (q < 16) {
        ushort4 h; h.x = f2h(s0); h.y = f2h(s1); h.z = f2h(s2); h.w = f2h(s3);
        *(ushort4*)(dlh + (size_t)row * 64 + q * 4) = h;
    } else {
        *(float4*)(xdbl + (size_t)row * 96 + q * 4) = make_float4(s0, s1, s2, s3);
    }
}

// out_proj partial reduce: out = p0 + p1 (fp16 partials -> f32 out)
__global__ __launch_bounds__(256) void out_reduce_k(
    const unsigned short* __restrict__ p, float* __restrict__ out)
{
    int i = blockIdx.x * 256 + threadIdx.x;   // 1048576 quads
    ushort4 a = ((const ushort4*)p)[i];
    ushort4 b = ((const ushort4*)(p + 4194304))[i];
    float4 v;
    v.x = h2f(a.x) + h2f(b.x);
    v.y = h2f(a.y) + h2f(b.y);
    v.z = h2f(a.z) + h2f(b.z);
    v.w = h2f(a.w) + h2f(b.w);
    ((float4*)out)[i] = v;
}

// ---------------- causal depthwise conv(4) + bias + SiLU, fp16 in -> fp16 out ----------
__global__ __launch_bounds__(256) void conv_silu_k(
    const unsigned short* __restrict__ xzh, const float* __restrict__ cw,
    const float* __restrict__ cb, unsigned short* __restrict__ xch)
{
    int i = blockIdx.x * 256 + threadIdx.x;   // NROWS*256
    int d8 = (i & 255) << 3;
    int row = i >> 8;
    int l = row & (SEQ - 1);
    const unsigned short* base = xzh + (size_t)row * 4096 + d8;
    ushort8v x0 = *(const ushort8v*)base;
    ushort8v x1 = {}, x2 = {}, x3 = {};
    if (l >= 1) x1 = *(const ushort8v*)(base - 4096);
    if (l >= 2) x2 = *(const ushort8v*)(base - 8192);
    if (l >= 3) x3 = *(const ushort8v*)(base - 12288);
    ushort8v out;
#pragma unroll
    for (int j = 0; j < 8; ++j) {
        float4 wv = *(const float4*)(cw + (size_t)(d8 + j) * 4);
        float a = cb[d8 + j];
        a = fmaf(h2f(x3[j]), wv.x, a);
        a = fmaf(h2f(x2[j]), wv.y, a);
        a = fmaf(h2f(x1[j]), wv.z, a);
        a = fmaf(h2f(x0[j]), wv.w, a);
        out[j] = f2h(a * sigf(a));
    }
    *(ushort8v*)(xch + (size_t)row * DIN + d8) = out;
}

// ---------------- chunked selective scan: register-resident 16-state ----------------
// A[n] = -(n+1) for the given inputs (A_log = log(tile(arange(1,17)))) -> dA via power
// chain (1 exp + 15 muls, guarded by runtime check; fallback = 16 exps).
__global__ __launch_bounds__(256) void scan_pass1(
    const unsigned short* __restrict__ dth, const unsigned short* __restrict__ xch,
    const float* __restrict__ xdbl, const float* __restrict__ Alog,
    float* __restrict__ hbuf, float* __restrict__ apbuf)
{
    const int b = blockIdx.z, c = blockIdx.y;
    const int d = blockIdx.x * 256 + threadIdx.x;
    float A[16];
#pragma unroll
    for (int q = 0; q < 4; ++q) *(float4*)&A[q * 4] = *(const float4*)&Alog[(size_t)d * 16 + q * 4];
    bool seq = true;
#pragma unroll
    for (int n = 0; n < 16; ++n) {
        A[n] = -__expf(A[n]);
        seq = seq && (fabsf(A[n] + (float)(n + 1)) < 1e-5f * (float)(n + 1));
    }
    float h[16] = {};
    float sumdt = 0.f;
    const int rowbase = b * SEQ + c * CHL;
    int row = rowbase;
    float dtv = h2f(dth[(size_t)row * DIN + d]);
    float xcv = h2f(xch[(size_t)row * DIN + d]);
    if (seq) {
        for (int t = 0; t < CHL; ++t) {
            const int nrow = row + ((t + 1) < CHL ? 1 : 0);
            float dtv2 = h2f(dth[(size_t)nrow * DIN + d]);
            float xcv2 = h2f(xch[(size_t)nrow * DIN + d]);
            const float* xr = xdbl + (size_t)row * 96;
            float u = dtv * xcv;
            sumdt += dtv;
            float r = __expf(-dtv);
            float dA = r;
#pragma unroll
            for (int n = 0; n < 16; ++n) {
                h[n] = fmaf(dA, h[n], u * xr[64 + n]);
                dA *= r;
            }
            dtv = dtv2; xcv = xcv2; row = nrow;
        }
    } else {
        for (int t = 0; t < CHL; ++t) {
            const int nrow = row + ((t + 1) < CHL ? 1 : 0);
            float dtv2 = h2f(dth[(size_t)nrow * DIN + d]);
            float xcv2 = h2f(xch[(size_t)nrow * DIN + d]);
            const float* xr = xdbl + (size_t)row * 96;
            float u = dtv * xcv;
            sumdt += dtv;
#pragma unroll
            for (int n = 0; n < 16; ++n) {
                float dA = __expf(dtv * A[n]);
                h[n] = fmaf(dA, h[n], u * xr[64 + n]);
            }
            dtv = dtv2; xcv = xcv2; row = nrow;
        }
    }
    float ap[16];
    if (seq) {
        float R = __expf(-sumdt);
        float a = R;
#pragma unroll
        for (int n = 0; n < 16; ++n) { ap[n] = a; a *= R; }
    } else {
#pragma unroll
        for (int n = 0; n < 16; ++n) ap[n] = __expf(sumdt * A[n]);
    }
    size_t e = ((size_t)(b * NCH + c) << 15) + (size_t)d * 16;
#pragma unroll
    for (int q = 0; q < 4; ++q) {
        *(float4*)(hbuf + e + q * 4)  = *(float4*)&h[q * 4];
        *(float4*)(apbuf + e + q * 4) = *(float4*)&ap[q * 4];
    }
}

__global__ __launch_bounds__(256) void scan_pass2(
    float* __restrict__ hbuf, const float* __restrict__ apbuf)
{
    int idx = blockIdx.x * 256 + threadIdx.x;   // 65536
    int b = idx >> 15;
    int dn = idx & 32767;
    float carry = 0.f;
    for (int c = 0; c < NCH; ++c) {
        size_t e = ((size_t)(b * NCH + c) << 15) + dn;
        float hl = hbuf[e];
        float ap = apbuf[e];
        hbuf[e] = carry;
        carry = fmaf(ap, carry, hl);
    }
}

// pass 3: re-scan from h_in; fused epilogue writes op fp16 (dense [4096][2048])
__global__ __launch_bounds__(256) void scan_pass3(
    const unsigned short* __restrict__ dth, const unsigned short* __restrict__ xch,
    const unsigned short* __restrict__ xzh, const float* __restrict__ xdbl,
    const float* __restrict__ Alog, const float* __restrict__ Dp,
    const float* __restrict__ hbuf, unsigned short* __restrict__ oph)
{
    const int b = blockIdx.z, c = blockIdx.y;
    const int d = blockIdx.x * 256 + threadIdx.x;
    float A[16];
#pragma unroll
    for (int q = 0; q < 4; ++q) *(float4*)&A[q * 4] = *(const float4*)&Alog[(size_t)d * 16 + q * 4];
    bool seq = true;
#pragma unroll
    for (int n = 0; n < 16; ++n) {
        A[n] = -__expf(A[n]);
        seq = seq && (fabsf(A[n] + (float)(n + 1)) < 1e-5f * (float)(n + 1));
    }
    float h[16];
    size_t e = ((size_t)(b * NCH + c) << 15) + (size_t)d * 16;
#pragma unroll
    for (int q = 0; q < 4; ++q) *(float4*)&h[q * 4] = *(const float4*)(hbuf + e + q * 4);
    const float Dd = Dp[d];
    const int rowbase = b * SEQ + c * CHL;
    int row = rowbase;
    float dtv = h2f(dth[(size_t)row * DIN + d]);
    float xcv = h2f(xch[(size_t)row * DIN + d]);
    float zv  = h2f(xzh[(size_t)row * 4096 + DIN + d]);
    if (seq) {
        for (int t = 0; t < CHL; ++t) {
            const int nrow = row + ((t + 1) < CHL ? 1 : 0);
            float dtv2 = h2f(dth[(size_t)nrow * DIN + d]);
            float xcv2 = h2f(xch[(size_t)nrow * DIN + d]);
            float zv2  = h2f(xzh[(size_t)nrow * 4096 + DIN + d]);
            const float* xr = xdbl + (size_t)row * 96;
            float u = dtv * xcv;
            float r = __expf(-dtv);
            float dA = r;
            float y = 0.f;
#pragma unroll
            for (int n = 0; n < 16; ++n) {
                h[n] = fmaf(dA, h[n], u * xr[64 + n]);
                y = fmaf(h[n], xr[80 + n], y);
                dA *= r;
            }
            float val = (y + xcv * Dd) * zv * sigf(zv);
            oph[(size_t)row * DIN + d] = f2h(val);
            dtv = dtv2; xcv = xcv2; zv = zv2; row = nrow;
        }
    } else {
        for (int t = 0; t < CHL; ++t) {
            const int nrow = row + ((t + 1) < CHL ? 1 : 0);
            float dtv2 = h2f(dth[(size_t)nrow * DIN + d]);
            float xcv2 = h2f(xch[(size_t)nrow * DIN + d]);
            float zv2  = h2f(xzh[(size_t)nrow * 4096 + DIN + d]);
            const float* xr = xdbl + (size_t)row * 96;
            float u = dtv * xcv;
            float y = 0.f;
#pragma unroll
            for (int n = 0; n < 16; ++n) {
                float dA = __expf(dtv * A[n]);
                h[n] = fmaf(dA, h[n], u * xr[64 + n]);
                y = fmaf(h[n], xr[80 + n], y);
            }
            float val = (y + xcv * Dd) * zv * sigf(zv);
            oph[(size_t)row * DIN + d] = f2h(val);
            dtv = dtv2; xcv = xcv2; zv = zv2; row = nrow;
        }
    }
}

extern "C" void kernel_launch(void* const* d_in, const int* in_sizes, int n_in,
                              void* d_out, int out_size, void* d_ws, size_t ws_size,
                              hipStream_t stream)
{
    const float* x    = (const float*)d_in[0];
    const float* wi   = (const float*)d_in[1];
    const float* cw   = (const float*)d_in[2];
    const float* cb   = (const float*)d_in[3];
    const float* wx   = (const float*)d_in[4];
    const float* wd   = (const float*)d_in[5];
    const float* bd   = (const float*)d_in[6];
    const float* alog = (const float*)d_in[7];
    const float* Dp   = (const float*)d_in[8];
    const float* wo   = (const float*)d_in[9];
    float* out = (float*)d_out;

    float* wsf  = (float*)d_ws;
    float* xzr  = wsf;                          // region 16,777,216 f32
    float* xcr  = wsf + 16777216;               // region  8,388,608 f32
    float* xdbl = wsf + 25165824;               // [4096][96] f32
    float* dtr  = wsf + 25559040;               // region  8,388,608 f32

    // xz region: fp16 xz [4096][4096] in first half; oph + hbuf fill the second half
    unsigned short* xzh = (unsigned short*)xzr;
    float* scr = xzr + 8388608;
    unsigned short* oph = (unsigned short*)scr;                 // [4096][2048] fp16
    float* hbuf         = scr + 4194304;                        // 4,194,304 f32 (NCH=64)

    // xc region: xch fp16 first half; apbuf second half
    unsigned short* xh  = (unsigned short*)xcr;                 // in_proj A; dead after gemm256
    unsigned short* xch = (unsigned short*)xcr;                 // conv output (overwrites xh)
    float* apbuf        = xcr + 4194304;                        // 4,194,304 f32 (NCH=64)

    // dt region (sequential lifetimes, all offsets in f32 units):
    unsigned short* wih    = (unsigned short*)dtr;               // [0,4.19M) in_proj W; dead after gemm256
    unsigned short* dth    = (unsigned short*)dtr;               // [0,4.19M) dt fp16; dead after pass3
    unsigned short* oparth = (unsigned short*)dtr;               // [0,4.19M) out partials (after pass3)
    unsigned short* wxh    = (unsigned short*)(dtr + 4194304);   // [4.19M,4.33M) padded Wx
    unsigned short* xparth = (unsigned short*)(dtr + 4325376);   // [4.33M,6.42M) xproj partials
    unsigned short* woh    = (unsigned short*)(dtr + 6422528);   // [6.42M,7.47M) wo fp16
    unsigned short* wdh    = (unsigned short*)(dtr + 7471104);   // [7.47M,7.54M) wd fp16
    unsigned short* dlh    = (unsigned short*)(dtr + 7536640);   // [7.54M,7.67M) dt_low fp16

    // 1) fp16 operands: x, wi, Wx(pad), wd, wo
    cvt_in_k<<<10624, 256, 0, stream>>>(x, wi, wx, wd, wo, xh, wih, wxh, wdh, woh);
    // 2) xz = x @ in_proj_w^T  -> fp16 (M=4096, N=4096, K=1024), counted-vmcnt 256^2
    gemm256_h<<<256, 512, 0, stream>>>(xh, wih, xzh, 1024, 4096, 16, 1024, 1024);
    // 3) xch = fp16 silu(conv(xs)+b)  (overwrites xh — dead)
    conv_silu_k<<<4096, 256, 0, stream>>>(xzh, cw, cb, xch);
    // 4) x_dbl = xch @ Wx^T, split-K 8x256 -> fp16 partials; reduce -> xdbl f32 + dlh fp16
    gemm_mfma_h<<<256, 256, 0, stream>>>(xch, wxh, xparth, 256, 128, 128, 32, 2048, 4096, 2048,
                                         nullptr, 8, NROWS * 128);
    xproj_reduce_k<<<512, 256, 0, stream>>>(xparth, xdbl, dlh);
    // 5) dt = fp16 softplus(dt_low @ Wd^T + bd)  (overwrites wih/xparth region [0,4.19M) only)
    gemm_mfma_h<<<512, 256, 0, stream>>>(dlh, wdh, dth, 64, 2048, 2048, 32, 64, 128, 64,
                                         bd, 1, 0);
    // 6) chunked scan (NCH=64, CHL=32); pass3 writes op fp16 dense
    scan_pass1<<<dim3(8, NCH, 2), 256, 0, stream>>>(dth, xch, xdbl, alog, hbuf, apbuf);
    scan_pass2<<<256, 256, 0, stream>>>(hbuf, apbuf);
    scan_pass3<<<dim3(8, NCH, 2), 256, 0, stream>>>(dth, xch, xzh, xdbl, alog, Dp, hbuf, oph);
    // 7) out = op @ out_proj_w^T, split-K 2x1024 -> fp16 partials (dth dead) + reduce
    gemm_mfma_h<<<512, 256, 0, stream>>>(oph, woh, oparth, 1024, 1024, 1024, 32, 2048, 4096, 2048,
                                         nullptr, 2, 4194304);
    out_reduce_k<<<4096, 256, 0, stream>>>(oparth, out);
}